// Round 1
// baseline (564.462 us; speedup 1.0000x reference)
//
#include <hip/hip_runtime.h>
#include <stdint.h>

typedef unsigned short u16;
typedef unsigned int   u32;
typedef __bf16 bf16x8 __attribute__((ext_vector_type(8)));
typedef float  f32x4  __attribute__((ext_vector_type(4)));
typedef u32    u32x4  __attribute__((ext_vector_type(4)));
typedef u32    u32x2  __attribute__((ext_vector_type(2)));

#define B_SZ  2
#define S_LEN 2048
#define NH    16
#define HD    64
#define DIM   1024
#define FF    4096
#define T_LEN 3072
#define PREV  1024
#define MROWS (B_SZ * S_LEN) /* 4096 */

__device__ __forceinline__ u16 f2bf(float f) {
  u32 u = __builtin_bit_cast(u32, f);
  u32 r = u + 0x7FFFu + ((u >> 16) & 1u);
  return (u16)(r >> 16);
}
__device__ __forceinline__ float bf2f(u16 h) {
  u32 u = ((u32)h) << 16;
  return __builtin_bit_cast(float, u);
}

// async global->LDS, 16B per lane. LDS dest must be wave-uniform base + lane*16.
__device__ __forceinline__ void gl_lds16(const void* g, void* l) {
  __builtin_amdgcn_global_load_lds(
      (const __attribute__((address_space(1))) u32*)g,
      (__attribute__((address_space(3))) u32*)l, 16, 0, 0);
}

// ---------------- fp32 -> bf16 convert (weights) ----------------
__global__ __launch_bounds__(256) void cvt_kernel(const float* __restrict__ src,
                                                  u16* __restrict__ dst, int n4) {
  int i = blockIdx.x * 256 + threadIdx.x;
  const int stride = gridDim.x * 256;
  for (; i < n4; i += stride) {
    f32x4 v = *(const f32x4*)&src[(long)i * 4];
    u32x2 o;
    o[0] = (u32)f2bf(v[0]) | ((u32)f2bf(v[1]) << 16);
    o[1] = (u32)f2bf(v[2]) | ((u32)f2bf(v[3]) << 16);
    *(u32x2*)&dst[(long)i * 4] = o;
  }
}

// ---------------- RMSNorm: fp32 row -> bf16 row ----------------
__global__ __launch_bounds__(256) void rmsnorm_kernel(const float* __restrict__ x,
                                                      const float* __restrict__ w,
                                                      u16* __restrict__ out) {
  const int row = blockIdx.x;
  const int tid = threadIdx.x;
  const long base = (long)row * DIM + tid * 4;
  f32x4 v = *(const f32x4*)&x[base];
  float ss = v[0] * v[0] + v[1] * v[1] + v[2] * v[2] + v[3] * v[3];
#pragma unroll
  for (int d = 1; d <= 32; d <<= 1) ss += __shfl_xor(ss, d, 64);
  __shared__ float red[4];
  if ((tid & 63) == 0) red[tid >> 6] = ss;
  __syncthreads();
  float tot = red[0] + red[1] + red[2] + red[3];
  const float sc = rsqrtf(tot * (1.f / (float)DIM) + 1e-6f);
  f32x4 wv4 = *(const f32x4*)&w[tid * 4];
  u32x2 o;
  o[0] = (u32)f2bf(v[0] * sc * wv4[0]) | ((u32)f2bf(v[1] * sc * wv4[1]) << 16);
  o[1] = (u32)f2bf(v[2] * sc * wv4[2]) | ((u32)f2bf(v[3] * sc * wv4[3]) << 16);
  *(u32x2*)&out[base] = o;
}

// ---------------- GEMM: C[M,N] = A[M,K](bf16) * Bw[N,K]^T(bf16) + bias ----------------
// m97 structure: 128x128 tile, BK=32, 4 waves, global_load_lds w=16, 2-barrier loop.
// EPI 0: bf16 store.  EPI 1: fp32 store of resid + acc.
template <int EPI>
__global__ __launch_bounds__(256) void gemm_bt(const u16* __restrict__ A,
                                               const u16* __restrict__ Bw,
                                               const float* __restrict__ bias,
                                               const float* __restrict__ resid,
                                               u16* __restrict__ out_bf,
                                               float* __restrict__ out_f,
                                               int N, int K) {
  __shared__ __align__(16) u16 As[128 * 32];
  __shared__ __align__(16) u16 Bs[128 * 32];
  const int tid = threadIdx.x;
  const int lane = tid & 63;
  const int wv = tid >> 6;
  const int wr = wv >> 1, wc = wv & 1;
  const long m0 = (long)blockIdx.y * 128;
  const long n0 = (long)blockIdx.x * 128;

  const int arow = tid >> 2;
  const int acol = (tid & 3) << 3;
  const u16* ag = A + (m0 + arow) * K + acol;
  const u16* bg = Bw + (n0 + arow) * K + acol;
  u16* al = As + tid * 8;
  u16* bl = Bs + tid * 8;
  const long hK = (long)64 * K;

  f32x4 acc[4][4] = {};
  const int l15 = lane & 15;
  const int lhi = lane >> 4;
  const int aoff0 = (wr * 64 + l15) * 32 + lhi * 8;
  const int boff0 = (wc * 64 + l15) * 32 + lhi * 8;

  for (int k0 = 0; k0 < K; k0 += 32) {
    gl_lds16(ag + k0, al);
    gl_lds16(ag + k0 + hK, al + 64 * 32);
    gl_lds16(bg + k0, bl);
    gl_lds16(bg + k0 + hK, bl + 64 * 32);
    __syncthreads();  // drains vmcnt (loads landed) + barrier
    bf16x8 af[4], bfr[4];
#pragma unroll
    for (int i = 0; i < 4; ++i) af[i] = *(const bf16x8*)&As[aoff0 + i * 16 * 32];
#pragma unroll
    for (int j = 0; j < 4; ++j) bfr[j] = *(const bf16x8*)&Bs[boff0 + j * 16 * 32];
#pragma unroll
    for (int i = 0; i < 4; ++i)
#pragma unroll
      for (int j = 0; j < 4; ++j)
        acc[i][j] = __builtin_amdgcn_mfma_f32_16x16x32_bf16(af[i], bfr[j], acc[i][j], 0, 0, 0);
    __syncthreads();  // reads done before next stage overwrites
  }

#pragma unroll
  for (int i = 0; i < 4; ++i) {
    const long row0 = m0 + wr * 64 + i * 16 + lhi * 4;
#pragma unroll
    for (int j = 0; j < 4; ++j) {
      const long col = n0 + wc * 64 + j * 16 + l15;
      const float bb = bias[col];
#pragma unroll
      for (int r = 0; r < 4; ++r) {
        const long idx = (row0 + r) * N + col;
        float v = acc[i][j][r] + bb;
        if (EPI == 0) out_bf[idx] = f2bf(v);
        else          out_f[idx] = resid[idx] + v;
      }
    }
  }
}

// ---------------- RoPE on Q (from fused qkv GEMM output) ----------------
__global__ __launch_bounds__(256) void rope_q_kernel(const u16* __restrict__ qkv,
                                                     const float* __restrict__ cosT,
                                                     const float* __restrict__ sinT,
                                                     u16* __restrict__ Q) {
  int idx = blockIdx.x * 256 + threadIdx.x;  // B*H*S*8 = 524288 units of 8 elems
  int u = idx & 7;
  int s = (idx >> 3) & (S_LEN - 1);
  int bh = idx >> 14;
  int b = bh >> 4, h = bh & 15;
  int pos = PREV + s;
  const u16* src = qkv + ((long)(b * S_LEN + s)) * (3 * DIM) + h * HD + u * 8;
  u32x4 d = *(const u32x4*)src;
  f32x4 cv = *(const f32x4*)&cosT[(long)pos * 32 + u * 4];
  f32x4 sv = *(const f32x4*)&sinT[(long)pos * 32 + u * 4];
  u32x4 o;
#pragma unroll
  for (int p = 0; p < 4; ++p) {
    float x0 = bf2f((u16)(d[p] & 0xffff));
    float x1 = bf2f((u16)(d[p] >> 16));
    float y0 = x0 * cv[p] - x1 * sv[p];
    float y1 = x0 * sv[p] + x1 * cv[p];
    o[p] = (u32)f2bf(y0) | ((u32)f2bf(y1) << 16);
  }
  *(u32x4*)&Q[((long)bh * S_LEN + s) * HD + u * 8] = o;
}

// ---------------- K_all = rope(concat(cache_k, k_new)); stored XOR-swizzled ----------------
// global layout per row j: 16B unit u stored at position (u ^ (j&7)) -> linear
// global_load_lds staging lands bank-conflict-free swizzled tiles in LDS.
__global__ __launch_bounds__(256) void rope_k_kernel(const u16* __restrict__ qkv,
                                                     const float* __restrict__ cache_k,
                                                     const float* __restrict__ cosT,
                                                     const float* __restrict__ sinT,
                                                     u16* __restrict__ Kall) {
  int idx = blockIdx.x * 256 + threadIdx.x;  // B*H*T*8 = 786432
  int u = idx & 7;
  int t2 = idx >> 3;
  int j = t2 % T_LEN;
  int bh = t2 / T_LEN;
  int b = bh >> 4, h = bh & 15;
  float e[8];
  if (j < PREV) {
    const float* src = cache_k + ((long)bh * PREV + j) * HD + u * 8;
    f32x4 a = *(const f32x4*)src;
    f32x4 c = *(const f32x4*)(src + 4);
    e[0] = a[0]; e[1] = a[1]; e[2] = a[2]; e[3] = a[3];
    e[4] = c[0]; e[5] = c[1]; e[6] = c[2]; e[7] = c[3];
  } else {
    const u16* src = qkv + ((long)(b * S_LEN + (j - PREV))) * (3 * DIM) + DIM + h * HD + u * 8;
    u32x4 d = *(const u32x4*)src;
#pragma unroll
    for (int p = 0; p < 4; ++p) {
      e[2 * p] = bf2f((u16)(d[p] & 0xffff));
      e[2 * p + 1] = bf2f((u16)(d[p] >> 16));
    }
  }
  f32x4 cv = *(const f32x4*)&cosT[(long)j * 32 + u * 4];
  f32x4 sv = *(const f32x4*)&sinT[(long)j * 32 + u * 4];
  u32x4 o;
#pragma unroll
  for (int p = 0; p < 4; ++p) {
    float y0 = e[2 * p] * cv[p] - e[2 * p + 1] * sv[p];
    float y1 = e[2 * p] * sv[p] + e[2 * p + 1] * cv[p];
    o[p] = (u32)f2bf(y0) | ((u32)f2bf(y1) << 16);
  }
  *(u32x4*)&Kall[((long)bh * T_LEN + j) * HD + (u ^ (j & 7)) * 8] = o;
}

// ---------------- V_all = concat(cache_v, v_new) bf16 (unswizzled) ----------------
__global__ __launch_bounds__(256) void build_v_kernel(const u16* __restrict__ qkv,
                                                      const float* __restrict__ cache_v,
                                                      u16* __restrict__ Vall) {
  int idx = blockIdx.x * 256 + threadIdx.x;
  int u = idx & 7;
  int t2 = idx >> 3;
  int j = t2 % T_LEN;
  int bh = t2 / T_LEN;
  int b = bh >> 4, h = bh & 15;
  u32x4 o;
  if (j < PREV) {
    const float* src = cache_v + ((long)bh * PREV + j) * HD + u * 8;
    f32x4 a = *(const f32x4*)src;
    f32x4 c = *(const f32x4*)(src + 4);
    o[0] = (u32)f2bf(a[0]) | ((u32)f2bf(a[1]) << 16);
    o[1] = (u32)f2bf(a[2]) | ((u32)f2bf(a[3]) << 16);
    o[2] = (u32)f2bf(c[0]) | ((u32)f2bf(c[1]) << 16);
    o[3] = (u32)f2bf(c[2]) | ((u32)f2bf(c[3]) << 16);
  } else {
    const u16* src = qkv + ((long)(b * S_LEN + (j - PREV))) * (3 * DIM) + 2 * DIM + h * HD + u * 8;
    o = *(const u32x4*)src;
  }
  *(u32x4*)&Vall[((long)bh * T_LEN + j) * HD + u * 8] = o;
}

// ---------------- flash attention: 64 q-rows/block, 4 waves x 16 rows ----------------
__global__ __launch_bounds__(256) void attn_kernel(const u16* __restrict__ Q,
                                                   const u16* __restrict__ Kall,
                                                   const u16* __restrict__ Vall,
                                                   u16* __restrict__ ctx, float slope) {
  __shared__ __align__(16) u16 Ks[64 * 64];      // swizzled (from global layout)
  __shared__ __align__(16) u16 Vt[64 * 72];      // transposed V, stride 72 (bank spread)
  __shared__ __align__(16) u16 Ps[4][16 * 72];   // per-wave P roundtrip, stride 72

  const int tid = threadIdx.x;
  const int lane = tid & 63;
  const int wv = tid >> 6;
  const int l15 = lane & 15;
  const int lhi = lane >> 4;
  const int bh = blockIdx.y;
  const int b = bh >> 4, h = bh & 15;
  const int q0 = blockIdx.x * 64;

  const long qbase = ((long)bh * S_LEN + q0 + wv * 16 + l15) * HD;
  bf16x8 aq0 = *(const bf16x8*)&Q[qbase + lhi * 8];
  bf16x8 aq1 = *(const bf16x8*)&Q[qbase + 32 + lhi * 8];

  f32x4 o[4] = {};
  float mrun[4], lrun[4];
#pragma unroll
  for (int r = 0; r < 4; ++r) { mrun[r] = -1e30f; lrun[r] = 0.f; }

  const int i_row0 = q0 + wv * 16 + lhi * 4;  // + r = query index in [0,S)
  const int kend = (PREV + q0 + 64 < T_LEN) ? (PREV + q0 + 64) : T_LEN;

  const long kgbase = (long)bh * T_LEN * HD;
  const int kkey = tid >> 3;
  const int khd = (tid & 7) * 8;
  const long vgl = kgbase + (long)lane * HD + wv * 16;

  for (int kt0 = 0; kt0 < kend; kt0 += 64) {
    // V tile to regs (global, no LDS hazard yet)
    u32x4 v0 = *(const u32x4*)&Vall[vgl + (long)kt0 * HD];
    u32x4 v1 = *(const u32x4*)&Vall[vgl + (long)kt0 * HD + 8];
    __syncthreads();  // (A) everyone done reading prev tile
    gl_lds16(&Kall[kgbase + (long)(kt0 + kkey) * HD + khd], &Ks[tid * 8]);
    gl_lds16(&Kall[kgbase + (long)(kt0 + kkey + 32) * HD + khd], &Ks[2048 + tid * 8]);
#pragma unroll
    for (int jj = 0; jj < 8; ++jj) {
      u32 w0 = v0[jj >> 1], w1 = v1[jj >> 1];
      Vt[(wv * 16 + jj) * 72 + lane] = (u16)((jj & 1) ? (w0 >> 16) : (w0 & 0xffff));
      Vt[(wv * 16 + 8 + jj) * 72 + lane] = (u16)((jj & 1) ? (w1 >> 16) : (w1 & 0xffff));
    }
    __syncthreads();  // (B) drains gl_lds + ds_writes

    // S = Q K^T  (B-frag: col=key, k=hd; un-XOR the stored swizzle)
    f32x4 sf[4];
#pragma unroll
    for (int jf = 0; jf < 4; ++jf) {
      const int ktl = jf * 16 + l15;
      const int sw = ktl & 7;
      bf16x8 bk0 = *(const bf16x8*)&Ks[ktl * 64 + ((lhi ^ sw) * 8)];
      bf16x8 bk1 = *(const bf16x8*)&Ks[ktl * 64 + (((4 + lhi) ^ sw) * 8)];
      f32x4 s = {};
      s = __builtin_amdgcn_mfma_f32_16x16x32_bf16(aq0, bk0, s, 0, 0, 0);
      s = __builtin_amdgcn_mfma_f32_16x16x32_bf16(aq1, bk1, s, 0, 0, 0);
      sf[jf] = s;
    }

    // scale + rel-pos bias + causal mask
#pragma unroll
    for (int jf = 0; jf < 4; ++jf) {
      const int jcol = kt0 + jf * 16 + l15;
#pragma unroll
      for (int r = 0; r < 4; ++r) {
        const int iabs = PREV + i_row0 + r;
        float s_ = sf[jf][r] * 0.125f + slope * (float)(jcol - iabs);
        sf[jf][r] = (jcol > iabs) ? -1e30f : s_;
      }
    }

    // online softmax (rows live across the 16 lanes of each lhi group)
    float scl[4];
#pragma unroll
    for (int r = 0; r < 4; ++r) {
      float mx = fmaxf(fmaxf(sf[0][r], sf[1][r]), fmaxf(sf[2][r], sf[3][r]));
#pragma unroll
      for (int d = 1; d <= 8; d <<= 1) mx = fmaxf(mx, __shfl_xor(mx, d, 64));
      float mnew = fmaxf(mrun[r], mx);
      scl[r] = __expf(mrun[r] - mnew);
      mrun[r] = mnew;
      float ps = 0.f;
#pragma unroll
      for (int jf = 0; jf < 4; ++jf) {
        float p = __expf(sf[jf][r] - mnew);
        sf[jf][r] = p;
        ps += p;
      }
#pragma unroll
      for (int d = 1; d <= 8; d <<= 1) ps += __shfl_xor(ps, d, 64);
      lrun[r] = lrun[r] * scl[r] + ps;
#pragma unroll
      for (int hf = 0; hf < 4; ++hf) o[hf][r] *= scl[r];
    }

    // P (C-layout) -> LDS -> A-frag layout
    u16* pw = &Ps[wv][0];
#pragma unroll
    for (int jf = 0; jf < 4; ++jf)
#pragma unroll
      for (int r = 0; r < 4; ++r)
        pw[(lhi * 4 + r) * 72 + jf * 16 + l15] = f2bf(sf[jf][r]);

    bf16x8 pa0 = *(const bf16x8*)&pw[l15 * 72 + lhi * 8];
    bf16x8 pa1 = *(const bf16x8*)&pw[l15 * 72 + 32 + lhi * 8];

    // O += P V   (B-frag from transposed V: col=hd, k=key)
#pragma unroll
    for (int hf = 0; hf < 4; ++hf) {
      const int vr = hf * 16 + l15;
      bf16x8 bv0 = *(const bf16x8*)&Vt[vr * 72 + lhi * 8];
      bf16x8 bv1 = *(const bf16x8*)&Vt[vr * 72 + 32 + lhi * 8];
      o[hf] = __builtin_amdgcn_mfma_f32_16x16x32_bf16(pa0, bv0, o[hf], 0, 0, 0);
      o[hf] = __builtin_amdgcn_mfma_f32_16x16x32_bf16(pa1, bv1, o[hf], 0, 0, 0);
    }
  }

#pragma unroll
  for (int r = 0; r < 4; ++r) {
    const int i = i_row0 + r;
    const float inv = 1.f / lrun[r];
    const long rb = ((long)b * S_LEN + i) * DIM + h * HD;
#pragma unroll
    for (int hf = 0; hf < 4; ++hf)
      ctx[rb + hf * 16 + l15] = f2bf(o[hf][r] * inv);
  }
}

// ---------------- gated = silu(g) * v ----------------
__global__ __launch_bounds__(256) void silu_mul_kernel(const u16* __restrict__ gv,
                                                       u16* __restrict__ out) {
  const int idx = blockIdx.x * 256 + threadIdx.x;  // 4096*512
  const int row = idx >> 9;
  const int c8 = (idx & 511) * 8;
  u32x4 g4 = *(const u32x4*)&gv[(long)row * (2 * FF) + c8];
  u32x4 v4 = *(const u32x4*)&gv[(long)row * (2 * FF) + FF + c8];
  u32x4 o;
#pragma unroll
  for (int p = 0; p < 4; ++p) {
    float g0 = bf2f((u16)(g4[p] & 0xffff)), g1 = bf2f((u16)(g4[p] >> 16));
    float w0 = bf2f((u16)(v4[p] & 0xffff)), w1 = bf2f((u16)(v4[p] >> 16));
    float s0 = g0 / (1.f + __expf(-g0)) * w0;
    float s1 = g1 / (1.f + __expf(-g1)) * w1;
    o[p] = (u32)f2bf(s0) | ((u32)f2bf(s1) << 16);
  }
  *(u32x4*)&out[(long)row * FF + c8] = o;
}

// ---------------------------------------------------------------------------
extern "C" void kernel_launch(void* const* d_in, const int* in_sizes, int n_in,
                              void* d_out, int out_size, void* d_ws, size_t ws_size,
                              hipStream_t stream) {
  (void)in_sizes; (void)n_in; (void)out_size; (void)ws_size;
  const float* x       = (const float*)d_in[0];
  const float* cache_k = (const float*)d_in[1];
  const float* cache_v = (const float*)d_in[2];
  const float* cosT    = (const float*)d_in[3];
  const float* sinT    = (const float*)d_in[4];
  const float* attn_w  = (const float*)d_in[5];
  const float* ffn_w   = (const float*)d_in[6];
  const float* wq      = (const float*)d_in[7];
  const float* bq      = (const float*)d_in[8];
  const float* wk      = (const float*)d_in[9];
  const float* bk      = (const float*)d_in[10];
  const float* wv_     = (const float*)d_in[11];
  const float* bv      = (const float*)d_in[12];
  const float* wo      = (const float*)d_in[13];
  const float* bo      = (const float*)d_in[14];
  const float* wg      = (const float*)d_in[15];
  const float* bg      = (const float*)d_in[16];
  const float* wval    = (const float*)d_in[17];
  const float* bval    = (const float*)d_in[18];
  const float* wp      = (const float*)d_in[19];
  const float* bp      = (const float*)d_in[20];
  float* out = (float*)d_out;

  char* w = (char*)d_ws;
  size_t off = 0;
  auto alloc = [&](size_t bytes) -> char* {
    char* p = w + off;
    off += (bytes + 255) & ~(size_t)255;
    return p;
  };
  // permanent
  u16*   wqkv_bf  = (u16*)alloc((size_t)3 * DIM * DIM * 2);
  u16*   wo_bf    = (u16*)alloc((size_t)DIM * DIM * 2);
  u16*   wgv_bf   = (u16*)alloc((size_t)2 * FF * DIM * 2);
  u16*   wproj_bf = (u16*)alloc((size_t)DIM * FF * 2);
  float* bqkv     = (float*)alloc((size_t)3 * DIM * 4);
  float* bgv      = (float*)alloc((size_t)2 * FF * 4);
  float* x2       = (float*)alloc((size_t)MROWS * DIM * 4);
  // arena with lifetime-based aliasing
  char* AR = alloc((size_t)117440512);
  u16* qkv   = (u16*)(AR + 0);          // [4096][3072]   live: qkv gemm -> rope/build
  u16* Qb    = (u16*)(AR + 25165824);   // [32][2048][64] live: rope -> attn
  u16* Kb    = (u16*)(AR + 33554432);   // [32][3072][64]
  u16* Vb    = (u16*)(AR + 46137344);   // [32][3072][64]
  u16* h1    = (u16*)(AR + 58720256);   // [4096][1024]   live: rms1 -> qkv gemm
  u16* ctx   = (u16*)(AR + 0);          // [4096][1024]   (aliases dead qkv)
  u16* h2    = (u16*)(AR + 8388608);    // [4096][1024]
  u16* gvb   = (u16*)(AR + 16777216);   // [4096][8192]   (aliases dead Q/K/V/h1)
  u16* gated = (u16*)(AR + 83886080);   // [4096][4096]

  // 1) weights -> bf16 (+ fused bias packs)
  cvt_kernel<<<512, 256, 0, stream>>>(wq, wqkv_bf, DIM * DIM / 4);
  cvt_kernel<<<512, 256, 0, stream>>>(wk, wqkv_bf + DIM * DIM, DIM * DIM / 4);
  cvt_kernel<<<512, 256, 0, stream>>>(wv_, wqkv_bf + 2 * DIM * DIM, DIM * DIM / 4);
  cvt_kernel<<<512, 256, 0, stream>>>(wo, wo_bf, DIM * DIM / 4);
  cvt_kernel<<<1024, 256, 0, stream>>>(wg, wgv_bf, FF * DIM / 4);
  cvt_kernel<<<1024, 256, 0, stream>>>(wval, wgv_bf + (size_t)FF * DIM, FF * DIM / 4);
  cvt_kernel<<<1024, 256, 0, stream>>>(wp, wproj_bf, DIM * FF / 4);
  hipMemcpyAsync(bqkv, bq, DIM * 4, hipMemcpyDeviceToDevice, stream);
  hipMemcpyAsync(bqkv + DIM, bk, DIM * 4, hipMemcpyDeviceToDevice, stream);
  hipMemcpyAsync(bqkv + 2 * DIM, bv, DIM * 4, hipMemcpyDeviceToDevice, stream);
  hipMemcpyAsync(bgv, bg, FF * 4, hipMemcpyDeviceToDevice, stream);
  hipMemcpyAsync(bgv + FF, bval, FF * 4, hipMemcpyDeviceToDevice, stream);

  // 2) attn rmsnorm, fused QKV gemm
  rmsnorm_kernel<<<MROWS, 256, 0, stream>>>(x, attn_w, h1);
  gemm_bt<0><<<dim3(24, 32), 256, 0, stream>>>(h1, wqkv_bf, bqkv, nullptr, qkv, nullptr,
                                               3 * DIM, DIM);
  // 3) rope + cache concat
  rope_q_kernel<<<2048, 256, 0, stream>>>(qkv, cosT, sinT, Qb);
  rope_k_kernel<<<3072, 256, 0, stream>>>(qkv, cache_k, cosT, sinT, Kb);
  build_v_kernel<<<3072, 256, 0, stream>>>(qkv, cache_v, Vb);
  // 4) attention
  attn_kernel<<<dim3(S_LEN / 64, B_SZ * NH), 256, 0, stream>>>(Qb, Kb, Vb, ctx,
                                                               2.0f / (float)(T_LEN - 1));
  // 5) o-proj + residual (fp32)
  gemm_bt<1><<<dim3(8, 32), 256, 0, stream>>>(ctx, wo_bf, bo, x, nullptr, x2, DIM, DIM);
  // 6) ffn rmsnorm, fused gate+value gemm, silu*v, proj + residual
  rmsnorm_kernel<<<MROWS, 256, 0, stream>>>(x2, ffn_w, h2);
  gemm_bt<0><<<dim3(64, 32), 256, 0, stream>>>(h2, wgv_bf, bgv, nullptr, gvb, nullptr,
                                               2 * FF, DIM);
  silu_mul_kernel<<<8192, 256, 0, stream>>>(gvb, gated);
  gemm_bt<1><<<dim3(8, 32), 256, 0, stream>>>(gated, wproj_bf, bp, x2, nullptr, out,
                                              DIM, FF);
}

// Round 2
// 466.943 us; speedup vs baseline: 1.2088x; 1.2088x over previous
//
#include <hip/hip_runtime.h>
#include <stdint.h>

typedef unsigned short u16;
typedef unsigned int   u32;
typedef __bf16 bf16x8 __attribute__((ext_vector_type(8)));
typedef float  f32x4  __attribute__((ext_vector_type(4)));
typedef u32    u32x4  __attribute__((ext_vector_type(4)));
typedef u32    u32x2  __attribute__((ext_vector_type(2)));

#define B_SZ  2
#define S_LEN 2048
#define NH    16
#define HD    64
#define DIM   1024
#define FF    4096
#define T_LEN 3072
#define PREV  1024
#define MROWS (B_SZ * S_LEN) /* 4096 */
#define LOG2E 1.44269504f

#define MFMA16 __builtin_amdgcn_mfma_f32_16x16x32_bf16

__device__ __forceinline__ u16 f2bf(float f) {
  u32 u = __builtin_bit_cast(u32, f);
  u32 r = u + 0x7FFFu + ((u >> 16) & 1u);
  return (u16)(r >> 16);
}
__device__ __forceinline__ float bf2f(u16 h) {
  u32 u = ((u32)h) << 16;
  return __builtin_bit_cast(float, u);
}
__device__ __forceinline__ u32 cvtpk(float lo, float hi) {
  u32 r;
  asm("v_cvt_pk_bf16_f32 %0, %1, %2" : "=v"(r) : "v"(lo), "v"(hi));
  return r;
}

// async global->LDS, 16B per lane. LDS dest must be wave-uniform base + lane*16.
__device__ __forceinline__ void gl_lds16(const void* g, void* l) {
  __builtin_amdgcn_global_load_lds(
      (const __attribute__((address_space(1))) u32*)g,
      (__attribute__((address_space(3))) u32*)l, 16, 0, 0);
}

// ---------------- fp32 -> bf16 convert (weights) ----------------
__global__ __launch_bounds__(256) void cvt_kernel(const float* __restrict__ src,
                                                  u16* __restrict__ dst, int n4) {
  int i = blockIdx.x * 256 + threadIdx.x;
  const int stride = gridDim.x * 256;
  for (; i < n4; i += stride) {
    f32x4 v = *(const f32x4*)&src[(long)i * 4];
    u32x2 o;
    o[0] = (u32)f2bf(v[0]) | ((u32)f2bf(v[1]) << 16);
    o[1] = (u32)f2bf(v[2]) | ((u32)f2bf(v[3]) << 16);
    *(u32x2*)&dst[(long)i * 4] = o;
  }
}

// ---------------- RMSNorm: fp32 row -> bf16 row ----------------
__global__ __launch_bounds__(256) void rmsnorm_kernel(const float* __restrict__ x,
                                                      const float* __restrict__ w,
                                                      u16* __restrict__ out) {
  const int row = blockIdx.x;
  const int tid = threadIdx.x;
  const long base = (long)row * DIM + tid * 4;
  f32x4 v = *(const f32x4*)&x[base];
  float ss = v[0] * v[0] + v[1] * v[1] + v[2] * v[2] + v[3] * v[3];
#pragma unroll
  for (int d = 1; d <= 32; d <<= 1) ss += __shfl_xor(ss, d, 64);
  __shared__ float red[4];
  if ((tid & 63) == 0) red[tid >> 6] = ss;
  __syncthreads();
  float tot = red[0] + red[1] + red[2] + red[3];
  const float sc = rsqrtf(tot * (1.f / (float)DIM) + 1e-6f);
  f32x4 wv4 = *(const f32x4*)&w[tid * 4];
  u32x2 o;
  o[0] = (u32)f2bf(v[0] * sc * wv4[0]) | ((u32)f2bf(v[1] * sc * wv4[1]) << 16);
  o[1] = (u32)f2bf(v[2] * sc * wv4[2]) | ((u32)f2bf(v[3] * sc * wv4[3]) << 16);
  *(u32x2*)&out[base] = o;
}

// ---------------- GEMM: C[M,N] = A[M,K](bf16) * Bw[N,K]^T(bf16) + bias ----------------
template <int EPI>
__global__ __launch_bounds__(256) void gemm_bt(const u16* __restrict__ A,
                                               const u16* __restrict__ Bw,
                                               const float* __restrict__ bias,
                                               const float* __restrict__ resid,
                                               u16* __restrict__ out_bf,
                                               float* __restrict__ out_f,
                                               int N, int K) {
  __shared__ __align__(16) u16 As[128 * 32];
  __shared__ __align__(16) u16 Bs[128 * 32];
  const int tid = threadIdx.x;
  const int lane = tid & 63;
  const int wv = tid >> 6;
  const int wr = wv >> 1, wc = wv & 1;
  const long m0 = (long)blockIdx.y * 128;
  const long n0 = (long)blockIdx.x * 128;

  const int arow = tid >> 2;
  const int acol = (tid & 3) << 3;
  const u16* ag = A + (m0 + arow) * K + acol;
  const u16* bg = Bw + (n0 + arow) * K + acol;
  u16* al = As + tid * 8;
  u16* bl = Bs + tid * 8;
  const long hK = (long)64 * K;

  f32x4 acc[4][4] = {};
  const int l15 = lane & 15;
  const int lhi = lane >> 4;
  const int aoff0 = (wr * 64 + l15) * 32 + lhi * 8;
  const int boff0 = (wc * 64 + l15) * 32 + lhi * 8;

  for (int k0 = 0; k0 < K; k0 += 32) {
    gl_lds16(ag + k0, al);
    gl_lds16(ag + k0 + hK, al + 64 * 32);
    gl_lds16(bg + k0, bl);
    gl_lds16(bg + k0 + hK, bl + 64 * 32);
    __syncthreads();
    bf16x8 af[4], bfr[4];
#pragma unroll
    for (int i = 0; i < 4; ++i) af[i] = *(const bf16x8*)&As[aoff0 + i * 16 * 32];
#pragma unroll
    for (int j = 0; j < 4; ++j) bfr[j] = *(const bf16x8*)&Bs[boff0 + j * 16 * 32];
#pragma unroll
    for (int i = 0; i < 4; ++i)
#pragma unroll
      for (int j = 0; j < 4; ++j)
        acc[i][j] = MFMA16(af[i], bfr[j], acc[i][j], 0, 0, 0);
    __syncthreads();
  }

#pragma unroll
  for (int i = 0; i < 4; ++i) {
    const long row0 = m0 + wr * 64 + i * 16 + lhi * 4;
#pragma unroll
    for (int j = 0; j < 4; ++j) {
      const long col = n0 + wc * 64 + j * 16 + l15;
      const float bb = bias[col];
#pragma unroll
      for (int r = 0; r < 4; ++r) {
        const long idx = (row0 + r) * N + col;
        float v = acc[i][j][r] + bb;
        if (EPI == 0) out_bf[idx] = f2bf(v);
        else          out_f[idx] = resid[idx] + v;
      }
    }
  }
}

// ---------------- RoPE on Q, pre-scaled by 0.125*log2(e) ----------------
__global__ __launch_bounds__(256) void rope_q_kernel(const u16* __restrict__ qkv,
                                                     const float* __restrict__ cosT,
                                                     const float* __restrict__ sinT,
                                                     u16* __restrict__ Q) {
  int idx = blockIdx.x * 256 + threadIdx.x;  // B*H*S*8 = 524288 units of 8 elems
  int u = idx & 7;
  int s = (idx >> 3) & (S_LEN - 1);
  int bh = idx >> 14;
  int b = bh >> 4, h = bh & 15;
  int pos = PREV + s;
  const float SC = 0.125f * LOG2E;
  const u16* src = qkv + ((long)(b * S_LEN + s)) * (3 * DIM) + h * HD + u * 8;
  u32x4 d = *(const u32x4*)src;
  f32x4 cv = *(const f32x4*)&cosT[(long)pos * 32 + u * 4];
  f32x4 sv = *(const f32x4*)&sinT[(long)pos * 32 + u * 4];
  u32x4 o;
#pragma unroll
  for (int p = 0; p < 4; ++p) {
    float x0 = bf2f((u16)(d[p] & 0xffff));
    float x1 = bf2f((u16)(d[p] >> 16));
    float y0 = (x0 * cv[p] - x1 * sv[p]) * SC;
    float y1 = (x0 * sv[p] + x1 * cv[p]) * SC;
    o[p] = (u32)f2bf(y0) | ((u32)f2bf(y1) << 16);
  }
  *(u32x4*)&Q[((long)bh * S_LEN + s) * HD + u * 8] = o;
}

// ---------------- K_all = rope(concat(cache_k, k_new)); stored XOR-swizzled ----------------
__global__ __launch_bounds__(256) void rope_k_kernel(const u16* __restrict__ qkv,
                                                     const float* __restrict__ cache_k,
                                                     const float* __restrict__ cosT,
                                                     const float* __restrict__ sinT,
                                                     u16* __restrict__ Kall) {
  int idx = blockIdx.x * 256 + threadIdx.x;  // B*H*T*8 = 786432
  int u = idx & 7;
  int t2 = idx >> 3;
  int j = t2 % T_LEN;
  int bh = t2 / T_LEN;
  int b = bh >> 4, h = bh & 15;
  float e[8];
  if (j < PREV) {
    const float* src = cache_k + ((long)bh * PREV + j) * HD + u * 8;
    f32x4 a = *(const f32x4*)src;
    f32x4 c = *(const f32x4*)(src + 4);
    e[0] = a[0]; e[1] = a[1]; e[2] = a[2]; e[3] = a[3];
    e[4] = c[0]; e[5] = c[1]; e[6] = c[2]; e[7] = c[3];
  } else {
    const u16* src = qkv + ((long)(b * S_LEN + (j - PREV))) * (3 * DIM) + DIM + h * HD + u * 8;
    u32x4 d = *(const u32x4*)src;
#pragma unroll
    for (int p = 0; p < 4; ++p) {
      e[2 * p] = bf2f((u16)(d[p] & 0xffff));
      e[2 * p + 1] = bf2f((u16)(d[p] >> 16));
    }
  }
  f32x4 cv = *(const f32x4*)&cosT[(long)j * 32 + u * 4];
  f32x4 sv = *(const f32x4*)&sinT[(long)j * 32 + u * 4];
  u32x4 o;
#pragma unroll
  for (int p = 0; p < 4; ++p) {
    float y0 = e[2 * p] * cv[p] - e[2 * p + 1] * sv[p];
    float y1 = e[2 * p] * sv[p] + e[2 * p + 1] * cv[p];
    o[p] = (u32)f2bf(y0) | ((u32)f2bf(y1) << 16);
  }
  *(u32x4*)&Kall[((long)bh * T_LEN + j) * HD + (u ^ (j & 7)) * 8] = o;
}

// ---------------- Vt_global[bh][hd][key], XOR-swizzled within 64-key spans ----------------
__global__ __launch_bounds__(256) void build_vt_kernel(const u16* __restrict__ qkv,
                                                       const float* __restrict__ cache_v,
                                                       u16* __restrict__ Vtg) {
  int idx = blockIdx.x * 256 + threadIdx.x;  // 32 * 384 * 64 = 786432
  int hd = idx & 63;
  int t2 = idx >> 6;
  int kb = t2 % 384;  // 8-key block
  int bh = t2 / 384;
  int b = bh >> 4, h = bh & 15;
  int key0 = kb * 8;
  u16 vals[8];
  if (key0 < PREV) {
#pragma unroll
    for (int i = 0; i < 8; ++i)
      vals[i] = f2bf(cache_v[((long)bh * PREV + key0 + i) * HD + hd]);
  } else {
#pragma unroll
    for (int i = 0; i < 8; ++i)
      vals[i] = qkv[((long)(b * S_LEN + key0 + i - PREV)) * (3 * DIM) + 2 * DIM + h * HD + hd];
  }
  u32x4 o;
#pragma unroll
  for (int p = 0; p < 4; ++p)
    o[p] = (u32)vals[2 * p] | ((u32)vals[2 * p + 1] << 16);
  const int span = kb >> 3;
  const int u = (kb & 7) ^ (hd & 7);
  *(u32x4*)&Vtg[((long)bh * HD + hd) * T_LEN + span * 64 + u * 8] = o;
}

// ---------------- flash attention, swapped-operand, dbuf, 64 q / block ----------------
__global__ __launch_bounds__(256, 4) void attn_kernel(const u16* __restrict__ Q,
                                                      const u16* __restrict__ Kg,
                                                      const u16* __restrict__ Vtg,
                                                      u16* __restrict__ ctx, float slope2) {
  __shared__ __align__(16) u16 Ks[2][64 * 64];  // [key][d], swizzled
  __shared__ __align__(16) u16 Vs[2][64 * 64];  // [hd][key], swizzled
  __shared__ __align__(16) u16 Ps[4][16 * 64];  // per-wave P[q][key], swizzled

  const int tid = threadIdx.x;
  const int lane = tid & 63;
  const int wv = tid >> 6;
  const int l15 = lane & 15;
  const int lhi = lane >> 4;
  const int c7 = l15 & 7;
  const int bh = blockIdx.x;       // balance: co-resident blocks differ in qt
  const int qt = blockIdx.y;
  const int b = bh >> 4, h = bh & 15;
  const int q0 = qt * 64;
  const int nt = (PREV + q0 + 64) >> 6;

  const long qrow = (long)bh * S_LEN + q0 + wv * 16 + l15;
  bf16x8 aq0 = *(const bf16x8*)&Q[qrow * HD + lhi * 8];
  bf16x8 aq1 = *(const bf16x8*)&Q[qrow * HD + 32 + lhi * 8];

  const long kgb = (long)bh * T_LEN * HD;  // K: [key][64]
  const long vgb = (long)bh * HD * T_LEN;  // Vt: [hd][T]
  const int srow = tid >> 3;               // staging row 0..31
  const int sunit = (tid & 7) * 8;

  // prologue: stage tile 0
  gl_lds16(&Kg[kgb + (long)srow * HD + sunit], &Ks[0][tid * 8]);
  gl_lds16(&Kg[kgb + (long)(srow + 32) * HD + sunit], &Ks[0][2048 + tid * 8]);
  gl_lds16(&Vtg[vgb + (long)srow * T_LEN + sunit], &Vs[0][tid * 8]);
  gl_lds16(&Vtg[vgb + (long)(srow + 32) * T_LEN + sunit], &Vs[0][2048 + tid * 8]);
  __syncthreads();

  f32x4 o[4] = {};
  float mrun = -1e30f, lrun = 0.f;
  const int iabs = PREV + q0 + wv * 16 + l15;  // this lane's absolute q position
  u16* Pw = &Ps[wv][0];

  for (int t = 0; t < nt; ++t) {
    const int cur = t & 1, nxt = cur ^ 1;
    const int kt0 = t << 6;
    if (t + 1 < nt) {
      const int kn = kt0 + 64;
      gl_lds16(&Kg[kgb + (long)(kn + srow) * HD + sunit], &Ks[nxt][tid * 8]);
      gl_lds16(&Kg[kgb + (long)(kn + srow + 32) * HD + sunit], &Ks[nxt][2048 + tid * 8]);
      gl_lds16(&Vtg[vgb + (long)srow * T_LEN + kn + sunit], &Vs[nxt][tid * 8]);
      gl_lds16(&Vtg[vgb + (long)(srow + 32) * T_LEN + kn + sunit], &Vs[nxt][2048 + tid * 8]);
    }

    // S^T = K * Q^T : per wave [64 key][16 q]
    f32x4 sf[4];
    __builtin_amdgcn_s_setprio(1);
#pragma unroll
    for (int jf = 0; jf < 4; ++jf) {
      const int krow = jf * 16 + l15;
      bf16x8 ak0 = *(const bf16x8*)&Ks[cur][krow * 64 + ((lhi ^ c7) * 8)];
      bf16x8 ak1 = *(const bf16x8*)&Ks[cur][krow * 64 + (((4 + lhi) ^ c7) * 8)];
      f32x4 s = {};
      s = MFMA16(ak0, aq0, s, 0, 0, 0);
      s = MFMA16(ak1, aq1, s, 0, 0, 0);
      sf[jf] = s;
    }
    __builtin_amdgcn_s_setprio(0);

    // bias (+ causal mask on last tile), in log2 domain
    const bool masked = (t == nt - 1);
#pragma unroll
    for (int jf = 0; jf < 4; ++jf)
#pragma unroll
      for (int r = 0; r < 4; ++r) {
        const int jcol = kt0 + jf * 16 + 4 * lhi + r;  // key position
        float s_ = sf[jf][r] + slope2 * (float)(jcol - iabs);
        sf[jf][r] = (masked && jcol > iabs) ? -1e30f : s_;
      }

    // row max for q=l15 (in-lane tree + reduce over lhi groups)
    float t0 = fmaxf(fmaxf(sf[0][0], sf[0][1]), fmaxf(sf[0][2], sf[0][3]));
    float t1 = fmaxf(fmaxf(sf[1][0], sf[1][1]), fmaxf(sf[1][2], sf[1][3]));
    float t2 = fmaxf(fmaxf(sf[2][0], sf[2][1]), fmaxf(sf[2][2], sf[2][3]));
    float t3 = fmaxf(fmaxf(sf[3][0], sf[3][1]), fmaxf(sf[3][2], sf[3][3]));
    float pmax = fmaxf(fmaxf(t0, t1), fmaxf(t2, t3));
    pmax = fmaxf(pmax, __shfl_xor(pmax, 16, 64));
    pmax = fmaxf(pmax, __shfl_xor(pmax, 32, 64));

    // defer-max: rescale only when max grew past threshold (log2 units)
    if (!__all(pmax - mrun <= 8.f)) {
      float mnew = fmaxf(mrun, pmax);
      float scl = exp2f(mrun - mnew);
      mrun = mnew;
      lrun *= scl;
#pragma unroll
      for (int r = 0; r < 4; ++r) {
        float sr = __shfl(scl, 4 * lhi + r, 64);  // scale for q row 4*lhi+r
#pragma unroll
        for (int hf = 0; hf < 4; ++hf) o[hf][r] *= sr;
      }
    }

    // P = exp2(s - m), pack pairs, swizzled b64 writes to per-wave LDS
    float ps = 0.f;
#pragma unroll
    for (int jf = 0; jf < 4; ++jf) {
      f32x4 p;
#pragma unroll
      for (int r = 0; r < 4; ++r) {
        p[r] = exp2f(sf[jf][r] - mrun);
        ps += p[r];
      }
      u32x2 pw2;
      pw2[0] = cvtpk(p[0], p[1]);
      pw2[1] = cvtpk(p[2], p[3]);
      const int u = (2 * jf + (lhi >> 1)) ^ c7;
      *(u32x2*)&Pw[l15 * 64 + u * 8 + (lhi & 1) * 4] = pw2;
    }
    ps += __shfl_xor(ps, 16, 64);
    ps += __shfl_xor(ps, 32, 64);
    lrun += ps;

    // O += P * V  (A = P from LDS, B = Vt rows)
    bf16x8 pa0 = *(const bf16x8*)&Pw[l15 * 64 + ((lhi ^ c7) * 8)];
    bf16x8 pa1 = *(const bf16x8*)&Pw[l15 * 64 + (((4 + lhi) ^ c7) * 8)];
    __builtin_amdgcn_s_setprio(1);
#pragma unroll
    for (int hf = 0; hf < 4; ++hf) {
      const int vrow = hf * 16 + l15;
      bf16x8 bv0 = *(const bf16x8*)&Vs[cur][vrow * 64 + ((lhi ^ c7) * 8)];
      bf16x8 bv1 = *(const bf16x8*)&Vs[cur][vrow * 64 + (((4 + lhi) ^ c7) * 8)];
      o[hf] = MFMA16(pa0, bv0, o[hf], 0, 0, 0);
      o[hf] = MFMA16(pa1, bv1, o[hf], 0, 0, 0);
    }
    __builtin_amdgcn_s_setprio(0);
    __syncthreads();  // staged loads landed + all reads of cur done
  }

  // epilogue: O rows are q_local = 4*lhi + r; cols hd = hf*16 + l15
#pragma unroll
  for (int r = 0; r < 4; ++r) {
    const float inv = 1.f / __shfl(lrun, 4 * lhi + r, 64);
    const long srow_ = (long)b * S_LEN + q0 + wv * 16 + 4 * lhi + r;
#pragma unroll
    for (int hf = 0; hf < 4; ++hf)
      ctx[srow_ * DIM + h * HD + hf * 16 + l15] = f2bf(o[hf][r] * inv);
  }
}

// ---------------- gated = silu(g) * v ----------------
__global__ __launch_bounds__(256) void silu_mul_kernel(const u16* __restrict__ gv,
                                                       u16* __restrict__ out) {
  const int idx = blockIdx.x * 256 + threadIdx.x;  // 4096*512
  const int row = idx >> 9;
  const int c8 = (idx & 511) * 8;
  u32x4 g4 = *(const u32x4*)&gv[(long)row * (2 * FF) + c8];
  u32x4 v4 = *(const u32x4*)&gv[(long)row * (2 * FF) + FF + c8];
  u32x4 o;
#pragma unroll
  for (int p = 0; p < 4; ++p) {
    float g0 = bf2f((u16)(g4[p] & 0xffff)), g1 = bf2f((u16)(g4[p] >> 16));
    float w0 = bf2f((u16)(v4[p] & 0xffff)), w1 = bf2f((u16)(v4[p] >> 16));
    float s0 = g0 / (1.f + __expf(-g0)) * w0;
    float s1 = g1 / (1.f + __expf(-g1)) * w1;
    o[p] = (u32)f2bf(s0) | ((u32)f2bf(s1) << 16);
  }
  *(u32x4*)&out[(long)row * FF + c8] = o;
}

// ---------------------------------------------------------------------------
extern "C" void kernel_launch(void* const* d_in, const int* in_sizes, int n_in,
                              void* d_out, int out_size, void* d_ws, size_t ws_size,
                              hipStream_t stream) {
  (void)in_sizes; (void)n_in; (void)out_size; (void)ws_size;
  const float* x       = (const float*)d_in[0];
  const float* cache_k = (const float*)d_in[1];
  const float* cache_v = (const float*)d_in[2];
  const float* cosT    = (const float*)d_in[3];
  const float* sinT    = (const float*)d_in[4];
  const float* attn_w  = (const float*)d_in[5];
  const float* ffn_w   = (const float*)d_in[6];
  const float* wq      = (const float*)d_in[7];
  const float* bq      = (const float*)d_in[8];
  const float* wk      = (const float*)d_in[9];
  const float* bk      = (const float*)d_in[10];
  const float* wv_     = (const float*)d_in[11];
  const float* bv      = (const float*)d_in[12];
  const float* wo      = (const float*)d_in[13];
  const float* bo      = (const float*)d_in[14];
  const float* wg      = (const float*)d_in[15];
  const float* bg      = (const float*)d_in[16];
  const float* wval    = (const float*)d_in[17];
  const float* bval    = (const float*)d_in[18];
  const float* wp      = (const float*)d_in[19];
  const float* bp      = (const float*)d_in[20];
  float* out = (float*)d_out;

  char* w = (char*)d_ws;
  size_t off = 0;
  auto alloc = [&](size_t bytes) -> char* {
    char* p = w + off;
    off += (bytes + 255) & ~(size_t)255;
    return p;
  };
  // permanent
  u16*   wqkv_bf  = (u16*)alloc((size_t)3 * DIM * DIM * 2);
  u16*   wo_bf    = (u16*)alloc((size_t)DIM * DIM * 2);
  u16*   wgv_bf   = (u16*)alloc((size_t)2 * FF * DIM * 2);
  u16*   wproj_bf = (u16*)alloc((size_t)DIM * FF * 2);
  float* bqkv     = (float*)alloc((size_t)3 * DIM * 4);
  float* bgv      = (float*)alloc((size_t)2 * FF * 4);
  float* x2       = (float*)alloc((size_t)MROWS * DIM * 4);
  // arena with lifetime-based aliasing
  char* AR = alloc((size_t)117440512);
  u16* qkv   = (u16*)(AR + 0);          // [4096][3072]   live: qkv gemm -> rope/build
  u16* Qb    = (u16*)(AR + 25165824);   // [32][2048][64] live: rope -> attn
  u16* Kb    = (u16*)(AR + 33554432);   // [32][3072][64]
  u16* Vtg   = (u16*)(AR + 46137344);   // [32][64][3072] transposed V
  u16* h1    = (u16*)(AR + 58720256);   // [4096][1024]   live: rms1 -> qkv gemm
  u16* ctx   = (u16*)(AR + 0);          // [4096][1024]   (aliases dead qkv)
  u16* h2    = (u16*)(AR + 8388608);    // [4096][1024]
  u16* gvb   = (u16*)(AR + 16777216);   // [4096][8192]   (aliases dead Q/K/V/h1)
  u16* gated = (u16*)(AR + 83886080);   // [4096][4096]

  // 1) weights -> bf16 (+ fused bias packs)
  cvt_kernel<<<512, 256, 0, stream>>>(wq, wqkv_bf, DIM * DIM / 4);
  cvt_kernel<<<512, 256, 0, stream>>>(wk, wqkv_bf + DIM * DIM, DIM * DIM / 4);
  cvt_kernel<<<512, 256, 0, stream>>>(wv_, wqkv_bf + 2 * DIM * DIM, DIM * DIM / 4);
  cvt_kernel<<<512, 256, 0, stream>>>(wo, wo_bf, DIM * DIM / 4);
  cvt_kernel<<<1024, 256, 0, stream>>>(wg, wgv_bf, FF * DIM / 4);
  cvt_kernel<<<1024, 256, 0, stream>>>(wval, wgv_bf + (size_t)FF * DIM, FF * DIM / 4);
  cvt_kernel<<<1024, 256, 0, stream>>>(wp, wproj_bf, DIM * FF / 4);
  hipMemcpyAsync(bqkv, bq, DIM * 4, hipMemcpyDeviceToDevice, stream);
  hipMemcpyAsync(bqkv + DIM, bk, DIM * 4, hipMemcpyDeviceToDevice, stream);
  hipMemcpyAsync(bqkv + 2 * DIM, bv, DIM * 4, hipMemcpyDeviceToDevice, stream);
  hipMemcpyAsync(bgv, bg, FF * 4, hipMemcpyDeviceToDevice, stream);
  hipMemcpyAsync(bgv + FF, bval, FF * 4, hipMemcpyDeviceToDevice, stream);

  // 2) attn rmsnorm, fused QKV gemm
  rmsnorm_kernel<<<MROWS, 256, 0, stream>>>(x, attn_w, h1);
  gemm_bt<0><<<dim3(24, 32), 256, 0, stream>>>(h1, wqkv_bf, bqkv, nullptr, qkv, nullptr,
                                               3 * DIM, DIM);
  // 3) rope + cache concat
  rope_q_kernel<<<2048, 256, 0, stream>>>(qkv, cosT, sinT, Qb);
  rope_k_kernel<<<3072, 256, 0, stream>>>(qkv, cache_k, cosT, sinT, Kb);
  build_vt_kernel<<<3072, 256, 0, stream>>>(qkv, cache_v, Vtg);
  // 4) attention (grid: x=bh for CU load balance across qt)
  attn_kernel<<<dim3(B_SZ * NH, S_LEN / 64), 256, 0, stream>>>(
      Qb, Kb, Vtg, ctx, (2.0f / (float)(T_LEN - 1)) * LOG2E);
  // 5) o-proj + residual (fp32)
  gemm_bt<1><<<dim3(8, 32), 256, 0, stream>>>(ctx, wo_bf, bo, x, nullptr, x2, DIM, DIM);
  // 6) ffn rmsnorm, fused gate+value gemm, silu*v, proj + residual
  rmsnorm_kernel<<<MROWS, 256, 0, stream>>>(x2, ffn_w, h2);
  gemm_bt<0><<<dim3(64, 32), 256, 0, stream>>>(h2, wgv_bf, bgv, nullptr, gvb, nullptr,
                                               2 * FF, DIM);
  silu_mul_kernel<<<8192, 256, 0, stream>>>(gvb, gated);
  gemm_bt<1><<<dim3(8, 32), 256, 0, stream>>>(gated, wproj_bf, bp, x2, nullptr, out,
                                              DIM, FF);
}

// Round 3
// 405.208 us; speedup vs baseline: 1.3930x; 1.1524x over previous
//
#include <hip/hip_runtime.h>
#include <stdint.h>

typedef unsigned short u16;
typedef unsigned int   u32;
typedef __bf16 bf16x8 __attribute__((ext_vector_type(8)));
typedef float  f32x4  __attribute__((ext_vector_type(4)));
typedef u32    u32x4  __attribute__((ext_vector_type(4)));
typedef u32    u32x2  __attribute__((ext_vector_type(2)));

#define B_SZ  2
#define S_LEN 2048
#define NH    16
#define HD    64
#define DIM   1024
#define FF    4096
#define T_LEN 3072
#define PREV  1024
#define MROWS (B_SZ * S_LEN) /* 4096 */
#define LOG2E 1.44269504f

#define MFMA16 __builtin_amdgcn_mfma_f32_16x16x32_bf16

__device__ __forceinline__ u16 f2bf(float f) {
  u32 u = __builtin_bit_cast(u32, f);
  u32 r = u + 0x7FFFu + ((u >> 16) & 1u);
  return (u16)(r >> 16);
}
__device__ __forceinline__ float bf2f(u16 h) {
  u32 u = ((u32)h) << 16;
  return __builtin_bit_cast(float, u);
}
__device__ __forceinline__ u32 cvtpk(float lo, float hi) {
  u32 r;
  asm("v_cvt_pk_bf16_f32 %0, %1, %2" : "=v"(r) : "v"(lo), "v"(hi));
  return r;
}

// async global->LDS, 16B per lane. LDS dest must be wave-uniform base + lane*16.
__device__ __forceinline__ void gl_lds16(const void* g, void* l) {
  __builtin_amdgcn_global_load_lds(
      (const __attribute__((address_space(1))) u32*)g,
      (__attribute__((address_space(3))) u32*)l, 16, 0, 0);
}

// ---------------- fp32 -> bf16 convert (weights) ----------------
__global__ __launch_bounds__(256) void cvt_kernel(const float* __restrict__ src,
                                                  u16* __restrict__ dst, int n4) {
  int i = blockIdx.x * 256 + threadIdx.x;
  const int stride = gridDim.x * 256;
  for (; i < n4; i += stride) {
    f32x4 v = *(const f32x4*)&src[(long)i * 4];
    u32x2 o;
    o[0] = (u32)f2bf(v[0]) | ((u32)f2bf(v[1]) << 16);
    o[1] = (u32)f2bf(v[2]) | ((u32)f2bf(v[3]) << 16);
    *(u32x2*)&dst[(long)i * 4] = o;
  }
}

// interleave wg/wval rows: dst row 2j = wg[j], row 2j+1 = wval[j]  (bf16)
__global__ __launch_bounds__(256) void cvt_ilv_kernel(const float* __restrict__ wg,
                                                      const float* __restrict__ wval,
                                                      u16* __restrict__ dst) {
  int i = blockIdx.x * 256 + threadIdx.x;  // FF * DIM/4 = 1048576 units
  const int stride = gridDim.x * 256;
  const int upr = DIM / 4;  // 256 4-elem units per row
  for (; i < FF * upr; i += stride) {
    int j = i / upr;
    int c = (i - j * upr) * 4;
    f32x4 g = *(const f32x4*)&wg[(long)j * DIM + c];
    f32x4 v = *(const f32x4*)&wval[(long)j * DIM + c];
    u32x2 og, ov;
    og[0] = (u32)f2bf(g[0]) | ((u32)f2bf(g[1]) << 16);
    og[1] = (u32)f2bf(g[2]) | ((u32)f2bf(g[3]) << 16);
    ov[0] = (u32)f2bf(v[0]) | ((u32)f2bf(v[1]) << 16);
    ov[1] = (u32)f2bf(v[2]) | ((u32)f2bf(v[3]) << 16);
    *(u32x2*)&dst[((long)2 * j) * DIM + c] = og;
    *(u32x2*)&dst[((long)2 * j + 1) * DIM + c] = ov;
  }
}

// interleave biases: dst[2i]=bg[i], dst[2i+1]=bval[i]
__global__ __launch_bounds__(256) void bias_ilv_kernel(const float* __restrict__ bg,
                                                       const float* __restrict__ bval,
                                                       float* __restrict__ dst) {
  int i = blockIdx.x * 256 + threadIdx.x;
  if (i < FF) {
    dst[2 * i] = bg[i];
    dst[2 * i + 1] = bval[i];
  }
}

// ---------------- RMSNorm: fp32 row -> bf16 row ----------------
__global__ __launch_bounds__(256) void rmsnorm_kernel(const float* __restrict__ x,
                                                      const float* __restrict__ w,
                                                      u16* __restrict__ out) {
  const int row = blockIdx.x;
  const int tid = threadIdx.x;
  const long base = (long)row * DIM + tid * 4;
  f32x4 v = *(const f32x4*)&x[base];
  float ss = v[0] * v[0] + v[1] * v[1] + v[2] * v[2] + v[3] * v[3];
#pragma unroll
  for (int d = 1; d <= 32; d <<= 1) ss += __shfl_xor(ss, d, 64);
  __shared__ float red[4];
  if ((tid & 63) == 0) red[tid >> 6] = ss;
  __syncthreads();
  float tot = red[0] + red[1] + red[2] + red[3];
  const float sc = rsqrtf(tot * (1.f / (float)DIM) + 1e-6f);
  f32x4 wv4 = *(const f32x4*)&w[tid * 4];
  u32x2 o;
  o[0] = (u32)f2bf(v[0] * sc * wv4[0]) | ((u32)f2bf(v[1] * sc * wv4[1]) << 16);
  o[1] = (u32)f2bf(v[2] * sc * wv4[2]) | ((u32)f2bf(v[3] * sc * wv4[3]) << 16);
  *(u32x2*)&out[base] = o;
}

// ---------------- GEMM: C[M,N] = A[M,K](bf16) * Bw[N,K]^T(bf16) + bias ----------------
// 2-phase double-buffered (T3-minimum): stage(t+1) -> ds_read+MFMA(t) -> 1 barrier.
// EPI 0: bf16 store. EPI 1: fp32 resid+acc. EPI 2: silu-mul on interleaved g/v cols,
//        bf16 store to N/2-wide output.
template <int EPI>
__global__ __launch_bounds__(256) void gemm_bt(const u16* __restrict__ A,
                                               const u16* __restrict__ Bw,
                                               const float* __restrict__ bias,
                                               const float* __restrict__ resid,
                                               u16* __restrict__ out_bf,
                                               float* __restrict__ out_f,
                                               int N, int K) {
  __shared__ __align__(16) u16 As[2][128 * 32];
  __shared__ __align__(16) u16 Bs[2][128 * 32];
  const int tid = threadIdx.x;
  const int lane = tid & 63;
  const int wv = tid >> 6;
  const int wr = wv >> 1, wc = wv & 1;
  const long m0 = (long)blockIdx.y * 128;
  const long n0 = (long)blockIdx.x * 128;

  const int arow = tid >> 2;
  const int acol = (tid & 3) << 3;
  const u16* ag = A + (m0 + arow) * K + acol;
  const u16* bg = Bw + (n0 + arow) * K + acol;
  const long hK = (long)64 * K;

  f32x4 acc[4][4] = {};
  const int l15 = lane & 15;
  const int lhi = lane >> 4;
  const int aoff0 = (wr * 64 + l15) * 32 + lhi * 8;
  const int boff0 = (wc * 64 + l15) * 32 + lhi * 8;
  const int nk = K >> 5;

  // prologue: stage tile 0 into buf 0
  gl_lds16(ag, &As[0][tid * 8]);
  gl_lds16(ag + hK, &As[0][2048 + tid * 8]);
  gl_lds16(bg, &Bs[0][tid * 8]);
  gl_lds16(bg + hK, &Bs[0][2048 + tid * 8]);
  __syncthreads();

  for (int t = 0; t < nk; ++t) {
    const int cur = t & 1, nxt = cur ^ 1;
    if (t + 1 < nk) {
      const int k1 = (t + 1) << 5;
      gl_lds16(ag + k1, &As[nxt][tid * 8]);
      gl_lds16(ag + k1 + hK, &As[nxt][2048 + tid * 8]);
      gl_lds16(bg + k1, &Bs[nxt][tid * 8]);
      gl_lds16(bg + k1 + hK, &Bs[nxt][2048 + tid * 8]);
    }
    bf16x8 af[4], bfr[4];
#pragma unroll
    for (int i = 0; i < 4; ++i) af[i] = *(const bf16x8*)&As[cur][aoff0 + i * 16 * 32];
#pragma unroll
    for (int j = 0; j < 4; ++j) bfr[j] = *(const bf16x8*)&Bs[cur][boff0 + j * 16 * 32];
    __builtin_amdgcn_s_setprio(1);
#pragma unroll
    for (int i = 0; i < 4; ++i)
#pragma unroll
      for (int j = 0; j < 4; ++j)
        acc[i][j] = MFMA16(af[i], bfr[j], acc[i][j], 0, 0, 0);
    __builtin_amdgcn_s_setprio(0);
    __syncthreads();  // drains staged loads for nxt; fences reads of cur
  }

#pragma unroll
  for (int i = 0; i < 4; ++i) {
    const long row0 = m0 + wr * 64 + i * 16 + lhi * 4;
#pragma unroll
    for (int j = 0; j < 4; ++j) {
      const long col = n0 + wc * 64 + j * 16 + l15;
      const float bb = bias[col];
#pragma unroll
      for (int r = 0; r < 4; ++r) {
        float v = acc[i][j][r] + bb;
        if (EPI == 2) {
          float other = __shfl_xor(v, 1, 64);
          if (!(l15 & 1)) {
            float s = v / (1.f + __expf(-v)) * other;  // silu(g)*v
            out_bf[(row0 + r) * (N >> 1) + (col >> 1)] = f2bf(s);
          }
        } else {
          const long idx = (row0 + r) * N + col;
          if (EPI == 0) out_bf[idx] = f2bf(v);
          else          out_f[idx] = resid[idx] + v;
        }
      }
    }
  }
}

// ---------------- RoPE on Q, pre-scaled by 0.125*log2(e) ----------------
__global__ __launch_bounds__(256) void rope_q_kernel(const u16* __restrict__ qkv,
                                                     const float* __restrict__ cosT,
                                                     const float* __restrict__ sinT,
                                                     u16* __restrict__ Q) {
  int idx = blockIdx.x * 256 + threadIdx.x;  // B*H*S*8 = 524288 units of 8 elems
  int u = idx & 7;
  int s = (idx >> 3) & (S_LEN - 1);
  int bh = idx >> 14;
  int b = bh >> 4, h = bh & 15;
  int pos = PREV + s;
  const float SC = 0.125f * LOG2E;
  const u16* src = qkv + ((long)(b * S_LEN + s)) * (3 * DIM) + h * HD + u * 8;
  u32x4 d = *(const u32x4*)src;
  f32x4 cv = *(const f32x4*)&cosT[(long)pos * 32 + u * 4];
  f32x4 sv = *(const f32x4*)&sinT[(long)pos * 32 + u * 4];
  u32x4 o;
#pragma unroll
  for (int p = 0; p < 4; ++p) {
    float x0 = bf2f((u16)(d[p] & 0xffff));
    float x1 = bf2f((u16)(d[p] >> 16));
    float y0 = (x0 * cv[p] - x1 * sv[p]) * SC;
    float y1 = (x0 * sv[p] + x1 * cv[p]) * SC;
    o[p] = (u32)f2bf(y0) | ((u32)f2bf(y1) << 16);
  }
  *(u32x4*)&Q[((long)bh * S_LEN + s) * HD + u * 8] = o;
}

// ---------------- K_all = rope(concat(cache_k, k_new)); stored XOR-swizzled ----------------
__global__ __launch_bounds__(256) void rope_k_kernel(const u16* __restrict__ qkv,
                                                     const float* __restrict__ cache_k,
                                                     const float* __restrict__ cosT,
                                                     const float* __restrict__ sinT,
                                                     u16* __restrict__ Kall) {
  int idx = blockIdx.x * 256 + threadIdx.x;  // B*H*T*8 = 786432
  int u = idx & 7;
  int t2 = idx >> 3;
  int j = t2 % T_LEN;
  int bh = t2 / T_LEN;
  int b = bh >> 4, h = bh & 15;
  float e[8];
  if (j < PREV) {
    const float* src = cache_k + ((long)bh * PREV + j) * HD + u * 8;
    f32x4 a = *(const f32x4*)src;
    f32x4 c = *(const f32x4*)(src + 4);
    e[0] = a[0]; e[1] = a[1]; e[2] = a[2]; e[3] = a[3];
    e[4] = c[0]; e[5] = c[1]; e[6] = c[2]; e[7] = c[3];
  } else {
    const u16* src = qkv + ((long)(b * S_LEN + (j - PREV))) * (3 * DIM) + DIM + h * HD + u * 8;
    u32x4 d = *(const u32x4*)src;
#pragma unroll
    for (int p = 0; p < 4; ++p) {
      e[2 * p] = bf2f((u16)(d[p] & 0xffff));
      e[2 * p + 1] = bf2f((u16)(d[p] >> 16));
    }
  }
  f32x4 cv = *(const f32x4*)&cosT[(long)j * 32 + u * 4];
  f32x4 sv = *(const f32x4*)&sinT[(long)j * 32 + u * 4];
  u32x4 o;
#pragma unroll
  for (int p = 0; p < 4; ++p) {
    float y0 = e[2 * p] * cv[p] - e[2 * p + 1] * sv[p];
    float y1 = e[2 * p] * sv[p] + e[2 * p + 1] * cv[p];
    o[p] = (u32)f2bf(y0) | ((u32)f2bf(y1) << 16);
  }
  *(u32x4*)&Kall[((long)bh * T_LEN + j) * HD + (u ^ (j & 7)) * 8] = o;
}

// ---------------- Vt_global[bh][hd][key], XOR-swizzled within 64-key spans ----------------
__global__ __launch_bounds__(256) void build_vt_kernel(const u16* __restrict__ qkv,
                                                       const float* __restrict__ cache_v,
                                                       u16* __restrict__ Vtg) {
  int idx = blockIdx.x * 256 + threadIdx.x;  // 32 * 384 * 64 = 786432
  int hd = idx & 63;
  int t2 = idx >> 6;
  int kb = t2 % 384;  // 8-key block
  int bh = t2 / 384;
  int b = bh >> 4, h = bh & 15;
  int key0 = kb * 8;
  u16 vals[8];
  if (key0 < PREV) {
#pragma unroll
    for (int i = 0; i < 8; ++i)
      vals[i] = f2bf(cache_v[((long)bh * PREV + key0 + i) * HD + hd]);
  } else {
#pragma unroll
    for (int i = 0; i < 8; ++i)
      vals[i] = qkv[((long)(b * S_LEN + key0 + i - PREV)) * (3 * DIM) + 2 * DIM + h * HD + hd];
  }
  u32x4 o;
#pragma unroll
  for (int p = 0; p < 4; ++p)
    o[p] = (u32)vals[2 * p] | ((u32)vals[2 * p + 1] << 16);
  const int span = kb >> 3;
  const int u = (kb & 7) ^ (hd & 7);
  *(u32x4*)&Vtg[((long)bh * HD + hd) * T_LEN + span * 64 + u * 8] = o;
}

// ---------------- flash attention, swapped-operand, dbuf, 64 q / block ----------------
__global__ __launch_bounds__(256, 4) void attn_kernel(const u16* __restrict__ Q,
                                                      const u16* __restrict__ Kg,
                                                      const u16* __restrict__ Vtg,
                                                      u16* __restrict__ ctx, float slope2) {
  __shared__ __align__(16) u16 Ks[2][64 * 64];  // [key][d], swizzled
  __shared__ __align__(16) u16 Vs[2][64 * 64];  // [hd][key], swizzled
  __shared__ __align__(16) u16 Ps[4][16 * 64];  // per-wave P[q][key], swizzled

  const int tid = threadIdx.x;
  const int lane = tid & 63;
  const int wv = tid >> 6;
  const int l15 = lane & 15;
  const int lhi = lane >> 4;
  const int c7 = l15 & 7;
  const int bh = blockIdx.x;       // balance: co-resident blocks differ in qt
  const int qt = blockIdx.y;
  const int b = bh >> 4, h = bh & 15;
  const int q0 = qt * 64;
  const int nt = (PREV + q0 + 64) >> 6;

  const long qrow = (long)bh * S_LEN + q0 + wv * 16 + l15;
  bf16x8 aq0 = *(const bf16x8*)&Q[qrow * HD + lhi * 8];
  bf16x8 aq1 = *(const bf16x8*)&Q[qrow * HD + 32 + lhi * 8];

  const long kgb = (long)bh * T_LEN * HD;  // K: [key][64]
  const long vgb = (long)bh * HD * T_LEN;  // Vt: [hd][T]
  const int srow = tid >> 3;               // staging row 0..31
  const int sunit = (tid & 7) * 8;

  // prologue: stage tile 0
  gl_lds16(&Kg[kgb + (long)srow * HD + sunit], &Ks[0][tid * 8]);
  gl_lds16(&Kg[kgb + (long)(srow + 32) * HD + sunit], &Ks[0][2048 + tid * 8]);
  gl_lds16(&Vtg[vgb + (long)srow * T_LEN + sunit], &Vs[0][tid * 8]);
  gl_lds16(&Vtg[vgb + (long)(srow + 32) * T_LEN + sunit], &Vs[0][2048 + tid * 8]);
  __syncthreads();

  f32x4 o[4] = {};
  float mrun = -1e30f, lrun = 0.f;
  const int iabs = PREV + q0 + wv * 16 + l15;  // this lane's absolute q position
  u16* Pw = &Ps[wv][0];

  for (int t = 0; t < nt; ++t) {
    const int cur = t & 1, nxt = cur ^ 1;
    const int kt0 = t << 6;
    if (t + 1 < nt) {
      const int kn = kt0 + 64;
      gl_lds16(&Kg[kgb + (long)(kn + srow) * HD + sunit], &Ks[nxt][tid * 8]);
      gl_lds16(&Kg[kgb + (long)(kn + srow + 32) * HD + sunit], &Ks[nxt][2048 + tid * 8]);
      gl_lds16(&Vtg[vgb + (long)srow * T_LEN + kn + sunit], &Vs[nxt][tid * 8]);
      gl_lds16(&Vtg[vgb + (long)(srow + 32) * T_LEN + kn + sunit], &Vs[nxt][2048 + tid * 8]);
    }

    // S^T = K * Q^T : per wave [64 key][16 q]
    f32x4 sf[4];
    __builtin_amdgcn_s_setprio(1);
#pragma unroll
    for (int jf = 0; jf < 4; ++jf) {
      const int krow = jf * 16 + l15;
      bf16x8 ak0 = *(const bf16x8*)&Ks[cur][krow * 64 + ((lhi ^ c7) * 8)];
      bf16x8 ak1 = *(const bf16x8*)&Ks[cur][krow * 64 + (((4 + lhi) ^ c7) * 8)];
      f32x4 s = {};
      s = MFMA16(ak0, aq0, s, 0, 0, 0);
      s = MFMA16(ak1, aq1, s, 0, 0, 0);
      sf[jf] = s;
    }
    __builtin_amdgcn_s_setprio(0);

    // bias (+ causal mask on last tile), in log2 domain
    const bool masked = (t == nt - 1);
#pragma unroll
    for (int jf = 0; jf < 4; ++jf)
#pragma unroll
      for (int r = 0; r < 4; ++r) {
        const int jcol = kt0 + jf * 16 + 4 * lhi + r;  // key position
        float s_ = sf[jf][r] + slope2 * (float)(jcol - iabs);
        sf[jf][r] = (masked && jcol > iabs) ? -1e30f : s_;
      }

    // row max for q=l15 (in-lane tree + reduce over lhi groups)
    float t0 = fmaxf(fmaxf(sf[0][0], sf[0][1]), fmaxf(sf[0][2], sf[0][3]));
    float t1 = fmaxf(fmaxf(sf[1][0], sf[1][1]), fmaxf(sf[1][2], sf[1][3]));
    float t2 = fmaxf(fmaxf(sf[2][0], sf[2][1]), fmaxf(sf[2][2], sf[2][3]));
    float t3 = fmaxf(fmaxf(sf[3][0], sf[3][1]), fmaxf(sf[3][2], sf[3][3]));
    float pmax = fmaxf(fmaxf(t0, t1), fmaxf(t2, t3));
    pmax = fmaxf(pmax, __shfl_xor(pmax, 16, 64));
    pmax = fmaxf(pmax, __shfl_xor(pmax, 32, 64));

    // defer-max: rescale only when max grew past threshold (log2 units)
    if (!__all(pmax - mrun <= 8.f)) {
      float mnew = fmaxf(mrun, pmax);
      float scl = exp2f(mrun - mnew);
      mrun = mnew;
      lrun *= scl;
#pragma unroll
      for (int r = 0; r < 4; ++r) {
        float sr = __shfl(scl, 4 * lhi + r, 64);  // scale for q row 4*lhi+r
#pragma unroll
        for (int hf = 0; hf < 4; ++hf) o[hf][r] *= sr;
      }
    }

    // P = exp2(s - m), pack pairs, swizzled b64 writes to per-wave LDS
    float ps = 0.f;
#pragma unroll
    for (int jf = 0; jf < 4; ++jf) {
      f32x4 p;
#pragma unroll
      for (int r = 0; r < 4; ++r) {
        p[r] = exp2f(sf[jf][r] - mrun);
        ps += p[r];
      }
      u32x2 pw2;
      pw2[0] = cvtpk(p[0], p[1]);
      pw2[1] = cvtpk(p[2], p[3]);
      const int u = (2 * jf + (lhi >> 1)) ^ c7;
      *(u32x2*)&Pw[l15 * 64 + u * 8 + (lhi & 1) * 4] = pw2;
    }
    ps += __shfl_xor(ps, 16, 64);
    ps += __shfl_xor(ps, 32, 64);
    lrun += ps;

    // O += P * V  (A = P from LDS, B = Vt rows)
    bf16x8 pa0 = *(const bf16x8*)&Pw[l15 * 64 + ((lhi ^ c7) * 8)];
    bf16x8 pa1 = *(const bf16x8*)&Pw[l15 * 64 + (((4 + lhi) ^ c7) * 8)];
    __builtin_amdgcn_s_setprio(1);
#pragma unroll
    for (int hf = 0; hf < 4; ++hf) {
      const int vrow = hf * 16 + l15;
      bf16x8 bv0 = *(const bf16x8*)&Vs[cur][vrow * 64 + ((lhi ^ c7) * 8)];
      bf16x8 bv1 = *(const bf16x8*)&Vs[cur][vrow * 64 + (((4 + lhi) ^ c7) * 8)];
      o[hf] = MFMA16(pa0, bv0, o[hf], 0, 0, 0);
      o[hf] = MFMA16(pa1, bv1, o[hf], 0, 0, 0);
    }
    __builtin_amdgcn_s_setprio(0);
    __syncthreads();  // staged loads landed + all reads of cur done
  }

  // epilogue: O rows are q_local = 4*lhi + r; cols hd = hf*16 + l15
#pragma unroll
  for (int r = 0; r < 4; ++r) {
    const float inv = 1.f / __shfl(lrun, 4 * lhi + r, 64);
    const long srow_ = (long)b * S_LEN + q0 + wv * 16 + 4 * lhi + r;
#pragma unroll
    for (int hf = 0; hf < 4; ++hf)
      ctx[srow_ * DIM + h * HD + hf * 16 + l15] = f2bf(o[hf][r] * inv);
  }
}

// ---------------------------------------------------------------------------
extern "C" void kernel_launch(void* const* d_in, const int* in_sizes, int n_in,
                              void* d_out, int out_size, void* d_ws, size_t ws_size,
                              hipStream_t stream) {
  (void)in_sizes; (void)n_in; (void)out_size; (void)ws_size;
  const float* x       = (const float*)d_in[0];
  const float* cache_k = (const float*)d_in[1];
  const float* cache_v = (const float*)d_in[2];
  const float* cosT    = (const float*)d_in[3];
  const float* sinT    = (const float*)d_in[4];
  const float* attn_w  = (const float*)d_in[5];
  const float* ffn_w   = (const float*)d_in[6];
  const float* wq      = (const float*)d_in[7];
  const float* bq      = (const float*)d_in[8];
  const float* wk      = (const float*)d_in[9];
  const float* bk      = (const float*)d_in[10];
  const float* wv_     = (const float*)d_in[11];
  const float* bv      = (const float*)d_in[12];
  const float* wo      = (const float*)d_in[13];
  const float* bo      = (const float*)d_in[14];
  const float* wg      = (const float*)d_in[15];
  const float* bg      = (const float*)d_in[16];
  const float* wval    = (const float*)d_in[17];
  const float* bval    = (const float*)d_in[18];
  const float* wp      = (const float*)d_in[19];
  const float* bp      = (const float*)d_in[20];
  float* out = (float*)d_out;

  char* w = (char*)d_ws;
  size_t off = 0;
  auto alloc = [&](size_t bytes) -> char* {
    char* p = w + off;
    off += (bytes + 255) & ~(size_t)255;
    return p;
  };
  // permanent
  u16*   wqkv_bf  = (u16*)alloc((size_t)3 * DIM * DIM * 2);
  u16*   wo_bf    = (u16*)alloc((size_t)DIM * DIM * 2);
  u16*   wgv_bf   = (u16*)alloc((size_t)2 * FF * DIM * 2);  // interleaved g/v rows
  u16*   wproj_bf = (u16*)alloc((size_t)DIM * FF * 2);
  float* bqkv     = (float*)alloc((size_t)3 * DIM * 4);
  float* bgv      = (float*)alloc((size_t)2 * FF * 4);      // interleaved
  float* x2       = (float*)alloc((size_t)MROWS * DIM * 4);
  // arena with lifetime-based aliasing
  char* AR = alloc((size_t)117440512);
  u16* qkv   = (u16*)(AR + 0);          // [4096][3072]   live: qkv gemm -> rope/build
  u16* Qb    = (u16*)(AR + 25165824);   // [32][2048][64] live: rope -> attn
  u16* Kb    = (u16*)(AR + 33554432);   // [32][3072][64]
  u16* Vtg   = (u16*)(AR + 46137344);   // [32][64][3072] transposed V
  u16* h1    = (u16*)(AR + 58720256);   // [4096][1024]   live: rms1 -> qkv gemm
  u16* ctx   = (u16*)(AR + 0);          // [4096][1024]   (aliases dead qkv)
  u16* h2    = (u16*)(AR + 8388608);    // [4096][1024]
  u16* gated = (u16*)(AR + 16777216);   // [4096][4096]   (aliases dead Qb/Kb region)

  // 1) weights -> bf16 (+ fused bias packs)
  cvt_kernel<<<512, 256, 0, stream>>>(wq, wqkv_bf, DIM * DIM / 4);
  cvt_kernel<<<512, 256, 0, stream>>>(wk, wqkv_bf + DIM * DIM, DIM * DIM / 4);
  cvt_kernel<<<512, 256, 0, stream>>>(wv_, wqkv_bf + 2 * DIM * DIM, DIM * DIM / 4);
  cvt_kernel<<<512, 256, 0, stream>>>(wo, wo_bf, DIM * DIM / 4);
  cvt_ilv_kernel<<<1024, 256, 0, stream>>>(wg, wval, wgv_bf);
  cvt_kernel<<<1024, 256, 0, stream>>>(wp, wproj_bf, DIM * FF / 4);
  bias_ilv_kernel<<<16, 256, 0, stream>>>(bg, bval, bgv);
  hipMemcpyAsync(bqkv, bq, DIM * 4, hipMemcpyDeviceToDevice, stream);
  hipMemcpyAsync(bqkv + DIM, bk, DIM * 4, hipMemcpyDeviceToDevice, stream);
  hipMemcpyAsync(bqkv + 2 * DIM, bv, DIM * 4, hipMemcpyDeviceToDevice, stream);

  // 2) attn rmsnorm, fused QKV gemm
  rmsnorm_kernel<<<MROWS, 256, 0, stream>>>(x, attn_w, h1);
  gemm_bt<0><<<dim3(24, 32), 256, 0, stream>>>(h1, wqkv_bf, bqkv, nullptr, qkv, nullptr,
                                               3 * DIM, DIM);
  // 3) rope + cache concat
  rope_q_kernel<<<2048, 256, 0, stream>>>(qkv, cosT, sinT, Qb);
  rope_k_kernel<<<3072, 256, 0, stream>>>(qkv, cache_k, cosT, sinT, Kb);
  build_vt_kernel<<<3072, 256, 0, stream>>>(qkv, cache_v, Vtg);
  // 4) attention (grid: x=bh for CU load balance across qt)
  attn_kernel<<<dim3(B_SZ * NH, S_LEN / 64), 256, 0, stream>>>(
      Qb, Kb, Vtg, ctx, (2.0f / (float)(T_LEN - 1)) * LOG2E);
  // 5) o-proj + residual (fp32)
  gemm_bt<1><<<dim3(8, 32), 256, 0, stream>>>(ctx, wo_bf, bo, x, nullptr, x2, DIM, DIM);
  // 6) ffn rmsnorm, fused gate+value gemm w/ silu epilogue, proj + residual
  rmsnorm_kernel<<<MROWS, 256, 0, stream>>>(x2, ffn_w, h2);
  gemm_bt<2><<<dim3(64, 32), 256, 0, stream>>>(h2, wgv_bf, bgv, nullptr, gated, nullptr,
                                               2 * FF, DIM);
  gemm_bt<1><<<dim3(8, 32), 256, 0, stream>>>(gated, wproj_bf, bp, x2, nullptr, out,
                                              DIM, FF);
}

// Round 4
// 397.673 us; speedup vs baseline: 1.4194x; 1.0189x over previous
//
#include <hip/hip_runtime.h>
#include <stdint.h>

typedef unsigned short u16;
typedef unsigned int   u32;
typedef __bf16 bf16x8 __attribute__((ext_vector_type(8)));
typedef float  f32x4  __attribute__((ext_vector_type(4)));
typedef u32    u32x4  __attribute__((ext_vector_type(4)));
typedef u32    u32x2  __attribute__((ext_vector_type(2)));

#define B_SZ  2
#define S_LEN 2048
#define NH    16
#define HD    64
#define DIM   1024
#define FF    4096
#define T_LEN 3072
#define PREV  1024
#define MROWS (B_SZ * S_LEN) /* 4096 */
#define LOG2E 1.44269504f

#define MFMA16 __builtin_amdgcn_mfma_f32_16x16x32_bf16

__device__ __forceinline__ u16 f2bf(float f) {
  u32 u = __builtin_bit_cast(u32, f);
  u32 r = u + 0x7FFFu + ((u >> 16) & 1u);
  return (u16)(r >> 16);
}
__device__ __forceinline__ float bf2f(u16 h) {
  u32 u = ((u32)h) << 16;
  return __builtin_bit_cast(float, u);
}
__device__ __forceinline__ u32 cvtpk(float lo, float hi) {
  u32 r;
  asm("v_cvt_pk_bf16_f32 %0, %1, %2" : "=v"(r) : "v"(lo), "v"(hi));
  return r;
}

// async global->LDS, 16B per lane. LDS dest must be wave-uniform base + lane*16.
__device__ __forceinline__ void gl_lds16(const void* g, void* l) {
  __builtin_amdgcn_global_load_lds(
      (const __attribute__((address_space(1))) u32*)g,
      (__attribute__((address_space(3))) u32*)l, 16, 0, 0);
}

// ---------------- fp32 -> bf16 convert (weights) ----------------
__global__ __launch_bounds__(256) void cvt_kernel(const float* __restrict__ src,
                                                  u16* __restrict__ dst, int n4) {
  int i = blockIdx.x * 256 + threadIdx.x;
  const int stride = gridDim.x * 256;
  for (; i < n4; i += stride) {
    f32x4 v = *(const f32x4*)&src[(long)i * 4];
    u32x2 o;
    o[0] = (u32)f2bf(v[0]) | ((u32)f2bf(v[1]) << 16);
    o[1] = (u32)f2bf(v[2]) | ((u32)f2bf(v[3]) << 16);
    *(u32x2*)&dst[(long)i * 4] = o;
  }
}

// interleave wg/wval rows: dst row 2j = wg[j], row 2j+1 = wval[j]  (bf16)
__global__ __launch_bounds__(256) void cvt_ilv_kernel(const float* __restrict__ wg,
                                                      const float* __restrict__ wval,
                                                      u16* __restrict__ dst) {
  int i = blockIdx.x * 256 + threadIdx.x;  // FF * DIM/4 = 1048576 units
  const int stride = gridDim.x * 256;
  const int upr = DIM / 4;  // 256 4-elem units per row
  for (; i < FF * upr; i += stride) {
    int j = i / upr;
    int c = (i - j * upr) * 4;
    f32x4 g = *(const f32x4*)&wg[(long)j * DIM + c];
    f32x4 v = *(const f32x4*)&wval[(long)j * DIM + c];
    u32x2 og, ov;
    og[0] = (u32)f2bf(g[0]) | ((u32)f2bf(g[1]) << 16);
    og[1] = (u32)f2bf(g[2]) | ((u32)f2bf(g[3]) << 16);
    ov[0] = (u32)f2bf(v[0]) | ((u32)f2bf(v[1]) << 16);
    ov[1] = (u32)f2bf(v[2]) | ((u32)f2bf(v[3]) << 16);
    *(u32x2*)&dst[((long)2 * j) * DIM + c] = og;
    *(u32x2*)&dst[((long)2 * j + 1) * DIM + c] = ov;
  }
}

// interleave biases: dst[2i]=bg[i], dst[2i+1]=bval[i]
__global__ __launch_bounds__(256) void bias_ilv_kernel(const float* __restrict__ bg,
                                                       const float* __restrict__ bval,
                                                       float* __restrict__ dst) {
  int i = blockIdx.x * 256 + threadIdx.x;
  if (i < FF) {
    dst[2 * i] = bg[i];
    dst[2 * i + 1] = bval[i];
  }
}

// ---------------- RMSNorm: fp32 row -> bf16 row ----------------
__global__ __launch_bounds__(256) void rmsnorm_kernel(const float* __restrict__ x,
                                                      const float* __restrict__ w,
                                                      u16* __restrict__ out) {
  const int row = blockIdx.x;
  const int tid = threadIdx.x;
  const long base = (long)row * DIM + tid * 4;
  f32x4 v = *(const f32x4*)&x[base];
  float ss = v[0] * v[0] + v[1] * v[1] + v[2] * v[2] + v[3] * v[3];
#pragma unroll
  for (int d = 1; d <= 32; d <<= 1) ss += __shfl_xor(ss, d, 64);
  __shared__ float red[4];
  if ((tid & 63) == 0) red[tid >> 6] = ss;
  __syncthreads();
  float tot = red[0] + red[1] + red[2] + red[3];
  const float sc = rsqrtf(tot * (1.f / (float)DIM) + 1e-6f);
  f32x4 wv4 = *(const f32x4*)&w[tid * 4];
  u32x2 o;
  o[0] = (u32)f2bf(v[0] * sc * wv4[0]) | ((u32)f2bf(v[1] * sc * wv4[1]) << 16);
  o[1] = (u32)f2bf(v[2] * sc * wv4[2]) | ((u32)f2bf(v[3] * sc * wv4[3]) << 16);
  *(u32x2*)&out[base] = o;
}

// ---------------- GEMM: C[M,N] = A[M,K](bf16) * Bw[N,K]^T(bf16) + bias ----------------
// 3-buffer pipeline, counted vmcnt (T4): prefetch distance 2, loads never drain to 0
// in steady state. Raw s_barrier + asm vmcnt; memory-clobber fences per rule #18.
// EPI 0: bf16 store. EPI 1: fp32 resid+acc. EPI 2: silu-mul interleaved g/v -> bf16.
// NB: 128 (2x2 waves of 64x64) or 64 (2x2 waves of 64x32).
template <int EPI, int NB>
__global__ __launch_bounds__(256) void gemm_bt(const u16* __restrict__ A,
                                               const u16* __restrict__ Bw,
                                               const float* __restrict__ bias,
                                               const float* __restrict__ resid,
                                               u16* __restrict__ out_bf,
                                               float* __restrict__ out_f,
                                               int N, int K) {
  constexpr int BHALF = NB / 64;   // B 64-row halves per tile: 2 or 1
  constexpr int NFR = NB / 32;     // N frags per wave: 4 or 2
  constexpr int LPT = 2 + BHALF;   // global_load_lds per tile: 4 or 3
  __shared__ __align__(16) u16 As[3][128 * 32];
  __shared__ __align__(16) u16 Bs[3][NB * 32];
  const int tid = threadIdx.x;
  const int lane = tid & 63;
  const int wv = tid >> 6;
  const int wr = wv >> 1, wc = wv & 1;
  const long m0 = (long)blockIdx.y * 128;
  const long n0 = (long)blockIdx.x * NB;

  const int arow = tid >> 2;
  const int acol = (tid & 3) << 3;
  const u16* ag = A + (m0 + arow) * K + acol;
  const u16* bg = Bw + (n0 + arow) * K + acol;
  const long hK = (long)64 * K;

  f32x4 acc[4][NFR] = {};
  const int l15 = lane & 15;
  const int lhi = lane >> 4;
  const int aoff0 = (wr * 64 + l15) * 32 + lhi * 8;
  const int boff0 = (wc * (NB / 2) + l15) * 32 + lhi * 8;
  const int nk = K >> 5;

  auto stage = [&](int t, int buf) {
    const int k0 = t << 5;
    gl_lds16(ag + k0, &As[buf][tid * 8]);
    gl_lds16(ag + k0 + hK, &As[buf][2048 + tid * 8]);
    gl_lds16(bg + k0, &Bs[buf][tid * 8]);
    if (BHALF == 2) gl_lds16(bg + k0 + hK, &Bs[buf][2048 + tid * 8]);
  };

  // prologue: tiles 0 and 1 in flight; wait tile 0 (allow tile 1 outstanding)
  stage(0, 0);
  stage(1, 1);
  asm volatile("s_waitcnt vmcnt(%0)" ::"n"(LPT) : "memory");
  __builtin_amdgcn_s_barrier();
  asm volatile("" ::: "memory");
  __builtin_amdgcn_sched_barrier(0);

  for (int t = 0; t < nk; ++t) {
    const int cb = t % 3;
    if (t + 2 < nk) stage(t + 2, (t + 2) % 3);
    bf16x8 af[4], bfr[NFR];
#pragma unroll
    for (int i = 0; i < 4; ++i) af[i] = *(const bf16x8*)&As[cb][aoff0 + i * 16 * 32];
#pragma unroll
    for (int j = 0; j < NFR; ++j) bfr[j] = *(const bf16x8*)&Bs[cb][boff0 + j * 16 * 32];
    __builtin_amdgcn_s_setprio(1);
#pragma unroll
    for (int i = 0; i < 4; ++i)
#pragma unroll
      for (int j = 0; j < NFR; ++j)
        acc[i][j] = MFMA16(af[i], bfr[j], acc[i][j], 0, 0, 0);
    __builtin_amdgcn_s_setprio(0);
    if (t + 2 < nk) {
      // wait tile t+1 landed; leave tile t+2's LPT loads in flight
      asm volatile("s_waitcnt vmcnt(%0)" ::"n"(LPT) : "memory");
      __builtin_amdgcn_s_barrier();
      asm volatile("" ::: "memory");
      __builtin_amdgcn_sched_barrier(0);
    } else if (t + 1 < nk) {
      asm volatile("s_waitcnt vmcnt(0)" ::: "memory");
      __builtin_amdgcn_s_barrier();
      asm volatile("" ::: "memory");
      __builtin_amdgcn_sched_barrier(0);
    }
  }

#pragma unroll
  for (int i = 0; i < 4; ++i) {
    const long row0 = m0 + wr * 64 + i * 16 + lhi * 4;
#pragma unroll
    for (int j = 0; j < NFR; ++j) {
      const long col = n0 + wc * (NB / 2) + j * 16 + l15;
      const float bb = bias[col];
#pragma unroll
      for (int r = 0; r < 4; ++r) {
        float v = acc[i][j][r] + bb;
        if (EPI == 2) {
          float other = __shfl_xor(v, 1, 64);
          if (!(l15 & 1)) {
            float s = v / (1.f + __expf(-v)) * other;  // silu(g)*v
            out_bf[(row0 + r) * (N >> 1) + (col >> 1)] = f2bf(s);
          }
        } else {
          const long idx = (row0 + r) * N + col;
          if (EPI == 0) out_bf[idx] = f2bf(v);
          else          out_f[idx] = resid[idx] + v;
        }
      }
    }
  }
}

// ---------------- RoPE on Q, pre-scaled by 0.125*log2(e) ----------------
__global__ __launch_bounds__(256) void rope_q_kernel(const u16* __restrict__ qkv,
                                                     const float* __restrict__ cosT,
                                                     const float* __restrict__ sinT,
                                                     u16* __restrict__ Q) {
  int idx = blockIdx.x * 256 + threadIdx.x;  // B*H*S*8 = 524288 units of 8 elems
  int u = idx & 7;
  int s = (idx >> 3) & (S_LEN - 1);
  int bh = idx >> 14;
  int b = bh >> 4, h = bh & 15;
  int pos = PREV + s;
  const float SC = 0.125f * LOG2E;
  const u16* src = qkv + ((long)(b * S_LEN + s)) * (3 * DIM) + h * HD + u * 8;
  u32x4 d = *(const u32x4*)src;
  f32x4 cv = *(const f32x4*)&cosT[(long)pos * 32 + u * 4];
  f32x4 sv = *(const f32x4*)&sinT[(long)pos * 32 + u * 4];
  u32x4 o;
#pragma unroll
  for (int p = 0; p < 4; ++p) {
    float x0 = bf2f((u16)(d[p] & 0xffff));
    float x1 = bf2f((u16)(d[p] >> 16));
    float y0 = (x0 * cv[p] - x1 * sv[p]) * SC;
    float y1 = (x0 * sv[p] + x1 * cv[p]) * SC;
    o[p] = (u32)f2bf(y0) | ((u32)f2bf(y1) << 16);
  }
  *(u32x4*)&Q[((long)bh * S_LEN + s) * HD + u * 8] = o;
}

// ---------------- K_all = rope(concat(cache_k, k_new)); stored XOR-swizzled ----------------
__global__ __launch_bounds__(256) void rope_k_kernel(const u16* __restrict__ qkv,
                                                     const float* __restrict__ cache_k,
                                                     const float* __restrict__ cosT,
                                                     const float* __restrict__ sinT,
                                                     u16* __restrict__ Kall) {
  int idx = blockIdx.x * 256 + threadIdx.x;  // B*H*T*8 = 786432
  int u = idx & 7;
  int t2 = idx >> 3;
  int j = t2 % T_LEN;
  int bh = t2 / T_LEN;
  int b = bh >> 4, h = bh & 15;
  float e[8];
  if (j < PREV) {
    const float* src = cache_k + ((long)bh * PREV + j) * HD + u * 8;
    f32x4 a = *(const f32x4*)src;
    f32x4 c = *(const f32x4*)(src + 4);
    e[0] = a[0]; e[1] = a[1]; e[2] = a[2]; e[3] = a[3];
    e[4] = c[0]; e[5] = c[1]; e[6] = c[2]; e[7] = c[3];
  } else {
    const u16* src = qkv + ((long)(b * S_LEN + (j - PREV))) * (3 * DIM) + DIM + h * HD + u * 8;
    u32x4 d = *(const u32x4*)src;
#pragma unroll
    for (int p = 0; p < 4; ++p) {
      e[2 * p] = bf2f((u16)(d[p] & 0xffff));
      e[2 * p + 1] = bf2f((u16)(d[p] >> 16));
    }
  }
  f32x4 cv = *(const f32x4*)&cosT[(long)j * 32 + u * 4];
  f32x4 sv = *(const f32x4*)&sinT[(long)j * 32 + u * 4];
  u32x4 o;
#pragma unroll
  for (int p = 0; p < 4; ++p) {
    float y0 = e[2 * p] * cv[p] - e[2 * p + 1] * sv[p];
    float y1 = e[2 * p] * sv[p] + e[2 * p + 1] * cv[p];
    o[p] = (u32)f2bf(y0) | ((u32)f2bf(y1) << 16);
  }
  *(u32x4*)&Kall[((long)bh * T_LEN + j) * HD + (u ^ (j & 7)) * 8] = o;
}

// ---------------- Vt_global[bh][hd][key], XOR-swizzled within 64-key spans ----------------
__global__ __launch_bounds__(256) void build_vt_kernel(const u16* __restrict__ qkv,
                                                       const float* __restrict__ cache_v,
                                                       u16* __restrict__ Vtg) {
  int idx = blockIdx.x * 256 + threadIdx.x;  // 32 * 384 * 64 = 786432
  int hd = idx & 63;
  int t2 = idx >> 6;
  int kb = t2 % 384;  // 8-key block
  int bh = t2 / 384;
  int b = bh >> 4, h = bh & 15;
  int key0 = kb * 8;
  u16 vals[8];
  if (key0 < PREV) {
#pragma unroll
    for (int i = 0; i < 8; ++i)
      vals[i] = f2bf(cache_v[((long)bh * PREV + key0 + i) * HD + hd]);
  } else {
#pragma unroll
    for (int i = 0; i < 8; ++i)
      vals[i] = qkv[((long)(b * S_LEN + key0 + i - PREV)) * (3 * DIM) + 2 * DIM + h * HD + hd];
  }
  u32x4 o;
#pragma unroll
  for (int p = 0; p < 4; ++p)
    o[p] = (u32)vals[2 * p] | ((u32)vals[2 * p + 1] << 16);
  const int span = kb >> 3;
  const int u = (kb & 7) ^ (hd & 7);
  *(u32x4*)&Vtg[((long)bh * HD + hd) * T_LEN + span * 64 + u * 8] = o;
}

// ---------------- flash attention, swapped-operand, dbuf, 64 q / block ----------------
__global__ __launch_bounds__(256, 4) void attn_kernel(const u16* __restrict__ Q,
                                                      const u16* __restrict__ Kg,
                                                      const u16* __restrict__ Vtg,
                                                      u16* __restrict__ ctx, float slope2) {
  __shared__ __align__(16) u16 Ks[2][64 * 64];  // [key][d], swizzled
  __shared__ __align__(16) u16 Vs[2][64 * 64];  // [hd][key], swizzled
  __shared__ __align__(16) u16 Ps[4][16 * 64];  // per-wave P[q][key], swizzled

  const int tid = threadIdx.x;
  const int lane = tid & 63;
  const int wv = tid >> 6;
  const int l15 = lane & 15;
  const int lhi = lane >> 4;
  const int c7 = l15 & 7;
  const int bh = blockIdx.x;       // balance: co-resident blocks differ in qt
  const int qt = blockIdx.y;
  const int b = bh >> 4, h = bh & 15;
  const int q0 = qt * 64;
  const int nt = (PREV + q0 + 64) >> 6;

  const long qrow = (long)bh * S_LEN + q0 + wv * 16 + l15;
  bf16x8 aq0 = *(const bf16x8*)&Q[qrow * HD + lhi * 8];
  bf16x8 aq1 = *(const bf16x8*)&Q[qrow * HD + 32 + lhi * 8];

  const long kgb = (long)bh * T_LEN * HD;  // K: [key][64]
  const long vgb = (long)bh * HD * T_LEN;  // Vt: [hd][T]
  const int srow = tid >> 3;               // staging row 0..31
  const int sunit = (tid & 7) * 8;

  // prologue: stage tile 0
  gl_lds16(&Kg[kgb + (long)srow * HD + sunit], &Ks[0][tid * 8]);
  gl_lds16(&Kg[kgb + (long)(srow + 32) * HD + sunit], &Ks[0][2048 + tid * 8]);
  gl_lds16(&Vtg[vgb + (long)srow * T_LEN + sunit], &Vs[0][tid * 8]);
  gl_lds16(&Vtg[vgb + (long)(srow + 32) * T_LEN + sunit], &Vs[0][2048 + tid * 8]);
  __syncthreads();

  f32x4 o[4] = {};
  float mrun = -1e30f, lrun = 0.f;
  const int iabs = PREV + q0 + wv * 16 + l15;  // this lane's absolute q position
  u16* Pw = &Ps[wv][0];

  for (int t = 0; t < nt; ++t) {
    const int cur = t & 1, nxt = cur ^ 1;
    const int kt0 = t << 6;
    if (t + 1 < nt) {
      const int kn = kt0 + 64;
      gl_lds16(&Kg[kgb + (long)(kn + srow) * HD + sunit], &Ks[nxt][tid * 8]);
      gl_lds16(&Kg[kgb + (long)(kn + srow + 32) * HD + sunit], &Ks[nxt][2048 + tid * 8]);
      gl_lds16(&Vtg[vgb + (long)srow * T_LEN + kn + sunit], &Vs[nxt][tid * 8]);
      gl_lds16(&Vtg[vgb + (long)(srow + 32) * T_LEN + kn + sunit], &Vs[nxt][2048 + tid * 8]);
    }

    // S^T = K * Q^T : per wave [64 key][16 q]
    f32x4 sf[4];
    __builtin_amdgcn_s_setprio(1);
#pragma unroll
    for (int jf = 0; jf < 4; ++jf) {
      const int krow = jf * 16 + l15;
      bf16x8 ak0 = *(const bf16x8*)&Ks[cur][krow * 64 + ((lhi ^ c7) * 8)];
      bf16x8 ak1 = *(const bf16x8*)&Ks[cur][krow * 64 + (((4 + lhi) ^ c7) * 8)];
      f32x4 s = {};
      s = MFMA16(ak0, aq0, s, 0, 0, 0);
      s = MFMA16(ak1, aq1, s, 0, 0, 0);
      sf[jf] = s;
    }
    __builtin_amdgcn_s_setprio(0);

    // bias (+ causal mask on last tile), in log2 domain
    const bool masked = (t == nt - 1);
#pragma unroll
    for (int jf = 0; jf < 4; ++jf)
#pragma unroll
      for (int r = 0; r < 4; ++r) {
        const int jcol = kt0 + jf * 16 + 4 * lhi + r;  // key position
        float s_ = sf[jf][r] + slope2 * (float)(jcol - iabs);
        sf[jf][r] = (masked && jcol > iabs) ? -1e30f : s_;
      }

    // row max for q=l15 (in-lane tree + reduce over lhi groups)
    float t0 = fmaxf(fmaxf(sf[0][0], sf[0][1]), fmaxf(sf[0][2], sf[0][3]));
    float t1 = fmaxf(fmaxf(sf[1][0], sf[1][1]), fmaxf(sf[1][2], sf[1][3]));
    float t2 = fmaxf(fmaxf(sf[2][0], sf[2][1]), fmaxf(sf[2][2], sf[2][3]));
    float t3 = fmaxf(fmaxf(sf[3][0], sf[3][1]), fmaxf(sf[3][2], sf[3][3]));
    float pmax = fmaxf(fmaxf(t0, t1), fmaxf(t2, t3));
    pmax = fmaxf(pmax, __shfl_xor(pmax, 16, 64));
    pmax = fmaxf(pmax, __shfl_xor(pmax, 32, 64));

    // defer-max: rescale only when max grew past threshold (log2 units)
    if (!__all(pmax - mrun <= 8.f)) {
      float mnew = fmaxf(mrun, pmax);
      float scl = exp2f(mrun - mnew);
      mrun = mnew;
      lrun *= scl;
#pragma unroll
      for (int r = 0; r < 4; ++r) {
        float sr = __shfl(scl, 4 * lhi + r, 64);  // scale for q row 4*lhi+r
#pragma unroll
        for (int hf = 0; hf < 4; ++hf) o[hf][r] *= sr;
      }
    }

    // P = exp2(s - m), pack pairs, swizzled b64 writes to per-wave LDS
    float ps = 0.f;
#pragma unroll
    for (int jf = 0; jf < 4; ++jf) {
      f32x4 p;
#pragma unroll
      for (int r = 0; r < 4; ++r) {
        p[r] = exp2f(sf[jf][r] - mrun);
        ps += p[r];
      }
      u32x2 pw2;
      pw2[0] = cvtpk(p[0], p[1]);
      pw2[1] = cvtpk(p[2], p[3]);
      const int u = (2 * jf + (lhi >> 1)) ^ c7;
      *(u32x2*)&Pw[l15 * 64 + u * 8 + (lhi & 1) * 4] = pw2;
    }
    ps += __shfl_xor(ps, 16, 64);
    ps += __shfl_xor(ps, 32, 64);
    lrun += ps;

    // O += P * V  (A = P from LDS, B = Vt rows)
    bf16x8 pa0 = *(const bf16x8*)&Pw[l15 * 64 + ((lhi ^ c7) * 8)];
    bf16x8 pa1 = *(const bf16x8*)&Pw[l15 * 64 + (((4 + lhi) ^ c7) * 8)];
    __builtin_amdgcn_s_setprio(1);
#pragma unroll
    for (int hf = 0; hf < 4; ++hf) {
      const int vrow = hf * 16 + l15;
      bf16x8 bv0 = *(const bf16x8*)&Vs[cur][vrow * 64 + ((lhi ^ c7) * 8)];
      bf16x8 bv1 = *(const bf16x8*)&Vs[cur][vrow * 64 + (((4 + lhi) ^ c7) * 8)];
      o[hf] = MFMA16(pa0, bv0, o[hf], 0, 0, 0);
      o[hf] = MFMA16(pa1, bv1, o[hf], 0, 0, 0);
    }
    __builtin_amdgcn_s_setprio(0);
    __syncthreads();  // staged loads landed + all reads of cur done
  }

  // epilogue: O rows are q_local = 4*lhi + r; cols hd = hf*16 + l15
#pragma unroll
  for (int r = 0; r < 4; ++r) {
    const float inv = 1.f / __shfl(lrun, 4 * lhi + r, 64);
    const long srow_ = (long)b * S_LEN + q0 + wv * 16 + 4 * lhi + r;
#pragma unroll
    for (int hf = 0; hf < 4; ++hf)
      ctx[srow_ * DIM + h * HD + hf * 16 + l15] = f2bf(o[hf][r] * inv);
  }
}

// ---------------------------------------------------------------------------
extern "C" void kernel_launch(void* const* d_in, const int* in_sizes, int n_in,
                              void* d_out, int out_size, void* d_ws, size_t ws_size,
                              hipStream_t stream) {
  (void)in_sizes; (void)n_in; (void)out_size; (void)ws_size;
  const float* x       = (const float*)d_in[0];
  const float* cache_k = (const float*)d_in[1];
  const float* cache_v = (const float*)d_in[2];
  const float* cosT    = (const float*)d_in[3];
  const float* sinT    = (const float*)d_in[4];
  const float* attn_w  = (const float*)d_in[5];
  const float* ffn_w   = (const float*)d_in[6];
  const float* wq      = (const float*)d_in[7];
  const float* bq      = (const float*)d_in[8];
  const float* wk      = (const float*)d_in[9];
  const float* bk      = (const float*)d_in[10];
  const float* wv_     = (const float*)d_in[11];
  const float* bv      = (const float*)d_in[12];
  const float* wo      = (const float*)d_in[13];
  const float* bo      = (const float*)d_in[14];
  const float* wg      = (const float*)d_in[15];
  const float* bg      = (const float*)d_in[16];
  const float* wval    = (const float*)d_in[17];
  const float* bval    = (const float*)d_in[18];
  const float* wp      = (const float*)d_in[19];
  const float* bp      = (const float*)d_in[20];
  float* out = (float*)d_out;

  char* w = (char*)d_ws;
  size_t off = 0;
  auto alloc = [&](size_t bytes) -> char* {
    char* p = w + off;
    off += (bytes + 255) & ~(size_t)255;
    return p;
  };
  // permanent
  u16*   wqkv_bf  = (u16*)alloc((size_t)3 * DIM * DIM * 2);
  u16*   wo_bf    = (u16*)alloc((size_t)DIM * DIM * 2);
  u16*   wgv_bf   = (u16*)alloc((size_t)2 * FF * DIM * 2);  // interleaved g/v rows
  u16*   wproj_bf = (u16*)alloc((size_t)DIM * FF * 2);
  float* bqkv     = (float*)alloc((size_t)3 * DIM * 4);
  float* bgv      = (float*)alloc((size_t)2 * FF * 4);      // interleaved
  float* x2       = (float*)alloc((size_t)MROWS * DIM * 4);
  // arena with lifetime-based aliasing
  char* AR = alloc((size_t)117440512);
  u16* qkv   = (u16*)(AR + 0);          // [4096][3072]   live: qkv gemm -> rope/build
  u16* Qb    = (u16*)(AR + 25165824);   // [32][2048][64] live: rope -> attn
  u16* Kb    = (u16*)(AR + 33554432);   // [32][3072][64]
  u16* Vtg   = (u16*)(AR + 46137344);   // [32][64][3072] transposed V
  u16* h1    = (u16*)(AR + 58720256);   // [4096][1024]   live: rms1 -> qkv gemm
  u16* ctx   = (u16*)(AR + 0);          // [4096][1024]   (aliases dead qkv)
  u16* h2    = (u16*)(AR + 8388608);    // [4096][1024]
  u16* gated = (u16*)(AR + 16777216);   // [4096][4096]   (aliases dead Qb/Kb region)

  // 1) weights -> bf16 (+ fused bias packs)
  cvt_kernel<<<512, 256, 0, stream>>>(wq, wqkv_bf, DIM * DIM / 4);
  cvt_kernel<<<512, 256, 0, stream>>>(wk, wqkv_bf + DIM * DIM, DIM * DIM / 4);
  cvt_kernel<<<512, 256, 0, stream>>>(wv_, wqkv_bf + 2 * DIM * DIM, DIM * DIM / 4);
  cvt_kernel<<<512, 256, 0, stream>>>(wo, wo_bf, DIM * DIM / 4);
  cvt_ilv_kernel<<<1024, 256, 0, stream>>>(wg, wval, wgv_bf);
  cvt_kernel<<<1024, 256, 0, stream>>>(wp, wproj_bf, DIM * FF / 4);
  bias_ilv_kernel<<<16, 256, 0, stream>>>(bg, bval, bgv);
  hipMemcpyAsync(bqkv, bq, DIM * 4, hipMemcpyDeviceToDevice, stream);
  hipMemcpyAsync(bqkv + DIM, bk, DIM * 4, hipMemcpyDeviceToDevice, stream);
  hipMemcpyAsync(bqkv + 2 * DIM, bv, DIM * 4, hipMemcpyDeviceToDevice, stream);

  // 2) attn rmsnorm, fused QKV gemm
  rmsnorm_kernel<<<MROWS, 256, 0, stream>>>(x, attn_w, h1);
  gemm_bt<0, 128><<<dim3(24, 32), 256, 0, stream>>>(h1, wqkv_bf, bqkv, nullptr, qkv,
                                                    nullptr, 3 * DIM, DIM);
  // 3) rope + cache concat
  rope_q_kernel<<<2048, 256, 0, stream>>>(qkv, cosT, sinT, Qb);
  rope_k_kernel<<<3072, 256, 0, stream>>>(qkv, cache_k, cosT, sinT, Kb);
  build_vt_kernel<<<3072, 256, 0, stream>>>(qkv, cache_v, Vtg);
  // 4) attention (grid: x=bh for CU load balance across qt)
  attn_kernel<<<dim3(B_SZ * NH, S_LEN / 64), 256, 0, stream>>>(
      Qb, Kb, Vtg, ctx, (2.0f / (float)(T_LEN - 1)) * LOG2E);
  // 5) o-proj + residual (fp32), skinny tile for occupancy
  gemm_bt<1, 64><<<dim3(16, 32), 256, 0, stream>>>(ctx, wo_bf, bo, x, nullptr, x2,
                                                   DIM, DIM);
  // 6) ffn rmsnorm, fused gate+value gemm w/ silu epilogue, proj + residual
  rmsnorm_kernel<<<MROWS, 256, 0, stream>>>(x2, ffn_w, h2);
  gemm_bt<2, 128><<<dim3(64, 32), 256, 0, stream>>>(h2, wgv_bf, bgv, nullptr, gated,
                                                    nullptr, 2 * FF, DIM);
  gemm_bt<1, 64><<<dim3(16, 32), 256, 0, stream>>>(gated, wproj_bf, bp, x2, nullptr, out,
                                                   DIM, FF);
}

// Round 5
// 386.936 us; speedup vs baseline: 1.4588x; 1.0277x over previous
//
#include <hip/hip_runtime.h>
#include <stdint.h>

typedef unsigned short u16;
typedef unsigned int   u32;
typedef __bf16 bf16x8 __attribute__((ext_vector_type(8)));
typedef float  f32x4  __attribute__((ext_vector_type(4)));
typedef u32    u32x4  __attribute__((ext_vector_type(4)));
typedef u32    u32x2  __attribute__((ext_vector_type(2)));

#define B_SZ  2
#define S_LEN 2048
#define NH    16
#define HD    64
#define DIM   1024
#define FF    4096
#define T_LEN 3072
#define PREV  1024
#define MROWS (B_SZ * S_LEN) /* 4096 */
#define LOG2E 1.44269504f

#define MFMA16 __builtin_amdgcn_mfma_f32_16x16x32_bf16

__device__ __forceinline__ u16 f2bf(float f) {
  u32 u = __builtin_bit_cast(u32, f);
  u32 r = u + 0x7FFFu + ((u >> 16) & 1u);
  return (u16)(r >> 16);
}
__device__ __forceinline__ float bf2f(u16 h) {
  u32 u = ((u32)h) << 16;
  return __builtin_bit_cast(float, u);
}
__device__ __forceinline__ u32 cvtpk(float lo, float hi) {
  u32 r;
  asm("v_cvt_pk_bf16_f32 %0, %1, %2" : "=v"(r) : "v"(lo), "v"(hi));
  return r;
}

// async global->LDS, 16B per lane. LDS dest must be wave-uniform base + lane*16.
__device__ __forceinline__ void gl_lds16(const void* g, void* l) {
  __builtin_amdgcn_global_load_lds(
      (const __attribute__((address_space(1))) u32*)g,
      (__attribute__((address_space(3))) u32*)l, 16, 0, 0);
}

#define GFENCE() asm volatile("" ::: "memory")
#define BARF()                         \
  do {                                 \
    GFENCE();                          \
    __builtin_amdgcn_s_barrier();      \
    GFENCE();                          \
  } while (0)

// ---------------- fp32 -> bf16 convert (linear, for 3-buf GEMM weights) ----------------
__global__ __launch_bounds__(256) void cvt_kernel(const float* __restrict__ src,
                                                  u16* __restrict__ dst, int n4) {
  int i = blockIdx.x * 256 + threadIdx.x;
  const int stride = gridDim.x * 256;
  for (; i < n4; i += stride) {
    f32x4 v = *(const f32x4*)&src[(long)i * 4];
    u32x2 o;
    o[0] = (u32)f2bf(v[0]) | ((u32)f2bf(v[1]) << 16);
    o[1] = (u32)f2bf(v[2]) | ((u32)f2bf(v[3]) << 16);
    *(u32x2*)&dst[(long)i * 4] = o;
  }
}

// ---------------- fp32 -> bf16, K-unit XOR-preswizzled (K=1024) ----------------
// dst[row][ (g&~7)|((g&7)^(row&7)) ] = src 16B unit g.
__global__ __launch_bounds__(256) void cvt_sw_kernel(const float* __restrict__ src,
                                                     u16* __restrict__ dst, int nunits) {
  int i = blockIdx.x * 256 + threadIdx.x;  // unit index over rows*(1024/8)
  const int stride = gridDim.x * 256;
  for (; i < nunits; i += stride) {
    int row = i >> 7;
    int g = i & 127;
    const float* s = &src[((long)row << 10) + g * 8];
    f32x4 a = *(const f32x4*)s;
    f32x4 b = *(const f32x4*)(s + 4);
    u32x4 o;
    o[0] = (u32)f2bf(a[0]) | ((u32)f2bf(a[1]) << 16);
    o[1] = (u32)f2bf(a[2]) | ((u32)f2bf(a[3]) << 16);
    o[2] = (u32)f2bf(b[0]) | ((u32)f2bf(b[1]) << 16);
    o[3] = (u32)f2bf(b[2]) | ((u32)f2bf(b[3]) << 16);
    const int gp = (g & ~7) | ((g & 7) ^ (row & 7));
    *(u32x4*)&dst[((long)row << 10) + gp * 8] = o;
  }
}

// interleave wg/wval rows (dst row 2j = wg[j], 2j+1 = wval[j]), preswizzled, K=1024
__global__ __launch_bounds__(256) void cvt_ilv_sw_kernel(const float* __restrict__ wg,
                                                         const float* __restrict__ wval,
                                                         u16* __restrict__ dst) {
  int i = blockIdx.x * 256 + threadIdx.x;  // FF * 128 units
  const int stride = gridDim.x * 256;
  for (; i < FF * 128; i += stride) {
    int j = i >> 7;
    int g = i & 127;
    const float* sg = &wg[((long)j << 10) + g * 8];
    const float* sv = &wval[((long)j << 10) + g * 8];
    f32x4 a = *(const f32x4*)sg;
    f32x4 b = *(const f32x4*)(sg + 4);
    u32x4 og;
    og[0] = (u32)f2bf(a[0]) | ((u32)f2bf(a[1]) << 16);
    og[1] = (u32)f2bf(a[2]) | ((u32)f2bf(a[3]) << 16);
    og[2] = (u32)f2bf(b[0]) | ((u32)f2bf(b[1]) << 16);
    og[3] = (u32)f2bf(b[2]) | ((u32)f2bf(b[3]) << 16);
    f32x4 c = *(const f32x4*)sv;
    f32x4 d = *(const f32x4*)(sv + 4);
    u32x4 ov;
    ov[0] = (u32)f2bf(c[0]) | ((u32)f2bf(c[1]) << 16);
    ov[1] = (u32)f2bf(c[2]) | ((u32)f2bf(c[3]) << 16);
    ov[2] = (u32)f2bf(d[0]) | ((u32)f2bf(d[1]) << 16);
    ov[3] = (u32)f2bf(d[2]) | ((u32)f2bf(d[3]) << 16);
    const int rg = 2 * j, rv = 2 * j + 1;
    const int gpg = (g & ~7) | ((g & 7) ^ (rg & 7));
    const int gpv = (g & ~7) | ((g & 7) ^ (rv & 7));
    *(u32x4*)&dst[((long)rg << 10) + gpg * 8] = og;
    *(u32x4*)&dst[((long)rv << 10) + gpv * 8] = ov;
  }
}

// interleave biases: dst[2i]=bg[i], dst[2i+1]=bval[i]
__global__ __launch_bounds__(256) void bias_ilv_kernel(const float* __restrict__ bg,
                                                       const float* __restrict__ bval,
                                                       float* __restrict__ dst) {
  int i = blockIdx.x * 256 + threadIdx.x;
  if (i < FF) {
    dst[2 * i] = bg[i];
    dst[2 * i + 1] = bval[i];
  }
}

// ---------------- RMSNorm: fp32 row -> bf16 row, K-unit XOR-preswizzled out ----------------
__global__ __launch_bounds__(256) void rmsnorm_kernel(const float* __restrict__ x,
                                                      const float* __restrict__ w,
                                                      u16* __restrict__ out) {
  const int row = blockIdx.x;
  const int tid = threadIdx.x;
  const long base = (long)row * DIM + tid * 4;
  f32x4 v = *(const f32x4*)&x[base];
  float ss = v[0] * v[0] + v[1] * v[1] + v[2] * v[2] + v[3] * v[3];
#pragma unroll
  for (int d = 1; d <= 32; d <<= 1) ss += __shfl_xor(ss, d, 64);
  __shared__ float red[4];
  if ((tid & 63) == 0) red[tid >> 6] = ss;
  __syncthreads();
  float tot = red[0] + red[1] + red[2] + red[3];
  const float sc = rsqrtf(tot * (1.f / (float)DIM) + 1e-6f);
  f32x4 wv4 = *(const f32x4*)&w[tid * 4];
  u32x2 o;
  o[0] = (u32)f2bf(v[0] * sc * wv4[0]) | ((u32)f2bf(v[1] * sc * wv4[1]) << 16);
  o[1] = (u32)f2bf(v[2] * sc * wv4[2]) | ((u32)f2bf(v[3] * sc * wv4[3]) << 16);
  const int u = tid >> 1, hf = tid & 1;
  const int up = (u & 0x78) | ((u & 7) ^ (row & 7));
  *(u32x2*)&out[(long)row * DIM + up * 8 + hf * 4] = o;
}

// ---------------- 256x256 8-phase GEMM (T2+T3+T4+T5), K multiple of 64 ----------------
// A[M,K], Bw[N,K] both bf16 with K-unit XOR pre-swizzle (u ^= row&7 per 64-elem tile).
// 8 waves (2M x 4N); per-wave 128x64 out = acc[8][4]. 4 phases/K-tile x 16 MFMA.
// Stage K-tile t+2 at phases P2 (A) / P3 (B); regions last ds_read at P1 -> WAR-safe.
// Boundary: vmcnt(8) leaves next prefetched tile in flight. EPI 0: bf16. EPI 2: silu.
template <int EPI>
__global__ __launch_bounds__(512, 2) void gemm256(const u16* __restrict__ A,
                                                  const u16* __restrict__ Bw,
                                                  const float* __restrict__ bias,
                                                  u16* __restrict__ out_bf,
                                                  int N, int K) {
  __shared__ __align__(16) u16 Ab[2][256 * 64];
  __shared__ __align__(16) u16 Bb[2][256 * 64];
  const int tid = threadIdx.x;
  const int lane = tid & 63;
  const int wid = tid >> 6;
  const int wm = wid >> 2, wn = wid & 3;
  const int l15 = lane & 15, lhi = lane >> 4;
  const int c7 = l15 & 7;
  const long m0 = (long)blockIdx.y * 256;
  const long n0 = (long)blockIdx.x * 256;
  const int NT = K >> 6;

  const int srow = tid >> 3;
  const int sunit = (tid & 7) * 8;
  const u16* agp = A + (m0 + srow) * K + sunit;
  const u16* bgp = Bw + (n0 + srow) * K + sunit;
  const int ldst = tid * 8;

  auto stageA = [&](int kt, int b) {
    const int k0 = kt << 6;
    u16* d = &Ab[b][0];
#pragma unroll
    for (int c = 0; c < 4; ++c)
      gl_lds16(agp + (long)(c * 64) * K + k0, d + c * 4096 + ldst);
  };
  auto stageB = [&](int kt, int b) {
    const int k0 = kt << 6;
    u16* d = &Bb[b][0];
#pragma unroll
    for (int c = 0; c < 4; ++c)
      gl_lds16(bgp + (long)(c * 64) * K + k0, d + c * 4096 + ldst);
  };

#define READ_A(MH)                                                               \
  _Pragma("unroll") for (int m_ = 0; m_ < 4; ++m_) {                             \
    _Pragma("unroll") for (int ks_ = 0; ks_ < 2; ++ks_) {                        \
      Afr[MH][m_ * 2 + ks_] =                                                    \
          *(const bf16x8*)&Ac[(wm * 128 + (MH)*64 + m_ * 16 + l15) * 64 +        \
                              (((ks_ * 4 + lhi) ^ c7) * 8)];                     \
    }                                                                            \
  }
#define READ_B(NH)                                                               \
  _Pragma("unroll") for (int n_ = 0; n_ < 2; ++n_) {                             \
    _Pragma("unroll") for (int ks_ = 0; ks_ < 2; ++ks_) {                        \
      Bfr[NH][n_ * 2 + ks_] =                                                    \
          *(const bf16x8*)&Bc[(wn * 64 + (NH)*32 + n_ * 16 + l15) * 64 +         \
                              (((ks_ * 4 + lhi) ^ c7) * 8)];                     \
    }                                                                            \
  }
#define QUAD(MH, NH)                                                             \
  do {                                                                           \
    __builtin_amdgcn_s_setprio(1);                                               \
    _Pragma("unroll") for (int m_ = 0; m_ < 4; ++m_) {                           \
      _Pragma("unroll") for (int n_ = 0; n_ < 2; ++n_) {                         \
        acc[(MH)*4 + m_][(NH)*2 + n_] =                                          \
            MFMA16(Afr[MH][m_ * 2], Bfr[NH][n_ * 2],                             \
                   acc[(MH)*4 + m_][(NH)*2 + n_], 0, 0, 0);                      \
        acc[(MH)*4 + m_][(NH)*2 + n_] =                                          \
            MFMA16(Afr[MH][m_ * 2 + 1], Bfr[NH][n_ * 2 + 1],                     \
                   acc[(MH)*4 + m_][(NH)*2 + n_], 0, 0, 0);                      \
      }                                                                          \
    }                                                                            \
    __builtin_amdgcn_s_setprio(0);                                               \
  } while (0)

  f32x4 acc[8][4] = {};

  // prologue: tiles 0,1 staged; wait tile 0 (tile 1 stays in flight)
  stageA(0, 0);
  stageB(0, 0);
  stageA(1, 1);
  stageB(1, 1);
  asm volatile("s_waitcnt vmcnt(8)" ::: "memory");
  __builtin_amdgcn_s_barrier();
  GFENCE();

  for (int kt = 0; kt < NT; ++kt) {
    const int b = kt & 1;
    const u16* Ac = &Ab[b][0];
    const u16* Bc = &Bb[b][0];
    bf16x8 Afr[2][8], Bfr[2][4];
    // P0: read A-half0 + B-half0
    READ_A(0);
    READ_B(0);
    BARF();
    QUAD(0, 0);
    BARF();
    // P1: read A-half1 + B-half1
    READ_A(1);
    READ_B(1);
    BARF();
    QUAD(0, 1);
    BARF();
    // P2: stage A(kt+2) (A regions free after P1)
    if (kt + 2 < NT) stageA(kt + 2, b);
    BARF();
    QUAD(1, 0);
    BARF();
    // P3: stage B(kt+2)
    if (kt + 2 < NT) stageB(kt + 2, b);
    BARF();
    QUAD(1, 1);
    // K-tile boundary: next tile must be resident; keep prefetch in flight
    if (kt + 1 < NT) {
      if (kt + 2 < NT)
        asm volatile("s_waitcnt vmcnt(8)" ::: "memory");
      else
        asm volatile("s_waitcnt vmcnt(0)" ::: "memory");
      __builtin_amdgcn_s_barrier();
      GFENCE();
    }
  }
#undef READ_A
#undef READ_B
#undef QUAD

#pragma unroll
  for (int mi = 0; mi < 8; ++mi) {
    const long row0 = m0 + wm * 128 + mi * 16 + lhi * 4;
#pragma unroll
    for (int ni = 0; ni < 4; ++ni) {
      const long col = n0 + wn * 64 + ni * 16 + l15;
      const float bb = bias[col];
#pragma unroll
      for (int r = 0; r < 4; ++r) {
        float v = acc[mi][ni][r] + bb;
        if (EPI == 2) {
          float other = __shfl_xor(v, 1, 64);
          if (!(l15 & 1)) {
            float s = v / (1.f + __expf(-v)) * other;  // silu(g)*v
            out_bf[(row0 + r) * (N >> 1) + (col >> 1)] = f2bf(s);
          }
        } else {
          out_bf[(row0 + r) * N + col] = f2bf(v);
        }
      }
    }
  }
}

// ---------------- 3-buffer GEMM (linear layouts) for skinny N ----------------
// EPI 1: fp32 resid+acc store.
template <int EPI, int NB>
__global__ __launch_bounds__(256) void gemm_bt(const u16* __restrict__ A,
                                               const u16* __restrict__ Bw,
                                               const float* __restrict__ bias,
                                               const float* __restrict__ resid,
                                               u16* __restrict__ out_bf,
                                               float* __restrict__ out_f,
                                               int N, int K) {
  constexpr int BHALF = NB / 64;
  constexpr int NFR = NB / 32;
  constexpr int LPT = 2 + BHALF;
  __shared__ __align__(16) u16 As[3][128 * 32];
  __shared__ __align__(16) u16 Bs[3][NB * 32];
  const int tid = threadIdx.x;
  const int lane = tid & 63;
  const int wv = tid >> 6;
  const int wr = wv >> 1, wc = wv & 1;
  const long m0 = (long)blockIdx.y * 128;
  const long n0 = (long)blockIdx.x * NB;

  const int arow = tid >> 2;
  const int acol = (tid & 3) << 3;
  const u16* ag = A + (m0 + arow) * K + acol;
  const u16* bg = Bw + (n0 + arow) * K + acol;
  const long hK = (long)64 * K;

  f32x4 acc[4][NFR] = {};
  const int l15 = lane & 15;
  const int lhi = lane >> 4;
  const int aoff0 = (wr * 64 + l15) * 32 + lhi * 8;
  const int boff0 = (wc * (NB / 2) + l15) * 32 + lhi * 8;
  const int nk = K >> 5;

  auto stage = [&](int t, int buf) {
    const int k0 = t << 5;
    gl_lds16(ag + k0, &As[buf][tid * 8]);
    gl_lds16(ag + k0 + hK, &As[buf][2048 + tid * 8]);
    gl_lds16(bg + k0, &Bs[buf][tid * 8]);
    if (BHALF == 2) gl_lds16(bg + k0 + hK, &Bs[buf][2048 + tid * 8]);
  };

  stage(0, 0);
  stage(1, 1);
  asm volatile("s_waitcnt vmcnt(%0)" ::"n"(LPT) : "memory");
  __builtin_amdgcn_s_barrier();
  GFENCE();

  for (int t = 0; t < nk; ++t) {
    const int cb = t % 3;
    if (t + 2 < nk) stage(t + 2, (t + 2) % 3);
    bf16x8 af[4], bfr[NFR];
#pragma unroll
    for (int i = 0; i < 4; ++i) af[i] = *(const bf16x8*)&As[cb][aoff0 + i * 16 * 32];
#pragma unroll
    for (int j = 0; j < NFR; ++j) bfr[j] = *(const bf16x8*)&Bs[cb][boff0 + j * 16 * 32];
    __builtin_amdgcn_s_setprio(1);
#pragma unroll
    for (int i = 0; i < 4; ++i)
#pragma unroll
      for (int j = 0; j < NFR; ++j)
        acc[i][j] = MFMA16(af[i], bfr[j], acc[i][j], 0, 0, 0);
    __builtin_amdgcn_s_setprio(0);
    if (t + 2 < nk) {
      asm volatile("s_waitcnt vmcnt(%0)" ::"n"(LPT) : "memory");
      __builtin_amdgcn_s_barrier();
      GFENCE();
    } else if (t + 1 < nk) {
      asm volatile("s_waitcnt vmcnt(0)" ::: "memory");
      __builtin_amdgcn_s_barrier();
      GFENCE();
    }
  }

#pragma unroll
  for (int i = 0; i < 4; ++i) {
    const long row0 = m0 + wr * 64 + i * 16 + lhi * 4;
#pragma unroll
    for (int j = 0; j < NFR; ++j) {
      const long col = n0 + wc * (NB / 2) + j * 16 + l15;
      const float bb = bias[col];
#pragma unroll
      for (int r = 0; r < 4; ++r) {
        const long idx = (row0 + r) * N + col;
        float v = acc[i][j][r] + bb;
        if (EPI == 0) out_bf[idx] = f2bf(v);
        else          out_f[idx] = resid[idx] + v;
      }
    }
  }
}

// ---------------- RoPE on Q, pre-scaled by 0.125*log2(e) ----------------
__global__ __launch_bounds__(256) void rope_q_kernel(const u16* __restrict__ qkv,
                                                     const float* __restrict__ cosT,
                                                     const float* __restrict__ sinT,
                                                     u16* __restrict__ Q) {
  int idx = blockIdx.x * 256 + threadIdx.x;  // B*H*S*8 = 524288 units of 8 elems
  int u = idx & 7;
  int s = (idx >> 3) & (S_LEN - 1);
  int bh = idx >> 14;
  int b = bh >> 4, h = bh & 15;
  int pos = PREV + s;
  const float SC = 0.125f * LOG2E;
  const u16* src = qkv + ((long)(b * S_LEN + s)) * (3 * DIM) + h * HD + u * 8;
  u32x4 d = *(const u32x4*)src;
  f32x4 cv = *(const f32x4*)&cosT[(long)pos * 32 + u * 4];
  f32x4 sv = *(const f32x4*)&sinT[(long)pos * 32 + u * 4];
  u32x4 o;
#pragma unroll
  for (int p = 0; p < 4; ++p) {
    float x0 = bf2f((u16)(d[p] & 0xffff));
    float x1 = bf2f((u16)(d[p] >> 16));
    float y0 = (x0 * cv[p] - x1 * sv[p]) * SC;
    float y1 = (x0 * sv[p] + x1 * cv[p]) * SC;
    o[p] = (u32)f2bf(y0) | ((u32)f2bf(y1) << 16);
  }
  *(u32x4*)&Q[((long)bh * S_LEN + s) * HD + u * 8] = o;
}

// ---------------- K_all = rope(concat(cache_k, k_new)); stored XOR-swizzled ----------------
__global__ __launch_bounds__(256) void rope_k_kernel(const u16* __restrict__ qkv,
                                                     const float* __restrict__ cache_k,
                                                     const float* __restrict__ cosT,
                                                     const float* __restrict__ sinT,
                                                     u16* __restrict__ Kall) {
  int idx = blockIdx.x * 256 + threadIdx.x;  // B*H*T*8 = 786432
  int u = idx & 7;
  int t2 = idx >> 3;
  int j = t2 % T_LEN;
  int bh = t2 / T_LEN;
  int b = bh >> 4, h = bh & 15;
  float e[8];
  if (j < PREV) {
    const float* src = cache_k + ((long)bh * PREV + j) * HD + u * 8;
    f32x4 a = *(const f32x4*)src;
    f32x4 c = *(const f32x4*)(src + 4);
    e[0] = a[0]; e[1] = a[1]; e[2] = a[2]; e[3] = a[3];
    e[4] = c[0]; e[5] = c[1]; e[6] = c[2]; e[7] = c[3];
  } else {
    const u16* src = qkv + ((long)(b * S_LEN + (j - PREV))) * (3 * DIM) + DIM + h * HD + u * 8;
    u32x4 d = *(const u32x4*)src;
#pragma unroll
    for (int p = 0; p < 4; ++p) {
      e[2 * p] = bf2f((u16)(d[p] & 0xffff));
      e[2 * p + 1] = bf2f((u16)(d[p] >> 16));
    }
  }
  f32x4 cv = *(const f32x4*)&cosT[(long)j * 32 + u * 4];
  f32x4 sv = *(const f32x4*)&sinT[(long)j * 32 + u * 4];
  u32x4 o;
#pragma unroll
  for (int p = 0; p < 4; ++p) {
    float y0 = e[2 * p] * cv[p] - e[2 * p + 1] * sv[p];
    float y1 = e[2 * p] * sv[p] + e[2 * p + 1] * cv[p];
    o[p] = (u32)f2bf(y0) | ((u32)f2bf(y1) << 16);
  }
  *(u32x4*)&Kall[((long)bh * T_LEN + j) * HD + (u ^ (j & 7)) * 8] = o;
}

// ---------------- Vt_global[bh][hd][key], XOR-swizzled within 64-key spans ----------------
__global__ __launch_bounds__(256) void build_vt_kernel(const u16* __restrict__ qkv,
                                                       const float* __restrict__ cache_v,
                                                       u16* __restrict__ Vtg) {
  int idx = blockIdx.x * 256 + threadIdx.x;  // 32 * 384 * 64 = 786432
  int hd = idx & 63;
  int t2 = idx >> 6;
  int kb = t2 % 384;  // 8-key block
  int bh = t2 / 384;
  int b = bh >> 4, h = bh & 15;
  int key0 = kb * 8;
  u16 vals[8];
  if (key0 < PREV) {
#pragma unroll
    for (int i = 0; i < 8; ++i)
      vals[i] = f2bf(cache_v[((long)bh * PREV + key0 + i) * HD + hd]);
  } else {
#pragma unroll
    for (int i = 0; i < 8; ++i)
      vals[i] = qkv[((long)(b * S_LEN + key0 + i - PREV)) * (3 * DIM) + 2 * DIM + h * HD + hd];
  }
  u32x4 o;
#pragma unroll
  for (int p = 0; p < 4; ++p)
    o[p] = (u32)vals[2 * p] | ((u32)vals[2 * p + 1] << 16);
  const int span = kb >> 3;
  const int u = (kb & 7) ^ (hd & 7);
  *(u32x4*)&Vtg[((long)bh * HD + hd) * T_LEN + span * 64 + u * 8] = o;
}

// ---------------- flash attention, swapped-operand, dbuf, 64 q / block ----------------
__global__ __launch_bounds__(256, 4) void attn_kernel(const u16* __restrict__ Q,
                                                      const u16* __restrict__ Kg,
                                                      const u16* __restrict__ Vtg,
                                                      u16* __restrict__ ctx, float slope2) {
  __shared__ __align__(16) u16 Ks[2][64 * 64];  // [key][d], swizzled
  __shared__ __align__(16) u16 Vs[2][64 * 64];  // [hd][key], swizzled
  __shared__ __align__(16) u16 Ps[4][16 * 64];  // per-wave P[q][key], swizzled

  const int tid = threadIdx.x;
  const int lane = tid & 63;
  const int wv = tid >> 6;
  const int l15 = lane & 15;
  const int lhi = lane >> 4;
  const int c7 = l15 & 7;
  const int bh = blockIdx.x;       // balance: co-resident blocks differ in qt
  const int qt = blockIdx.y;
  const int b = bh >> 4, h = bh & 15;
  const int q0 = qt * 64;
  const int nt = (PREV + q0 + 64) >> 6;

  const long qrow = (long)bh * S_LEN + q0 + wv * 16 + l15;
  bf16x8 aq0 = *(const bf16x8*)&Q[qrow * HD + lhi * 8];
  bf16x8 aq1 = *(const bf16x8*)&Q[qrow * HD + 32 + lhi * 8];

  const long kgb = (long)bh * T_LEN * HD;  // K: [key][64]
  const long vgb = (long)bh * HD * T_LEN;  // Vt: [hd][T]
  const int srow = tid >> 3;               // staging row 0..31
  const int sunit = (tid & 7) * 8;

  // prologue: stage tile 0
  gl_lds16(&Kg[kgb + (long)srow * HD + sunit], &Ks[0][tid * 8]);
  gl_lds16(&Kg[kgb + (long)(srow + 32) * HD + sunit], &Ks[0][2048 + tid * 8]);
  gl_lds16(&Vtg[vgb + (long)srow * T_LEN + sunit], &Vs[0][tid * 8]);
  gl_lds16(&Vtg[vgb + (long)(srow + 32) * T_LEN + sunit], &Vs[0][2048 + tid * 8]);
  __syncthreads();

  f32x4 o[4] = {};
  float mrun = -1e30f, lrun = 0.f;
  const int iabs = PREV + q0 + wv * 16 + l15;  // this lane's absolute q position
  u16* Pw = &Ps[wv][0];

  for (int t = 0; t < nt; ++t) {
    const int cur = t & 1, nxt = cur ^ 1;
    const int kt0 = t << 6;
    if (t + 1 < nt) {
      const int kn = kt0 + 64;
      gl_lds16(&Kg[kgb + (long)(kn + srow) * HD + sunit], &Ks[nxt][tid * 8]);
      gl_lds16(&Kg[kgb + (long)(kn + srow + 32) * HD + sunit], &Ks[nxt][2048 + tid * 8]);
      gl_lds16(&Vtg[vgb + (long)srow * T_LEN + kn + sunit], &Vs[nxt][tid * 8]);
      gl_lds16(&Vtg[vgb + (long)(srow + 32) * T_LEN + kn + sunit], &Vs[nxt][2048 + tid * 8]);
    }

    // S^T = K * Q^T : per wave [64 key][16 q]
    f32x4 sf[4];
    __builtin_amdgcn_s_setprio(1);
#pragma unroll
    for (int jf = 0; jf < 4; ++jf) {
      const int krow = jf * 16 + l15;
      bf16x8 ak0 = *(const bf16x8*)&Ks[cur][krow * 64 + ((lhi ^ c7) * 8)];
      bf16x8 ak1 = *(const bf16x8*)&Ks[cur][krow * 64 + (((4 + lhi) ^ c7) * 8)];
      f32x4 s = {};
      s = MFMA16(ak0, aq0, s, 0, 0, 0);
      s = MFMA16(ak1, aq1, s, 0, 0, 0);
      sf[jf] = s;
    }
    __builtin_amdgcn_s_setprio(0);

    // bias (+ causal mask on last tile), in log2 domain
    const bool masked = (t == nt - 1);
#pragma unroll
    for (int jf = 0; jf < 4; ++jf)
#pragma unroll
      for (int r = 0; r < 4; ++r) {
        const int jcol = kt0 + jf * 16 + 4 * lhi + r;  // key position
        float s_ = sf[jf][r] + slope2 * (float)(jcol - iabs);
        sf[jf][r] = (masked && jcol > iabs) ? -1e30f : s_;
      }

    // row max for q=l15 (in-lane tree + reduce over lhi groups)
    float t0 = fmaxf(fmaxf(sf[0][0], sf[0][1]), fmaxf(sf[0][2], sf[0][3]));
    float t1 = fmaxf(fmaxf(sf[1][0], sf[1][1]), fmaxf(sf[1][2], sf[1][3]));
    float t2 = fmaxf(fmaxf(sf[2][0], sf[2][1]), fmaxf(sf[2][2], sf[2][3]));
    float t3 = fmaxf(fmaxf(sf[3][0], sf[3][1]), fmaxf(sf[3][2], sf[3][3]));
    float pmax = fmaxf(fmaxf(t0, t1), fmaxf(t2, t3));
    pmax = fmaxf(pmax, __shfl_xor(pmax, 16, 64));
    pmax = fmaxf(pmax, __shfl_xor(pmax, 32, 64));

    // defer-max: rescale only when max grew past threshold (log2 units)
    if (!__all(pmax - mrun <= 8.f)) {
      float mnew = fmaxf(mrun, pmax);
      float scl = exp2f(mrun - mnew);
      mrun = mnew;
      lrun *= scl;
#pragma unroll
      for (int r = 0; r < 4; ++r) {
        float sr = __shfl(scl, 4 * lhi + r, 64);  // scale for q row 4*lhi+r
#pragma unroll
        for (int hf = 0; hf < 4; ++hf) o[hf][r] *= sr;
      }
    }

    // P = exp2(s - m), pack pairs, swizzled b64 writes to per-wave LDS
    float ps = 0.f;
#pragma unroll
    for (int jf = 0; jf < 4; ++jf) {
      f32x4 p;
#pragma unroll
      for (int r = 0; r < 4; ++r) {
        p[r] = exp2f(sf[jf][r] - mrun);
        ps += p[r];
      }
      u32x2 pw2;
      pw2[0] = cvtpk(p[0], p[1]);
      pw2[1] = cvtpk(p[2], p[3]);
      const int u = (2 * jf + (lhi >> 1)) ^ c7;
      *(u32x2*)&Pw[l15 * 64 + u * 8 + (lhi & 1) * 4] = pw2;
    }
    ps += __shfl_xor(ps, 16, 64);
    ps += __shfl_xor(ps, 32, 64);
    lrun += ps;

    // O += P * V  (A = P from LDS, B = Vt rows)
    bf16x8 pa0 = *(const bf16x8*)&Pw[l15 * 64 + ((lhi ^ c7) * 8)];
    bf16x8 pa1 = *(const bf16x8*)&Pw[l15 * 64 + (((4 + lhi) ^ c7) * 8)];
    __builtin_amdgcn_s_setprio(1);
#pragma unroll
    for (int hf = 0; hf < 4; ++hf) {
      const int vrow = hf * 16 + l15;
      bf16x8 bv0 = *(const bf16x8*)&Vs[cur][vrow * 64 + ((lhi ^ c7) * 8)];
      bf16x8 bv1 = *(const bf16x8*)&Vs[cur][vrow * 64 + (((4 + lhi) ^ c7) * 8)];
      o[hf] = MFMA16(pa0, bv0, o[hf], 0, 0, 0);
      o[hf] = MFMA16(pa1, bv1, o[hf], 0, 0, 0);
    }
    __builtin_amdgcn_s_setprio(0);
    __syncthreads();  // staged loads landed + all reads of cur done
  }

  // epilogue: O rows are q_local = 4*lhi + r; cols hd = hf*16 + l15
#pragma unroll
  for (int r = 0; r < 4; ++r) {
    const float inv = 1.f / __shfl(lrun, 4 * lhi + r, 64);
    const long srow_ = (long)b * S_LEN + q0 + wv * 16 + 4 * lhi + r;
#pragma unroll
    for (int hf = 0; hf < 4; ++hf)
      ctx[srow_ * DIM + h * HD + hf * 16 + l15] = f2bf(o[hf][r] * inv);
  }
}

// ---------------------------------------------------------------------------
extern "C" void kernel_launch(void* const* d_in, const int* in_sizes, int n_in,
                              void* d_out, int out_size, void* d_ws, size_t ws_size,
                              hipStream_t stream) {
  (void)in_sizes; (void)n_in; (void)out_size; (void)ws_size;
  const float* x       = (const float*)d_in[0];
  const float* cache_k = (const float*)d_in[1];
  const float* cache_v = (const float*)d_in[2];
  const float* cosT    = (const float*)d_in[3];
  const float* sinT    = (const float*)d_in[4];
  const float* attn_w  = (const float*)d_in[5];
  const float* ffn_w   = (const float*)d_in[6];
  const float* wq      = (const float*)d_in[7];
  const float* bq      = (const float*)d_in[8];
  const float* wk      = (const float*)d_in[9];
  const float* bk      = (const float*)d_in[10];
  const float* wv_     = (const float*)d_in[11];
  const float* bv      = (const float*)d_in[12];
  const float* wo      = (const float*)d_in[13];
  const float* bo      = (const float*)d_in[14];
  const float* wg      = (const float*)d_in[15];
  const float* bg      = (const float*)d_in[16];
  const float* wval    = (const float*)d_in[17];
  const float* bval    = (const float*)d_in[18];
  const float* wp      = (const float*)d_in[19];
  const float* bp      = (const float*)d_in[20];
  float* out = (float*)d_out;

  char* w = (char*)d_ws;
  size_t off = 0;
  auto alloc = [&](size_t bytes) -> char* {
    char* p = w + off;
    off += (bytes + 255) & ~(size_t)255;
    return p;
  };
  // permanent
  u16*   wqkv_bf  = (u16*)alloc((size_t)3 * DIM * DIM * 2);  // preswizzled
  u16*   wo_bf    = (u16*)alloc((size_t)DIM * DIM * 2);      // linear
  u16*   wgv_bf   = (u16*)alloc((size_t)2 * FF * DIM * 2);   // interleaved+preswizzled
  u16*   wproj_bf = (u16*)alloc((size_t)DIM * FF * 2);       // linear
  float* bqkv     = (float*)alloc((size_t)3 * DIM * 4);
  float* bgv      = (float*)alloc((size_t)2 * FF * 4);       // interleaved
  float* x2       = (float*)alloc((size_t)MROWS * DIM * 4);
  // arena with lifetime-based aliasing
  char* AR = alloc((size_t)117440512);
  u16* qkv   = (u16*)(AR + 0);          // [4096][3072]   live: qkv gemm -> rope/build
  u16* Qb    = (u16*)(AR + 25165824);   // [32][2048][64] live: rope -> attn
  u16* Kb    = (u16*)(AR + 33554432);   // [32][3072][64]
  u16* Vtg   = (u16*)(AR + 46137344);   // [32][64][3072] transposed V
  u16* h1    = (u16*)(AR + 58720256);   // [4096][1024]   preswizzled (qkv gemm A)
  u16* ctx   = (u16*)(AR + 0);          // [4096][1024]   linear (aliases dead qkv)
  u16* h2    = (u16*)(AR + 8388608);    // [4096][1024]   preswizzled (gv gemm A)
  u16* gated = (u16*)(AR + 16777216);   // [4096][4096]   linear

  // 1) weights -> bf16 (preswizzled for 256-GEMMs; linear for skinny GEMMs)
  cvt_sw_kernel<<<512, 256, 0, stream>>>(wq, wqkv_bf, DIM * DIM / 8);
  cvt_sw_kernel<<<512, 256, 0, stream>>>(wk, wqkv_bf + DIM * DIM, DIM * DIM / 8);
  cvt_sw_kernel<<<512, 256, 0, stream>>>(wv_, wqkv_bf + 2 * DIM * DIM, DIM * DIM / 8);
  cvt_kernel<<<512, 256, 0, stream>>>(wo, wo_bf, DIM * DIM / 4);
  cvt_ilv_sw_kernel<<<1024, 256, 0, stream>>>(wg, wval, wgv_bf);
  cvt_kernel<<<1024, 256, 0, stream>>>(wp, wproj_bf, DIM * FF / 4);
  bias_ilv_kernel<<<16, 256, 0, stream>>>(bg, bval, bgv);
  hipMemcpyAsync(bqkv, bq, DIM * 4, hipMemcpyDeviceToDevice, stream);
  hipMemcpyAsync(bqkv + DIM, bk, DIM * 4, hipMemcpyDeviceToDevice, stream);
  hipMemcpyAsync(bqkv + 2 * DIM, bv, DIM * 4, hipMemcpyDeviceToDevice, stream);

  // 2) attn rmsnorm (swizzled out), fused QKV 256-gemm
  rmsnorm_kernel<<<MROWS, 256, 0, stream>>>(x, attn_w, h1);
  gemm256<0><<<dim3(12, 16), 512, 0, stream>>>(h1, wqkv_bf, bqkv, qkv, 3 * DIM, DIM);
  // 3) rope + cache concat
  rope_q_kernel<<<2048, 256, 0, stream>>>(qkv, cosT, sinT, Qb);
  rope_k_kernel<<<3072, 256, 0, stream>>>(qkv, cache_k, cosT, sinT, Kb);
  build_vt_kernel<<<3072, 256, 0, stream>>>(qkv, cache_v, Vtg);
  // 4) attention (grid: x=bh for CU load balance across qt)
  attn_kernel<<<dim3(B_SZ * NH, S_LEN / 64), 256, 0, stream>>>(
      Qb, Kb, Vtg, ctx, (2.0f / (float)(T_LEN - 1)) * LOG2E);
  // 5) o-proj + residual (fp32), skinny tile
  gemm_bt<1, 64><<<dim3(16, 32), 256, 0, stream>>>(ctx, wo_bf, bo, x, nullptr, x2,
                                                   DIM, DIM);
  // 6) ffn rmsnorm (swizzled out), gate+value 256-gemm w/ silu epilogue, proj + residual
  rmsnorm_kernel<<<MROWS, 256, 0, stream>>>(x2, ffn_w, h2);
  gemm256<2><<<dim3(32, 16), 512, 0, stream>>>(h2, wgv_bf, bgv, gated, 2 * FF, DIM);
  gemm_bt<1, 64><<<dim3(16, 32), 256, 0, stream>>>(gated, wproj_bf, bp, x2, nullptr, out,
                                                   DIM, FF);
}

// Round 6
// 383.188 us; speedup vs baseline: 1.4731x; 1.0098x over previous
//
#include <hip/hip_runtime.h>
#include <stdint.h>

typedef unsigned short u16;
typedef unsigned int   u32;
typedef __bf16 bf16x8 __attribute__((ext_vector_type(8)));
typedef float  f32x4  __attribute__((ext_vector_type(4)));
typedef u32    u32x4  __attribute__((ext_vector_type(4)));
typedef u32    u32x2  __attribute__((ext_vector_type(2)));

#define B_SZ  2
#define S_LEN 2048
#define NH    16
#define HD    64
#define DIM   1024
#define FF    4096
#define T_LEN 3072
#define PREV  1024
#define MROWS (B_SZ * S_LEN) /* 4096 */
#define LOG2E 1.44269504f

#define MFMA16 __builtin_amdgcn_mfma_f32_16x16x32_bf16

__device__ __forceinline__ u16 f2bf(float f) {
  u32 u = __builtin_bit_cast(u32, f);
  u32 r = u + 0x7FFFu + ((u >> 16) & 1u);
  return (u16)(r >> 16);
}
__device__ __forceinline__ float bf2f(u16 h) {
  u32 u = ((u32)h) << 16;
  return __builtin_bit_cast(float, u);
}
__device__ __forceinline__ u32 cvtpk(float lo, float hi) {
  u32 r;
  asm("v_cvt_pk_bf16_f32 %0, %1, %2" : "=v"(r) : "v"(lo), "v"(hi));
  return r;
}

// async global->LDS, 16B per lane. LDS dest must be wave-uniform base + lane*16.
__device__ __forceinline__ void gl_lds16(const void* g, void* l) {
  __builtin_amdgcn_global_load_lds(
      (const __attribute__((address_space(1))) u32*)g,
      (__attribute__((address_space(3))) u32*)l, 16, 0, 0);
}

#define GFENCE() asm volatile("" ::: "memory")
#define BARF()                         \
  do {                                 \
    GFENCE();                          \
    __builtin_amdgcn_s_barrier();      \
    GFENCE();                          \
  } while (0)

// ---------------- fp32 -> bf16 convert (linear, for 3-buf GEMM weights) ----------------
__global__ __launch_bounds__(256) void cvt_kernel(const float* __restrict__ src,
                                                  u16* __restrict__ dst, int n4) {
  int i = blockIdx.x * 256 + threadIdx.x;
  const int stride = gridDim.x * 256;
  for (; i < n4; i += stride) {
    f32x4 v = *(const f32x4*)&src[(long)i * 4];
    u32x2 o;
    o[0] = (u32)f2bf(v[0]) | ((u32)f2bf(v[1]) << 16);
    o[1] = (u32)f2bf(v[2]) | ((u32)f2bf(v[3]) << 16);
    *(u32x2*)&dst[(long)i * 4] = o;
  }
}

// ---------------- fp32 -> bf16, K-unit XOR-preswizzled (K=1024) ----------------
// dst[row][ (g&~7)|((g&7)^(row&7)) ] = src 16B unit g.
__global__ __launch_bounds__(256) void cvt_sw_kernel(const float* __restrict__ src,
                                                     u16* __restrict__ dst, int nunits) {
  int i = blockIdx.x * 256 + threadIdx.x;  // unit index over rows*(1024/8)
  const int stride = gridDim.x * 256;
  for (; i < nunits; i += stride) {
    int row = i >> 7;
    int g = i & 127;
    const float* s = &src[((long)row << 10) + g * 8];
    f32x4 a = *(const f32x4*)s;
    f32x4 b = *(const f32x4*)(s + 4);
    u32x4 o;
    o[0] = (u32)f2bf(a[0]) | ((u32)f2bf(a[1]) << 16);
    o[1] = (u32)f2bf(a[2]) | ((u32)f2bf(a[3]) << 16);
    o[2] = (u32)f2bf(b[0]) | ((u32)f2bf(b[1]) << 16);
    o[3] = (u32)f2bf(b[2]) | ((u32)f2bf(b[3]) << 16);
    const int gp = (g & ~7) | ((g & 7) ^ (row & 7));
    *(u32x4*)&dst[((long)row << 10) + gp * 8] = o;
  }
}

// interleave wg/wval rows (dst row 2j = wg[j], 2j+1 = wval[j]), preswizzled, K=1024
__global__ __launch_bounds__(256) void cvt_ilv_sw_kernel(const float* __restrict__ wg,
                                                         const float* __restrict__ wval,
                                                         u16* __restrict__ dst) {
  int i = blockIdx.x * 256 + threadIdx.x;  // FF * 128 units
  const int stride = gridDim.x * 256;
  for (; i < FF * 128; i += stride) {
    int j = i >> 7;
    int g = i & 127;
    const float* sg = &wg[((long)j << 10) + g * 8];
    const float* sv = &wval[((long)j << 10) + g * 8];
    f32x4 a = *(const f32x4*)sg;
    f32x4 b = *(const f32x4*)(sg + 4);
    u32x4 og;
    og[0] = (u32)f2bf(a[0]) | ((u32)f2bf(a[1]) << 16);
    og[1] = (u32)f2bf(a[2]) | ((u32)f2bf(a[3]) << 16);
    og[2] = (u32)f2bf(b[0]) | ((u32)f2bf(b[1]) << 16);
    og[3] = (u32)f2bf(b[2]) | ((u32)f2bf(b[3]) << 16);
    f32x4 c = *(const f32x4*)sv;
    f32x4 d = *(const f32x4*)(sv + 4);
    u32x4 ov;
    ov[0] = (u32)f2bf(c[0]) | ((u32)f2bf(c[1]) << 16);
    ov[1] = (u32)f2bf(c[2]) | ((u32)f2bf(c[3]) << 16);
    ov[2] = (u32)f2bf(d[0]) | ((u32)f2bf(d[1]) << 16);
    ov[3] = (u32)f2bf(d[2]) | ((u32)f2bf(d[3]) << 16);
    const int rg = 2 * j, rv = 2 * j + 1;
    const int gpg = (g & ~7) | ((g & 7) ^ (rg & 7));
    const int gpv = (g & ~7) | ((g & 7) ^ (rv & 7));
    *(u32x4*)&dst[((long)rg << 10) + gpg * 8] = og;
    *(u32x4*)&dst[((long)rv << 10) + gpv * 8] = ov;
  }
}

// interleave biases: dst[2i]=bg[i], dst[2i+1]=bval[i]
__global__ __launch_bounds__(256) void bias_ilv_kernel(const float* __restrict__ bg,
                                                       const float* __restrict__ bval,
                                                       float* __restrict__ dst) {
  int i = blockIdx.x * 256 + threadIdx.x;
  if (i < FF) {
    dst[2 * i] = bg[i];
    dst[2 * i + 1] = bval[i];
  }
}

// ---------------- RMSNorm: fp32 row -> bf16 row, K-unit XOR-preswizzled out ----------------
__global__ __launch_bounds__(256) void rmsnorm_kernel(const float* __restrict__ x,
                                                      const float* __restrict__ w,
                                                      u16* __restrict__ out) {
  const int row = blockIdx.x;
  const int tid = threadIdx.x;
  const long base = (long)row * DIM + tid * 4;
  f32x4 v = *(const f32x4*)&x[base];
  float ss = v[0] * v[0] + v[1] * v[1] + v[2] * v[2] + v[3] * v[3];
#pragma unroll
  for (int d = 1; d <= 32; d <<= 1) ss += __shfl_xor(ss, d, 64);
  __shared__ float red[4];
  if ((tid & 63) == 0) red[tid >> 6] = ss;
  __syncthreads();
  float tot = red[0] + red[1] + red[2] + red[3];
  const float sc = rsqrtf(tot * (1.f / (float)DIM) + 1e-6f);
  f32x4 wv4 = *(const f32x4*)&w[tid * 4];
  u32x2 o;
  o[0] = (u32)f2bf(v[0] * sc * wv4[0]) | ((u32)f2bf(v[1] * sc * wv4[1]) << 16);
  o[1] = (u32)f2bf(v[2] * sc * wv4[2]) | ((u32)f2bf(v[3] * sc * wv4[3]) << 16);
  const int u = tid >> 1, hf = tid & 1;
  const int up = (u & 0x78) | ((u & 7) ^ (row & 7));
  *(u32x2*)&out[(long)row * DIM + up * 8 + hf * 4] = o;
}

// ---------------- 256x256 8-phase GEMM (T2+T3+T4+T5), K multiple of 64 ----------------
template <int EPI>
__global__ __launch_bounds__(512, 2) void gemm256(const u16* __restrict__ A,
                                                  const u16* __restrict__ Bw,
                                                  const float* __restrict__ bias,
                                                  u16* __restrict__ out_bf,
                                                  int N, int K) {
  __shared__ __align__(16) u16 Ab[2][256 * 64];
  __shared__ __align__(16) u16 Bb[2][256 * 64];
  const int tid = threadIdx.x;
  const int lane = tid & 63;
  const int wid = tid >> 6;
  const int wm = wid >> 2, wn = wid & 3;
  const int l15 = lane & 15, lhi = lane >> 4;
  const int c7 = l15 & 7;
  const long m0 = (long)blockIdx.y * 256;
  const long n0 = (long)blockIdx.x * 256;
  const int NT = K >> 6;

  const int srow = tid >> 3;
  const int sunit = (tid & 7) * 8;
  const u16* agp = A + (m0 + srow) * K + sunit;
  const u16* bgp = Bw + (n0 + srow) * K + sunit;
  const int ldst = tid * 8;

  auto stageA = [&](int kt, int b) {
    const int k0 = kt << 6;
    u16* d = &Ab[b][0];
#pragma unroll
    for (int c = 0; c < 4; ++c)
      gl_lds16(agp + (long)(c * 64) * K + k0, d + c * 4096 + ldst);
  };
  auto stageB = [&](int kt, int b) {
    const int k0 = kt << 6;
    u16* d = &Bb[b][0];
#pragma unroll
    for (int c = 0; c < 4; ++c)
      gl_lds16(bgp + (long)(c * 64) * K + k0, d + c * 4096 + ldst);
  };

#define READ_A(MH)                                                               \
  _Pragma("unroll") for (int m_ = 0; m_ < 4; ++m_) {                             \
    _Pragma("unroll") for (int ks_ = 0; ks_ < 2; ++ks_) {                        \
      Afr[MH][m_ * 2 + ks_] =                                                    \
          *(const bf16x8*)&Ac[(wm * 128 + (MH)*64 + m_ * 16 + l15) * 64 +        \
                              (((ks_ * 4 + lhi) ^ c7) * 8)];                     \
    }                                                                            \
  }
#define READ_B(NH)                                                               \
  _Pragma("unroll") for (int n_ = 0; n_ < 2; ++n_) {                             \
    _Pragma("unroll") for (int ks_ = 0; ks_ < 2; ++ks_) {                        \
      Bfr[NH][n_ * 2 + ks_] =                                                    \
          *(const bf16x8*)&Bc[(wn * 64 + (NH)*32 + n_ * 16 + l15) * 64 +         \
                              (((ks_ * 4 + lhi) ^ c7) * 8)];                     \
    }                                                                            \
  }
#define QUAD(MH, NH)                                                             \
  do {                                                                           \
    __builtin_amdgcn_s_setprio(1);                                               \
    _Pragma("unroll") for (int m_ = 0; m_ < 4; ++m_) {                           \
      _Pragma("unroll") for (int n_ = 0; n_ < 2; ++n_) {                         \
        acc[(MH)*4 + m_][(NH)*2 + n_] =                                          \
            MFMA16(Afr[MH][m_ * 2], Bfr[NH][n_ * 2],                             \
                   acc[(MH)*4 + m_][(NH)*2 + n_], 0, 0, 0);                      \
        acc[(MH)*4 + m_][(NH)*2 + n_] =                                          \
            MFMA16(Afr[MH][m_ * 2 + 1], Bfr[NH][n_ * 2 + 1],                     \
                   acc[(MH)*4 + m_][(NH)*2 + n_], 0, 0, 0);                      \
      }                                                                          \
    }                                                                            \
    __builtin_amdgcn_s_setprio(0);                                               \
  } while (0)

  f32x4 acc[8][4] = {};

  // prologue: tiles 0,1 staged; wait tile 0 (tile 1 stays in flight)
  stageA(0, 0);
  stageB(0, 0);
  stageA(1, 1);
  stageB(1, 1);
  asm volatile("s_waitcnt vmcnt(8)" ::: "memory");
  __builtin_amdgcn_s_barrier();
  GFENCE();

  for (int kt = 0; kt < NT; ++kt) {
    const int b = kt & 1;
    const u16* Ac = &Ab[b][0];
    const u16* Bc = &Bb[b][0];
    bf16x8 Afr[2][8], Bfr[2][4];
    // P0: read A-half0 + B-half0
    READ_A(0);
    READ_B(0);
    BARF();
    QUAD(0, 0);
    BARF();
    // P1: read A-half1 + B-half1
    READ_A(1);
    READ_B(1);
    BARF();
    QUAD(0, 1);
    BARF();
    // P2: stage A(kt+2) (A regions free after P1)
    if (kt + 2 < NT) stageA(kt + 2, b);
    BARF();
    QUAD(1, 0);
    BARF();
    // P3: stage B(kt+2)
    if (kt + 2 < NT) stageB(kt + 2, b);
    BARF();
    QUAD(1, 1);
    // K-tile boundary: next tile must be resident; keep prefetch in flight
    if (kt + 1 < NT) {
      if (kt + 2 < NT)
        asm volatile("s_waitcnt vmcnt(8)" ::: "memory");
      else
        asm volatile("s_waitcnt vmcnt(0)" ::: "memory");
      __builtin_amdgcn_s_barrier();
      GFENCE();
    }
  }
#undef READ_A
#undef READ_B
#undef QUAD

#pragma unroll
  for (int mi = 0; mi < 8; ++mi) {
    const long row0 = m0 + wm * 128 + mi * 16 + lhi * 4;
#pragma unroll
    for (int ni = 0; ni < 4; ++ni) {
      const long col = n0 + wn * 64 + ni * 16 + l15;
      const float bb = bias[col];
#pragma unroll
      for (int r = 0; r < 4; ++r) {
        float v = acc[mi][ni][r] + bb;
        if (EPI == 2) {
          float other = __shfl_xor(v, 1, 64);
          if (!(l15 & 1)) {
            float s = v / (1.f + __expf(-v)) * other;  // silu(g)*v
            out_bf[(row0 + r) * (N >> 1) + (col >> 1)] = f2bf(s);
          }
        } else {
          out_bf[(row0 + r) * N + col] = f2bf(v);
        }
      }
    }
  }
}

// ---------------- 3-buffer GEMM (linear layouts) for skinny N ----------------
template <int EPI, int NB>
__global__ __launch_bounds__(256) void gemm_bt(const u16* __restrict__ A,
                                               const u16* __restrict__ Bw,
                                               const float* __restrict__ bias,
                                               const float* __restrict__ resid,
                                               u16* __restrict__ out_bf,
                                               float* __restrict__ out_f,
                                               int N, int K) {
  constexpr int BHALF = NB / 64;
  constexpr int NFR = NB / 32;
  constexpr int LPT = 2 + BHALF;
  __shared__ __align__(16) u16 As[3][128 * 32];
  __shared__ __align__(16) u16 Bs[3][NB * 32];
  const int tid = threadIdx.x;
  const int lane = tid & 63;
  const int wv = tid >> 6;
  const int wr = wv >> 1, wc = wv & 1;
  const long m0 = (long)blockIdx.y * 128;
  const long n0 = (long)blockIdx.x * NB;

  const int arow = tid >> 2;
  const int acol = (tid & 3) << 3;
  const u16* ag = A + (m0 + arow) * K + acol;
  const u16* bg = Bw + (n0 + arow) * K + acol;
  const long hK = (long)64 * K;

  f32x4 acc[4][NFR] = {};
  const int l15 = lane & 15;
  const int lhi = lane >> 4;
  const int aoff0 = (wr * 64 + l15) * 32 + lhi * 8;
  const int boff0 = (wc * (NB / 2) + l15) * 32 + lhi * 8;
  const int nk = K >> 5;

  auto stage = [&](int t, int buf) {
    const int k0 = t << 5;
    gl_lds16(ag + k0, &As[buf][tid * 8]);
    gl_lds16(ag + k0 + hK, &As[buf][2048 + tid * 8]);
    gl_lds16(bg + k0, &Bs[buf][tid * 8]);
    if (BHALF == 2) gl_lds16(bg + k0 + hK, &Bs[buf][2048 + tid * 8]);
  };

  stage(0, 0);
  stage(1, 1);
  asm volatile("s_waitcnt vmcnt(%0)" ::"n"(LPT) : "memory");
  __builtin_amdgcn_s_barrier();
  GFENCE();

  for (int t = 0; t < nk; ++t) {
    const int cb = t % 3;
    if (t + 2 < nk) stage(t + 2, (t + 2) % 3);
    bf16x8 af[4], bfr[NFR];
#pragma unroll
    for (int i = 0; i < 4; ++i) af[i] = *(const bf16x8*)&As[cb][aoff0 + i * 16 * 32];
#pragma unroll
    for (int j = 0; j < NFR; ++j) bfr[j] = *(const bf16x8*)&Bs[cb][boff0 + j * 16 * 32];
    __builtin_amdgcn_s_setprio(1);
#pragma unroll
    for (int i = 0; i < 4; ++i)
#pragma unroll
      for (int j = 0; j < NFR; ++j)
        acc[i][j] = MFMA16(af[i], bfr[j], acc[i][j], 0, 0, 0);
    __builtin_amdgcn_s_setprio(0);
    if (t + 2 < nk) {
      asm volatile("s_waitcnt vmcnt(%0)" ::"n"(LPT) : "memory");
      __builtin_amdgcn_s_barrier();
      GFENCE();
    } else if (t + 1 < nk) {
      asm volatile("s_waitcnt vmcnt(0)" ::: "memory");
      __builtin_amdgcn_s_barrier();
      GFENCE();
    }
  }

#pragma unroll
  for (int i = 0; i < 4; ++i) {
    const long row0 = m0 + wr * 64 + i * 16 + lhi * 4;
#pragma unroll
    for (int j = 0; j < NFR; ++j) {
      const long col = n0 + wc * (NB / 2) + j * 16 + l15;
      const float bb = bias[col];
#pragma unroll
      for (int r = 0; r < 4; ++r) {
        const long idx = (row0 + r) * N + col;
        float v = acc[i][j][r] + bb;
        if (EPI == 0) out_bf[idx] = f2bf(v);
        else          out_f[idx] = resid[idx] + v;
      }
    }
  }
}

// ---------------- RoPE on Q, pre-scaled by 0.125*log2(e) ----------------
__global__ __launch_bounds__(256) void rope_q_kernel(const u16* __restrict__ qkv,
                                                     const float* __restrict__ cosT,
                                                     const float* __restrict__ sinT,
                                                     u16* __restrict__ Q) {
  int idx = blockIdx.x * 256 + threadIdx.x;  // B*H*S*8 = 524288 units of 8 elems
  int u = idx & 7;
  int s = (idx >> 3) & (S_LEN - 1);
  int bh = idx >> 14;
  int b = bh >> 4, h = bh & 15;
  int pos = PREV + s;
  const float SC = 0.125f * LOG2E;
  const u16* src = qkv + ((long)(b * S_LEN + s)) * (3 * DIM) + h * HD + u * 8;
  u32x4 d = *(const u32x4*)src;
  f32x4 cv = *(const f32x4*)&cosT[(long)pos * 32 + u * 4];
  f32x4 sv = *(const f32x4*)&sinT[(long)pos * 32 + u * 4];
  u32x4 o;
#pragma unroll
  for (int p = 0; p < 4; ++p) {
    float x0 = bf2f((u16)(d[p] & 0xffff));
    float x1 = bf2f((u16)(d[p] >> 16));
    float y0 = (x0 * cv[p] - x1 * sv[p]) * SC;
    float y1 = (x0 * sv[p] + x1 * cv[p]) * SC;
    o[p] = (u32)f2bf(y0) | ((u32)f2bf(y1) << 16);
  }
  *(u32x4*)&Q[((long)bh * S_LEN + s) * HD + u * 8] = o;
}

// ---------------- K_all = rope(concat(cache_k, k_new)); stored XOR-swizzled ----------------
__global__ __launch_bounds__(256) void rope_k_kernel(const u16* __restrict__ qkv,
                                                     const float* __restrict__ cache_k,
                                                     const float* __restrict__ cosT,
                                                     const float* __restrict__ sinT,
                                                     u16* __restrict__ Kall) {
  int idx = blockIdx.x * 256 + threadIdx.x;  // B*H*T*8 = 786432
  int u = idx & 7;
  int t2 = idx >> 3;
  int j = t2 % T_LEN;
  int bh = t2 / T_LEN;
  int b = bh >> 4, h = bh & 15;
  float e[8];
  if (j < PREV) {
    const float* src = cache_k + ((long)bh * PREV + j) * HD + u * 8;
    f32x4 a = *(const f32x4*)src;
    f32x4 c = *(const f32x4*)(src + 4);
    e[0] = a[0]; e[1] = a[1]; e[2] = a[2]; e[3] = a[3];
    e[4] = c[0]; e[5] = c[1]; e[6] = c[2]; e[7] = c[3];
  } else {
    const u16* src = qkv + ((long)(b * S_LEN + (j - PREV))) * (3 * DIM) + DIM + h * HD + u * 8;
    u32x4 d = *(const u32x4*)src;
#pragma unroll
    for (int p = 0; p < 4; ++p) {
      e[2 * p] = bf2f((u16)(d[p] & 0xffff));
      e[2 * p + 1] = bf2f((u16)(d[p] >> 16));
    }
  }
  f32x4 cv = *(const f32x4*)&cosT[(long)j * 32 + u * 4];
  f32x4 sv = *(const f32x4*)&sinT[(long)j * 32 + u * 4];
  u32x4 o;
#pragma unroll
  for (int p = 0; p < 4; ++p) {
    float y0 = e[2 * p] * cv[p] - e[2 * p + 1] * sv[p];
    float y1 = e[2 * p] * sv[p] + e[2 * p + 1] * cv[p];
    o[p] = (u32)f2bf(y0) | ((u32)f2bf(y1) << 16);
  }
  *(u32x4*)&Kall[((long)bh * T_LEN + j) * HD + (u ^ (j & 7)) * 8] = o;
}

// ---------------- Vt_global[bh][hd][key], XOR-swizzled within 64-key spans ----------------
__global__ __launch_bounds__(256) void build_vt_kernel(const u16* __restrict__ qkv,
                                                       const float* __restrict__ cache_v,
                                                       u16* __restrict__ Vtg) {
  int idx = blockIdx.x * 256 + threadIdx.x;  // 32 * 384 * 64 = 786432
  int hd = idx & 63;
  int t2 = idx >> 6;
  int kb = t2 % 384;  // 8-key block
  int bh = t2 / 384;
  int b = bh >> 4, h = bh & 15;
  int key0 = kb * 8;
  u16 vals[8];
  if (key0 < PREV) {
#pragma unroll
    for (int i = 0; i < 8; ++i)
      vals[i] = f2bf(cache_v[((long)bh * PREV + key0 + i) * HD + hd]);
  } else {
#pragma unroll
    for (int i = 0; i < 8; ++i)
      vals[i] = qkv[((long)(b * S_LEN + key0 + i - PREV)) * (3 * DIM) + 2 * DIM + h * HD + hd];
  }
  u32x4 o;
#pragma unroll
  for (int p = 0; p < 4; ++p)
    o[p] = (u32)vals[2 * p] | ((u32)vals[2 * p + 1] << 16);
  const int span = kb >> 3;
  const int u = (kb & 7) ^ (hd & 7);
  *(u32x4*)&Vtg[((long)bh * HD + hd) * T_LEN + span * 64 + u * 8] = o;
}

// ---------------- flash attention, swapped-operand, dbuf, VALU-lean softmax ----------------
// Softmax shift-invariance: bias slope*(j-i) -> slope*j (row const cancels). Per-thread
// bias constants be[], per-tile scalar ktf folded into m_eff. Mask only on final tile
// (uniform branch). Row-sum via MFMA ones-trick; lrun kept in O-domain (f32x4).
__global__ __launch_bounds__(256, 4) void attn_kernel(const u16* __restrict__ Q,
                                                      const u16* __restrict__ Kg,
                                                      const u16* __restrict__ Vtg,
                                                      u16* __restrict__ ctx, float slope2) {
  __shared__ __align__(16) u16 Ks[2][64 * 64];  // [key][d], swizzled
  __shared__ __align__(16) u16 Vs[2][64 * 64];  // [hd][key], swizzled
  __shared__ __align__(16) u16 Ps[4][16 * 64];  // per-wave P[q][key], swizzled

  const int tid = threadIdx.x;
  const int lane = tid & 63;
  const int wv = tid >> 6;
  const int l15 = lane & 15;
  const int lhi = lane >> 4;
  const int c7 = l15 & 7;
  const int bh = blockIdx.x;       // balance: co-resident blocks differ in qt
  const int qt = blockIdx.y;
  const int b = bh >> 4, h = bh & 15;
  const int q0 = qt * 64;
  const int nt = (PREV + q0 + 64) >> 6;

  const long qrow = (long)bh * S_LEN + q0 + wv * 16 + l15;
  bf16x8 aq0 = *(const bf16x8*)&Q[qrow * HD + lhi * 8];
  bf16x8 aq1 = *(const bf16x8*)&Q[qrow * HD + 32 + lhi * 8];

  const long kgb = (long)bh * T_LEN * HD;  // K: [key][64]
  const long vgb = (long)bh * HD * T_LEN;  // Vt: [hd][T]
  const int srow = tid >> 3;               // staging row 0..31
  const int sunit = (tid & 7) * 8;

  const u16* kst = Kg + kgb + (long)srow * HD + sunit;     // +64*HD per tile
  const u16* vst = Vtg + vgb + (long)srow * T_LEN + sunit; // +64 per tile

  // prologue: stage tile 0
  gl_lds16(kst, &Ks[0][tid * 8]);
  gl_lds16(kst + 32 * HD, &Ks[0][2048 + tid * 8]);
  gl_lds16(vst, &Vs[0][tid * 8]);
  gl_lds16(vst + (long)32 * T_LEN, &Vs[0][2048 + tid * 8]);
  kst += 64 * HD;
  vst += 64;
  __syncthreads();

  f32x4 o[4] = {};
  f32x4 lrun = {0.f, 0.f, 0.f, 0.f};  // O-domain: row r = q_local 4*lhi+r
  float mrun = -1e30f;                // l15-domain (q = l15), abs-bias units
  const int qq = wv * 16 + l15;       // local q (mask threshold in final tile)
  u16* Pw = &Ps[wv][0];

  f32x4 be[4];  // per-thread bias constants slope*(jf*16+4*lhi+r)
#pragma unroll
  for (int jf = 0; jf < 4; ++jf)
#pragma unroll
    for (int r = 0; r < 4; ++r)
      be[jf][r] = slope2 * (float)(jf * 16 + 4 * lhi + r);
  const float bmax = slope2 * 63.f;

  bf16x8 vones;
#pragma unroll
  for (int e = 0; e < 8; ++e) vones[e] = (__bf16)1.0f;

  float ktf = 0.f;
  const float kstep = slope2 * 64.f;

  for (int t = 0; t < nt; ++t) {
    const int cur = t & 1, nxt = cur ^ 1;
    const bool last = (t == nt - 1);
    if (!last) {
      gl_lds16(kst, &Ks[nxt][tid * 8]);
      gl_lds16(kst + 32 * HD, &Ks[nxt][2048 + tid * 8]);
      gl_lds16(vst, &Vs[nxt][tid * 8]);
      gl_lds16(vst + (long)32 * T_LEN, &Vs[nxt][2048 + tid * 8]);
      kst += 64 * HD;
      vst += 64;
    }

    // S^T = K * Q^T : per wave [64 key][16 q]
    f32x4 sf[4];
    __builtin_amdgcn_s_setprio(1);
#pragma unroll
    for (int jf = 0; jf < 4; ++jf) {
      const int krow = jf * 16 + l15;
      bf16x8 ak0 = *(const bf16x8*)&Ks[cur][krow * 64 + ((lhi ^ c7) * 8)];
      bf16x8 ak1 = *(const bf16x8*)&Ks[cur][krow * 64 + (((4 + lhi) ^ c7) * 8)];
      f32x4 s = {};
      s = MFMA16(ak0, aq0, s, 0, 0, 0);
      s = MFMA16(ak1, aq1, s, 0, 0, 0);
      sf[jf] = s;
    }
    __builtin_amdgcn_s_setprio(0);

    if (last) {  // causal mask (triangular final tile): key jloc > qq
#pragma unroll
      for (int jf = 0; jf < 4; ++jf)
#pragma unroll
        for (int r = 0; r < 4; ++r)
          if (jf * 16 + 4 * lhi + r > qq) sf[jf][r] = -1e30f;
    }

    // raw row-max (bias bounded by bmax; defer-max absorbs the slack)
    float h0 = fmaxf(fmaxf(sf[0][0], sf[0][1]), fmaxf(sf[0][2], sf[0][3]));
    float h1 = fmaxf(fmaxf(sf[1][0], sf[1][1]), fmaxf(sf[1][2], sf[1][3]));
    float h2 = fmaxf(fmaxf(sf[2][0], sf[2][1]), fmaxf(sf[2][2], sf[2][3]));
    float h3 = fmaxf(fmaxf(sf[3][0], sf[3][1]), fmaxf(sf[3][2], sf[3][3]));
    float pm = fmaxf(fmaxf(h0, h1), fmaxf(h2, h3));
    pm = fmaxf(pm, __shfl_xor(pm, 16, 64));
    pm = fmaxf(pm, __shfl_xor(pm, 32, 64));
    const float pmax_abs = pm + ktf + bmax;  // upper bound of true abs max

    if (!__all(pmax_abs - mrun <= 8.f)) {
      const float mnew = fmaxf(mrun, pmax_abs);
      const float scl = exp2f(mrun - mnew);
      mrun = mnew;
#pragma unroll
      for (int r = 0; r < 4; ++r) {
        const float sr = __shfl(scl, 4 * lhi + r, 64);  // scale for q row 4*lhi+r
        lrun[r] *= sr;
#pragma unroll
        for (int hf = 0; hf < 4; ++hf) o[hf][r] *= sr;
      }
    }
    const float meff = mrun - ktf;

    // P = exp2(s + be - meff), pack pairs, swizzled b64 writes to per-wave LDS
#pragma unroll
    for (int jf = 0; jf < 4; ++jf) {
      f32x4 p;
#pragma unroll
      for (int r = 0; r < 4; ++r)
        p[r] = exp2f(sf[jf][r] + (be[jf][r] - meff));
      u32x2 pw2;
      pw2[0] = cvtpk(p[0], p[1]);
      pw2[1] = cvtpk(p[2], p[3]);
      const int u = (2 * jf + (lhi >> 1)) ^ c7;
      *(u32x2*)&Pw[l15 * 64 + u * 8 + (lhi & 1) * 4] = pw2;
    }

    // O += P * V ; row-sum via ones-MFMA (lrun in O-domain)
    bf16x8 pa0 = *(const bf16x8*)&Pw[l15 * 64 + ((lhi ^ c7) * 8)];
    bf16x8 pa1 = *(const bf16x8*)&Pw[l15 * 64 + (((4 + lhi) ^ c7) * 8)];
    f32x4 psum = {};
    __builtin_amdgcn_s_setprio(1);
    psum = MFMA16(pa0, vones, psum, 0, 0, 0);
    psum = MFMA16(pa1, vones, psum, 0, 0, 0);
#pragma unroll
    for (int hf = 0; hf < 4; ++hf) {
      const int vrow = hf * 16 + l15;
      bf16x8 bv0 = *(const bf16x8*)&Vs[cur][vrow * 64 + ((lhi ^ c7) * 8)];
      bf16x8 bv1 = *(const bf16x8*)&Vs[cur][vrow * 64 + (((4 + lhi) ^ c7) * 8)];
      o[hf] = MFMA16(pa0, bv0, o[hf], 0, 0, 0);
      o[hf] = MFMA16(pa1, bv1, o[hf], 0, 0, 0);
    }
    __builtin_amdgcn_s_setprio(0);
    lrun += psum;

    ktf += kstep;
    if (!last) __syncthreads();  // staged loads landed + all reads of cur done
  }

  // epilogue: O rows are q_local = 4*lhi + r; cols hd = hf*16 + l15
#pragma unroll
  for (int r = 0; r < 4; ++r) {
    const float inv = 1.f / lrun[r];
    const long srow_ = (long)b * S_LEN + q0 + wv * 16 + 4 * lhi + r;
#pragma unroll
    for (int hf = 0; hf < 4; ++hf)
      ctx[srow_ * DIM + h * HD + hf * 16 + l15] = f2bf(o[hf][r] * inv);
  }
}

// ---------------------------------------------------------------------------
extern "C" void kernel_launch(void* const* d_in, const int* in_sizes, int n_in,
                              void* d_out, int out_size, void* d_ws, size_t ws_size,
                              hipStream_t stream) {
  (void)in_sizes; (void)n_in; (void)out_size; (void)ws_size;
  const float* x       = (const float*)d_in[0];
  const float* cache_k = (const float*)d_in[1];
  const float* cache_v = (const float*)d_in[2];
  const float* cosT    = (const float*)d_in[3];
  const float* sinT    = (const float*)d_in[4];
  const float* attn_w  = (const float*)d_in[5];
  const float* ffn_w   = (const float*)d_in[6];
  const float* wq      = (const float*)d_in[7];
  const float* bq      = (const float*)d_in[8];
  const float* wk      = (const float*)d_in[9];
  const float* bk      = (const float*)d_in[10];
  const float* wv_     = (const float*)d_in[11];
  const float* bv      = (const float*)d_in[12];
  const float* wo      = (const float*)d_in[13];
  const float* bo      = (const float*)d_in[14];
  const float* wg      = (const float*)d_in[15];
  const float* bg      = (const float*)d_in[16];
  const float* wval    = (const float*)d_in[17];
  const float* bval    = (const float*)d_in[18];
  const float* wp      = (const float*)d_in[19];
  const float* bp      = (const float*)d_in[20];
  float* out = (float*)d_out;

  char* w = (char*)d_ws;
  size_t off = 0;
  auto alloc = [&](size_t bytes) -> char* {
    char* p = w + off;
    off += (bytes + 255) & ~(size_t)255;
    return p;
  };
  // permanent
  u16*   wqkv_bf  = (u16*)alloc((size_t)3 * DIM * DIM * 2);  // preswizzled
  u16*   wo_bf    = (u16*)alloc((size_t)DIM * DIM * 2);      // linear
  u16*   wgv_bf   = (u16*)alloc((size_t)2 * FF * DIM * 2);   // interleaved+preswizzled
  u16*   wproj_bf = (u16*)alloc((size_t)DIM * FF * 2);       // linear
  float* bqkv     = (float*)alloc((size_t)3 * DIM * 4);
  float* bgv      = (float*)alloc((size_t)2 * FF * 4);       // interleaved
  float* x2       = (float*)alloc((size_t)MROWS * DIM * 4);
  // arena with lifetime-based aliasing
  char* AR = alloc((size_t)117440512);
  u16* qkv   = (u16*)(AR + 0);          // [4096][3072]   live: qkv gemm -> rope/build
  u16* Qb    = (u16*)(AR + 25165824);   // [32][2048][64] live: rope -> attn
  u16* Kb    = (u16*)(AR + 33554432);   // [32][3072][64]
  u16* Vtg   = (u16*)(AR + 46137344);   // [32][64][3072] transposed V
  u16* h1    = (u16*)(AR + 58720256);   // [4096][1024]   preswizzled (qkv gemm A)
  u16* ctx   = (u16*)(AR + 0);          // [4096][1024]   linear (aliases dead qkv)
  u16* h2    = (u16*)(AR + 8388608);    // [4096][1024]   preswizzled (gv gemm A)
  u16* gated = (u16*)(AR + 16777216);   // [4096][4096]   linear

  // 1) weights -> bf16 (preswizzled for 256-GEMMs; linear for skinny GEMMs)
  cvt_sw_kernel<<<512, 256, 0, stream>>>(wq, wqkv_bf, DIM * DIM / 8);
  cvt_sw_kernel<<<512, 256, 0, stream>>>(wk, wqkv_bf + DIM * DIM, DIM * DIM / 8);
  cvt_sw_kernel<<<512, 256, 0, stream>>>(wv_, wqkv_bf + 2 * DIM * DIM, DIM * DIM / 8);
  cvt_kernel<<<512, 256, 0, stream>>>(wo, wo_bf, DIM * DIM / 4);
  cvt_ilv_sw_kernel<<<1024, 256, 0, stream>>>(wg, wval, wgv_bf);
  cvt_kernel<<<1024, 256, 0, stream>>>(wp, wproj_bf, DIM * FF / 4);
  bias_ilv_kernel<<<16, 256, 0, stream>>>(bg, bval, bgv);
  hipMemcpyAsync(bqkv, bq, DIM * 4, hipMemcpyDeviceToDevice, stream);
  hipMemcpyAsync(bqkv + DIM, bk, DIM * 4, hipMemcpyDeviceToDevice, stream);
  hipMemcpyAsync(bqkv + 2 * DIM, bv, DIM * 4, hipMemcpyDeviceToDevice, stream);

  // 2) attn rmsnorm (swizzled out), fused QKV 256-gemm
  rmsnorm_kernel<<<MROWS, 256, 0, stream>>>(x, attn_w, h1);
  gemm256<0><<<dim3(12, 16), 512, 0, stream>>>(h1, wqkv_bf, bqkv, qkv, 3 * DIM, DIM);
  // 3) rope + cache concat
  rope_q_kernel<<<2048, 256, 0, stream>>>(qkv, cosT, sinT, Qb);
  rope_k_kernel<<<3072, 256, 0, stream>>>(qkv, cache_k, cosT, sinT, Kb);
  build_vt_kernel<<<3072, 256, 0, stream>>>(qkv, cache_v, Vtg);
  // 4) attention (grid: x=bh for CU load balance across qt)
  attn_kernel<<<dim3(B_SZ * NH, S_LEN / 64), 256, 0, stream>>>(
      Qb, Kb, Vtg, ctx, (2.0f / (float)(T_LEN - 1)) * LOG2E);
  // 5) o-proj + residual (fp32), skinny tile
  gemm_bt<1, 64><<<dim3(16, 32), 256, 0, stream>>>(ctx, wo_bf, bo, x, nullptr, x2,
                                                   DIM, DIM);
  // 6) ffn rmsnorm (swizzled out), gate+value 256-gemm w/ silu epilogue, proj + residual
  rmsnorm_kernel<<<MROWS, 256, 0, stream>>>(x2, ffn_w, h2);
  gemm256<2><<<dim3(32, 16), 512, 0, stream>>>(h2, wgv_bf, bgv, gated, 2 * FF, DIM);
  gemm_bt<1, 64><<<dim3(16, 32), 256, 0, stream>>>(gated, wproj_bf, bp, x2, nullptr, out,
                                                   DIM, FF);
}

// Round 7
// 372.605 us; speedup vs baseline: 1.5149x; 1.0284x over previous
//
#include <hip/hip_runtime.h>
#include <stdint.h>

typedef unsigned short u16;
typedef unsigned int   u32;
typedef __bf16 bf16x8 __attribute__((ext_vector_type(8)));
typedef float  f32x4  __attribute__((ext_vector_type(4)));
typedef u32    u32x4  __attribute__((ext_vector_type(4)));
typedef u32    u32x2  __attribute__((ext_vector_type(2)));

#define B_SZ  2
#define S_LEN 2048
#define NH    16
#define HD    64
#define DIM   1024
#define FF    4096
#define T_LEN 3072
#define PREV  1024
#define MROWS (B_SZ * S_LEN) /* 4096 */
#define LOG2E 1.44269504f

#define MFMA16 __builtin_amdgcn_mfma_f32_16x16x32_bf16

__device__ __forceinline__ u16 f2bf(float f) {
  u32 u = __builtin_bit_cast(u32, f);
  u32 r = u + 0x7FFFu + ((u >> 16) & 1u);
  return (u16)(r >> 16);
}
__device__ __forceinline__ float bf2f(u16 h) {
  u32 u = ((u32)h) << 16;
  return __builtin_bit_cast(float, u);
}
__device__ __forceinline__ u32 cvtpk(float lo, float hi) {
  u32 r;
  asm("v_cvt_pk_bf16_f32 %0, %1, %2" : "=v"(r) : "v"(lo), "v"(hi));
  return r;
}

// async global->LDS, 16B per lane. LDS dest must be wave-uniform base + lane*16.
__device__ __forceinline__ void gl_lds16(const void* g, void* l) {
  __builtin_amdgcn_global_load_lds(
      (const __attribute__((address_space(1))) u32*)g,
      (__attribute__((address_space(3))) u32*)l, 16, 0, 0);
}

#define GFENCE() asm volatile("" ::: "memory")
#define BARF()                         \
  do {                                 \
    GFENCE();                          \
    __builtin_amdgcn_s_barrier();      \
    GFENCE();                          \
  } while (0)

// ---------------- fp32 -> bf16 convert (linear, for 3-buf GEMM weights) ----------------
__global__ __launch_bounds__(256) void cvt_kernel(const float* __restrict__ src,
                                                  u16* __restrict__ dst, int n4) {
  int i = blockIdx.x * 256 + threadIdx.x;
  const int stride = gridDim.x * 256;
  for (; i < n4; i += stride) {
    f32x4 v = *(const f32x4*)&src[(long)i * 4];
    u32x2 o;
    o[0] = (u32)f2bf(v[0]) | ((u32)f2bf(v[1]) << 16);
    o[1] = (u32)f2bf(v[2]) | ((u32)f2bf(v[3]) << 16);
    *(u32x2*)&dst[(long)i * 4] = o;
  }
}

// ---------------- fp32 -> bf16, K-unit XOR-preswizzled (K=1024) ----------------
__global__ __launch_bounds__(256) void cvt_sw_kernel(const float* __restrict__ src,
                                                     u16* __restrict__ dst, int nunits) {
  int i = blockIdx.x * 256 + threadIdx.x;  // unit index over rows*(1024/8)
  const int stride = gridDim.x * 256;
  for (; i < nunits; i += stride) {
    int row = i >> 7;
    int g = i & 127;
    const float* s = &src[((long)row << 10) + g * 8];
    f32x4 a = *(const f32x4*)s;
    f32x4 b = *(const f32x4*)(s + 4);
    u32x4 o;
    o[0] = (u32)f2bf(a[0]) | ((u32)f2bf(a[1]) << 16);
    o[1] = (u32)f2bf(a[2]) | ((u32)f2bf(a[3]) << 16);
    o[2] = (u32)f2bf(b[0]) | ((u32)f2bf(b[1]) << 16);
    o[3] = (u32)f2bf(b[2]) | ((u32)f2bf(b[3]) << 16);
    const int gp = (g & ~7) | ((g & 7) ^ (row & 7));
    *(u32x4*)&dst[((long)row << 10) + gp * 8] = o;
  }
}

// interleave wg/wval rows (dst row 2j = wg[j], 2j+1 = wval[j]), preswizzled, K=1024
__global__ __launch_bounds__(256) void cvt_ilv_sw_kernel(const float* __restrict__ wg,
                                                         const float* __restrict__ wval,
                                                         u16* __restrict__ dst) {
  int i = blockIdx.x * 256 + threadIdx.x;  // FF * 128 units
  const int stride = gridDim.x * 256;
  for (; i < FF * 128; i += stride) {
    int j = i >> 7;
    int g = i & 127;
    const float* sg = &wg[((long)j << 10) + g * 8];
    const float* sv = &wval[((long)j << 10) + g * 8];
    f32x4 a = *(const f32x4*)sg;
    f32x4 b = *(const f32x4*)(sg + 4);
    u32x4 og;
    og[0] = (u32)f2bf(a[0]) | ((u32)f2bf(a[1]) << 16);
    og[1] = (u32)f2bf(a[2]) | ((u32)f2bf(a[3]) << 16);
    og[2] = (u32)f2bf(b[0]) | ((u32)f2bf(b[1]) << 16);
    og[3] = (u32)f2bf(b[2]) | ((u32)f2bf(b[3]) << 16);
    f32x4 c = *(const f32x4*)sv;
    f32x4 d = *(const f32x4*)(sv + 4);
    u32x4 ov;
    ov[0] = (u32)f2bf(c[0]) | ((u32)f2bf(c[1]) << 16);
    ov[1] = (u32)f2bf(c[2]) | ((u32)f2bf(c[3]) << 16);
    ov[2] = (u32)f2bf(d[0]) | ((u32)f2bf(d[1]) << 16);
    ov[3] = (u32)f2bf(d[2]) | ((u32)f2bf(d[3]) << 16);
    const int rg = 2 * j, rv = 2 * j + 1;
    const int gpg = (g & ~7) | ((g & 7) ^ (rg & 7));
    const int gpv = (g & ~7) | ((g & 7) ^ (rv & 7));
    *(u32x4*)&dst[((long)rg << 10) + gpg * 8] = og;
    *(u32x4*)&dst[((long)rv << 10) + gpv * 8] = ov;
  }
}

// interleave biases: dst[2i]=bg[i], dst[2i+1]=bval[i]
__global__ __launch_bounds__(256) void bias_ilv_kernel(const float* __restrict__ bg,
                                                       const float* __restrict__ bval,
                                                       float* __restrict__ dst) {
  int i = blockIdx.x * 256 + threadIdx.x;
  if (i < FF) {
    dst[2 * i] = bg[i];
    dst[2 * i + 1] = bval[i];
  }
}

// ---------------- RMSNorm: fp32 row -> bf16 row, K-unit XOR-preswizzled out ----------------
__global__ __launch_bounds__(256) void rmsnorm_kernel(const float* __restrict__ x,
                                                      const float* __restrict__ w,
                                                      u16* __restrict__ out) {
  const int row = blockIdx.x;
  const int tid = threadIdx.x;
  const long base = (long)row * DIM + tid * 4;
  f32x4 v = *(const f32x4*)&x[base];
  float ss = v[0] * v[0] + v[1] * v[1] + v[2] * v[2] + v[3] * v[3];
#pragma unroll
  for (int d = 1; d <= 32; d <<= 1) ss += __shfl_xor(ss, d, 64);
  __shared__ float red[4];
  if ((tid & 63) == 0) red[tid >> 6] = ss;
  __syncthreads();
  float tot = red[0] + red[1] + red[2] + red[3];
  const float sc = rsqrtf(tot * (1.f / (float)DIM) + 1e-6f);
  f32x4 wv4 = *(const f32x4*)&w[tid * 4];
  u32x2 o;
  o[0] = (u32)f2bf(v[0] * sc * wv4[0]) | ((u32)f2bf(v[1] * sc * wv4[1]) << 16);
  o[1] = (u32)f2bf(v[2] * sc * wv4[2]) | ((u32)f2bf(v[3] * sc * wv4[3]) << 16);
  const int u = tid >> 1, hf = tid & 1;
  const int up = (u & 0x78) | ((u & 7) ^ (row & 7));
  *(u32x2*)&out[(long)row * DIM + up * 8 + hf * 4] = o;
}

// ---------------- 256x256 8-phase GEMM (T2+T3+T4+T5), K multiple of 64 ----------------
template <int EPI>
__global__ __launch_bounds__(512, 2) void gemm256(const u16* __restrict__ A,
                                                  const u16* __restrict__ Bw,
                                                  const float* __restrict__ bias,
                                                  u16* __restrict__ out_bf,
                                                  int N, int K) {
  __shared__ __align__(16) u16 Ab[2][256 * 64];
  __shared__ __align__(16) u16 Bb[2][256 * 64];
  const int tid = threadIdx.x;
  const int lane = tid & 63;
  const int wid = tid >> 6;
  const int wm = wid >> 2, wn = wid & 3;
  const int l15 = lane & 15, lhi = lane >> 4;
  const int c7 = l15 & 7;
  const long m0 = (long)blockIdx.y * 256;
  const long n0 = (long)blockIdx.x * 256;
  const int NT = K >> 6;

  const int srow = tid >> 3;
  const int sunit = (tid & 7) * 8;
  const u16* agp = A + (m0 + srow) * K + sunit;
  const u16* bgp = Bw + (n0 + srow) * K + sunit;
  const int ldst = tid * 8;

  auto stageA = [&](int kt, int b) {
    const int k0 = kt << 6;
    u16* d = &Ab[b][0];
#pragma unroll
    for (int c = 0; c < 4; ++c)
      gl_lds16(agp + (long)(c * 64) * K + k0, d + c * 4096 + ldst);
  };
  auto stageB = [&](int kt, int b) {
    const int k0 = kt << 6;
    u16* d = &Bb[b][0];
#pragma unroll
    for (int c = 0; c < 4; ++c)
      gl_lds16(bgp + (long)(c * 64) * K + k0, d + c * 4096 + ldst);
  };

#define READ_A(MH)                                                               \
  _Pragma("unroll") for (int m_ = 0; m_ < 4; ++m_) {                             \
    _Pragma("unroll") for (int ks_ = 0; ks_ < 2; ++ks_) {                        \
      Afr[MH][m_ * 2 + ks_] =                                                    \
          *(const bf16x8*)&Ac[(wm * 128 + (MH)*64 + m_ * 16 + l15) * 64 +        \
                              (((ks_ * 4 + lhi) ^ c7) * 8)];                     \
    }                                                                            \
  }
#define READ_B(NH)                                                               \
  _Pragma("unroll") for (int n_ = 0; n_ < 2; ++n_) {                             \
    _Pragma("unroll") for (int ks_ = 0; ks_ < 2; ++ks_) {                        \
      Bfr[NH][n_ * 2 + ks_] =                                                    \
          *(const bf16x8*)&Bc[(wn * 64 + (NH)*32 + n_ * 16 + l15) * 64 +         \
                              (((ks_ * 4 + lhi) ^ c7) * 8)];                     \
    }                                                                            \
  }
#define QUAD(MH, NH)                                                             \
  do {                                                                           \
    __builtin_amdgcn_s_setprio(1);                                               \
    _Pragma("unroll") for (int m_ = 0; m_ < 4; ++m_) {                           \
      _Pragma("unroll") for (int n_ = 0; n_ < 2; ++n_) {                         \
        acc[(MH)*4 + m_][(NH)*2 + n_] =                                          \
            MFMA16(Afr[MH][m_ * 2], Bfr[NH][n_ * 2],                             \
                   acc[(MH)*4 + m_][(NH)*2 + n_], 0, 0, 0);                      \
        acc[(MH)*4 + m_][(NH)*2 + n_] =                                          \
            MFMA16(Afr[MH][m_ * 2 + 1], Bfr[NH][n_ * 2 + 1],                     \
                   acc[(MH)*4 + m_][(NH)*2 + n_], 0, 0, 0);                      \
      }                                                                          \
    }                                                                            \
    __builtin_amdgcn_s_setprio(0);                                               \
  } while (0)

  f32x4 acc[8][4] = {};

  // prologue: tiles 0,1 staged; wait tile 0 (tile 1 stays in flight)
  stageA(0, 0);
  stageB(0, 0);
  stageA(1, 1);
  stageB(1, 1);
  asm volatile("s_waitcnt vmcnt(8)" ::: "memory");
  __builtin_amdgcn_s_barrier();
  GFENCE();

  for (int kt = 0; kt < NT; ++kt) {
    const int b = kt & 1;
    const u16* Ac = &Ab[b][0];
    const u16* Bc = &Bb[b][0];
    bf16x8 Afr[2][8], Bfr[2][4];
    // P0: read A-half0 + B-half0
    READ_A(0);
    READ_B(0);
    BARF();
    QUAD(0, 0);
    BARF();
    // P1: read A-half1 + B-half1
    READ_A(1);
    READ_B(1);
    BARF();
    QUAD(0, 1);
    BARF();
    // P2: stage A(kt+2) (A regions free after P1)
    if (kt + 2 < NT) stageA(kt + 2, b);
    BARF();
    QUAD(1, 0);
    BARF();
    // P3: stage B(kt+2)
    if (kt + 2 < NT) stageB(kt + 2, b);
    BARF();
    QUAD(1, 1);
    // K-tile boundary: next tile must be resident; keep prefetch in flight
    if (kt + 1 < NT) {
      if (kt + 2 < NT)
        asm volatile("s_waitcnt vmcnt(8)" ::: "memory");
      else
        asm volatile("s_waitcnt vmcnt(0)" ::: "memory");
      __builtin_amdgcn_s_barrier();
      GFENCE();
    }
  }
#undef READ_A
#undef READ_B
#undef QUAD

#pragma unroll
  for (int mi = 0; mi < 8; ++mi) {
    const long row0 = m0 + wm * 128 + mi * 16 + lhi * 4;
#pragma unroll
    for (int ni = 0; ni < 4; ++ni) {
      const long col = n0 + wn * 64 + ni * 16 + l15;
      const float bb = bias[col];
#pragma unroll
      for (int r = 0; r < 4; ++r) {
        float v = acc[mi][ni][r] + bb;
        if (EPI == 2) {
          float other = __shfl_xor(v, 1, 64);
          if (!(l15 & 1)) {
            float s = v / (1.f + __expf(-v)) * other;  // silu(g)*v
            out_bf[(row0 + r) * (N >> 1) + (col >> 1)] = f2bf(s);
          }
        } else {
          out_bf[(row0 + r) * N + col] = f2bf(v);
        }
      }
    }
  }
}

// ---------------- 3-buffer GEMM (linear layouts) for skinny N ----------------
template <int EPI, int NB>
__global__ __launch_bounds__(256) void gemm_bt(const u16* __restrict__ A,
                                               const u16* __restrict__ Bw,
                                               const float* __restrict__ bias,
                                               const float* __restrict__ resid,
                                               u16* __restrict__ out_bf,
                                               float* __restrict__ out_f,
                                               int N, int K) {
  constexpr int BHALF = NB / 64;
  constexpr int NFR = NB / 32;
  constexpr int LPT = 2 + BHALF;
  __shared__ __align__(16) u16 As[3][128 * 32];
  __shared__ __align__(16) u16 Bs[3][NB * 32];
  const int tid = threadIdx.x;
  const int lane = tid & 63;
  const int wv = tid >> 6;
  const int wr = wv >> 1, wc = wv & 1;
  const long m0 = (long)blockIdx.y * 128;
  const long n0 = (long)blockIdx.x * NB;

  const int arow = tid >> 2;
  const int acol = (tid & 3) << 3;
  const u16* ag = A + (m0 + arow) * K + acol;
  const u16* bg = Bw + (n0 + arow) * K + acol;
  const long hK = (long)64 * K;

  f32x4 acc[4][NFR] = {};
  const int l15 = lane & 15;
  const int lhi = lane >> 4;
  const int aoff0 = (wr * 64 + l15) * 32 + lhi * 8;
  const int boff0 = (wc * (NB / 2) + l15) * 32 + lhi * 8;
  const int nk = K >> 5;

  auto stage = [&](int t, int buf) {
    const int k0 = t << 5;
    gl_lds16(ag + k0, &As[buf][tid * 8]);
    gl_lds16(ag + k0 + hK, &As[buf][2048 + tid * 8]);
    gl_lds16(bg + k0, &Bs[buf][tid * 8]);
    if (BHALF == 2) gl_lds16(bg + k0 + hK, &Bs[buf][2048 + tid * 8]);
  };

  stage(0, 0);
  stage(1, 1);
  asm volatile("s_waitcnt vmcnt(%0)" ::"n"(LPT) : "memory");
  __builtin_amdgcn_s_barrier();
  GFENCE();

  for (int t = 0; t < nk; ++t) {
    const int cb = t % 3;
    if (t + 2 < nk) stage(t + 2, (t + 2) % 3);
    bf16x8 af[4], bfr[NFR];
#pragma unroll
    for (int i = 0; i < 4; ++i) af[i] = *(const bf16x8*)&As[cb][aoff0 + i * 16 * 32];
#pragma unroll
    for (int j = 0; j < NFR; ++j) bfr[j] = *(const bf16x8*)&Bs[cb][boff0 + j * 16 * 32];
    __builtin_amdgcn_s_setprio(1);
#pragma unroll
    for (int i = 0; i < 4; ++i)
#pragma unroll
      for (int j = 0; j < NFR; ++j)
        acc[i][j] = MFMA16(af[i], bfr[j], acc[i][j], 0, 0, 0);
    __builtin_amdgcn_s_setprio(0);
    if (t + 2 < nk) {
      asm volatile("s_waitcnt vmcnt(%0)" ::"n"(LPT) : "memory");
      __builtin_amdgcn_s_barrier();
      GFENCE();
    } else if (t + 1 < nk) {
      asm volatile("s_waitcnt vmcnt(0)" ::: "memory");
      __builtin_amdgcn_s_barrier();
      GFENCE();
    }
  }

#pragma unroll
  for (int i = 0; i < 4; ++i) {
    const long row0 = m0 + wr * 64 + i * 16 + lhi * 4;
#pragma unroll
    for (int j = 0; j < NFR; ++j) {
      const long col = n0 + wc * (NB / 2) + j * 16 + l15;
      const float bb = bias[col];
#pragma unroll
      for (int r = 0; r < 4; ++r) {
        const long idx = (row0 + r) * N + col;
        float v = acc[i][j][r] + bb;
        if (EPI == 0) out_bf[idx] = f2bf(v);
        else          out_f[idx] = resid[idx] + v;
      }
    }
  }
}

// ---------------- RoPE on Q, pre-scaled by 0.125*log2(e) ----------------
__global__ __launch_bounds__(256) void rope_q_kernel(const u16* __restrict__ qkv,
                                                     const float* __restrict__ cosT,
                                                     const float* __restrict__ sinT,
                                                     u16* __restrict__ Q) {
  int idx = blockIdx.x * 256 + threadIdx.x;  // B*H*S*8 = 524288 units of 8 elems
  int u = idx & 7;
  int s = (idx >> 3) & (S_LEN - 1);
  int bh = idx >> 14;
  int b = bh >> 4, h = bh & 15;
  int pos = PREV + s;
  const float SC = 0.125f * LOG2E;
  const u16* src = qkv + ((long)(b * S_LEN + s)) * (3 * DIM) + h * HD + u * 8;
  u32x4 d = *(const u32x4*)src;
  f32x4 cv = *(const f32x4*)&cosT[(long)pos * 32 + u * 4];
  f32x4 sv = *(const f32x4*)&sinT[(long)pos * 32 + u * 4];
  u32x4 o;
#pragma unroll
  for (int p = 0; p < 4; ++p) {
    float x0 = bf2f((u16)(d[p] & 0xffff));
    float x1 = bf2f((u16)(d[p] >> 16));
    float y0 = (x0 * cv[p] - x1 * sv[p]) * SC;
    float y1 = (x0 * sv[p] + x1 * cv[p]) * SC;
    o[p] = (u32)f2bf(y0) | ((u32)f2bf(y1) << 16);
  }
  *(u32x4*)&Q[((long)bh * S_LEN + s) * HD + u * 8] = o;
}

// ---------------- K_all = rope(concat(cache_k, k_new)); stored XOR-swizzled ----------------
__global__ __launch_bounds__(256) void rope_k_kernel(const u16* __restrict__ qkv,
                                                     const float* __restrict__ cache_k,
                                                     const float* __restrict__ cosT,
                                                     const float* __restrict__ sinT,
                                                     u16* __restrict__ Kall) {
  int idx = blockIdx.x * 256 + threadIdx.x;  // B*H*T*8 = 786432
  int u = idx & 7;
  int t2 = idx >> 3;
  int j = t2 % T_LEN;
  int bh = t2 / T_LEN;
  int b = bh >> 4, h = bh & 15;
  float e[8];
  if (j < PREV) {
    const float* src = cache_k + ((long)bh * PREV + j) * HD + u * 8;
    f32x4 a = *(const f32x4*)src;
    f32x4 c = *(const f32x4*)(src + 4);
    e[0] = a[0]; e[1] = a[1]; e[2] = a[2]; e[3] = a[3];
    e[4] = c[0]; e[5] = c[1]; e[6] = c[2]; e[7] = c[3];
  } else {
    const u16* src = qkv + ((long)(b * S_LEN + (j - PREV))) * (3 * DIM) + DIM + h * HD + u * 8;
    u32x4 d = *(const u32x4*)src;
#pragma unroll
    for (int p = 0; p < 4; ++p) {
      e[2 * p] = bf2f((u16)(d[p] & 0xffff));
      e[2 * p + 1] = bf2f((u16)(d[p] >> 16));
    }
  }
  f32x4 cv = *(const f32x4*)&cosT[(long)j * 32 + u * 4];
  f32x4 sv = *(const f32x4*)&sinT[(long)j * 32 + u * 4];
  u32x4 o;
#pragma unroll
  for (int p = 0; p < 4; ++p) {
    float y0 = e[2 * p] * cv[p] - e[2 * p + 1] * sv[p];
    float y1 = e[2 * p] * sv[p] + e[2 * p + 1] * cv[p];
    o[p] = (u32)f2bf(y0) | ((u32)f2bf(y1) << 16);
  }
  *(u32x4*)&Kall[((long)bh * T_LEN + j) * HD + (u ^ (j & 7)) * 8] = o;
}

// ---------------- Vt_global[bh][hd][key], XOR-swizzled within 64-key spans ----------------
__global__ __launch_bounds__(256) void build_vt_kernel(const u16* __restrict__ qkv,
                                                       const float* __restrict__ cache_v,
                                                       u16* __restrict__ Vtg) {
  int idx = blockIdx.x * 256 + threadIdx.x;  // 32 * 384 * 64 = 786432
  int hd = idx & 63;
  int t2 = idx >> 6;
  int kb = t2 % 384;  // 8-key block
  int bh = t2 / 384;
  int b = bh >> 4, h = bh & 15;
  int key0 = kb * 8;
  u16 vals[8];
  if (key0 < PREV) {
#pragma unroll
    for (int i = 0; i < 8; ++i)
      vals[i] = f2bf(cache_v[((long)bh * PREV + key0 + i) * HD + hd]);
  } else {
#pragma unroll
    for (int i = 0; i < 8; ++i)
      vals[i] = qkv[((long)(b * S_LEN + key0 + i - PREV)) * (3 * DIM) + 2 * DIM + h * HD + hd];
  }
  u32x4 o;
#pragma unroll
  for (int p = 0; p < 4; ++p)
    o[p] = (u32)vals[2 * p] | ((u32)vals[2 * p + 1] << 16);
  const int span = kb >> 3;
  const int u = (kb & 7) ^ (hd & 7);
  *(u32x4*)&Vtg[((long)bh * HD + hd) * T_LEN + span * 64 + u * 8] = o;
}

// ---------------- flash attention: paired dual-Q blocks, shared KV sweep ----------------
// Block (bh, p) handles q-tiles qtA=p and qtB=31-p in ONE KV sweep: ntA+ntB = 65 const
// -> perfect CU load balance (512 blocks, 2/CU). Shared K/V staging + register frags
// for both q-sets during the overlap (t < ntA).
__global__ __launch_bounds__(256, 2) void attn_kernel(const u16* __restrict__ Q,
                                                      const u16* __restrict__ Kg,
                                                      const u16* __restrict__ Vtg,
                                                      u16* __restrict__ ctx, float slope2) {
  __shared__ __align__(16) u16 Ks[2][64 * 64];  // [key][d], swizzled
  __shared__ __align__(16) u16 Vs[2][64 * 64];  // [hd][key], swizzled
  __shared__ __align__(16) u16 Ps[4][16 * 64];  // per-wave P[q][key], swizzled

  const int tid = threadIdx.x;
  const int lane = tid & 63;
  const int wv = tid >> 6;
  const int l15 = lane & 15;
  const int lhi = lane >> 4;
  const int c7 = l15 & 7;
  const int bh = blockIdx.x;
  const int p = blockIdx.y;            // pair index 0..15
  const int b = bh >> 4, h = bh & 15;
  const int qA0 = p * 64;
  const int qB0 = (31 - p) * 64;
  const int ntA = 17 + p;              // (PREV + qA0 + 64) >> 6
  const int ntB = 48 - p;              // ntA + ntB = 65

  const long qrowA = (long)bh * S_LEN + qA0 + wv * 16 + l15;
  const long qrowB = (long)bh * S_LEN + qB0 + wv * 16 + l15;
  bf16x8 aqA0 = *(const bf16x8*)&Q[qrowA * HD + lhi * 8];
  bf16x8 aqA1 = *(const bf16x8*)&Q[qrowA * HD + 32 + lhi * 8];
  bf16x8 aqB0 = *(const bf16x8*)&Q[qrowB * HD + lhi * 8];
  bf16x8 aqB1 = *(const bf16x8*)&Q[qrowB * HD + 32 + lhi * 8];

  const long kgb = (long)bh * T_LEN * HD;  // K: [key][64]
  const long vgb = (long)bh * HD * T_LEN;  // Vt: [hd][T]
  const int srow = tid >> 3;               // staging row 0..31
  const int sunit = (tid & 7) * 8;

  const u16* kst = Kg + kgb + (long)srow * HD + sunit;     // +64*HD per tile
  const u16* vst = Vtg + vgb + (long)srow * T_LEN + sunit; // +64 per tile

  // prologue: stage tile 0
  gl_lds16(kst, &Ks[0][tid * 8]);
  gl_lds16(kst + 32 * HD, &Ks[0][2048 + tid * 8]);
  gl_lds16(vst, &Vs[0][tid * 8]);
  gl_lds16(vst + (long)32 * T_LEN, &Vs[0][2048 + tid * 8]);
  kst += 64 * HD;
  vst += 64;
  __syncthreads();

  f32x4 oA[4] = {}, oB[4] = {};
  f32x4 lrunA = {0.f, 0.f, 0.f, 0.f}, lrunB = {0.f, 0.f, 0.f, 0.f};
  float mrunA = -1e30f, mrunB = -1e30f;
  const int qq = wv * 16 + l15;  // local q (mask threshold, same layout both q-sets)
  u16* Pw = &Ps[wv][0];

  f32x4 be[4];  // per-thread bias constants slope*(jf*16+4*lhi+r)
#pragma unroll
  for (int jf = 0; jf < 4; ++jf)
#pragma unroll
    for (int r = 0; r < 4; ++r)
      be[jf][r] = slope2 * (float)(jf * 16 + 4 * lhi + r);
  const float bmax = slope2 * 63.f;

  bf16x8 vones;
#pragma unroll
  for (int e = 0; e < 8; ++e) vones[e] = (__bf16)1.0f;

  float ktf = 0.f;
  const float kstep = slope2 * 64.f;

  // softmax + PV for one q-set (all loops compile-time; vf shared)
  auto process = [&](f32x4 (&sf)[4], bool maskNow, f32x4 (&o)[4], f32x4& lrun,
                     float& mrun, bf16x8 (&vf)[8]) {
    if (maskNow) {
#pragma unroll
      for (int jf = 0; jf < 4; ++jf)
#pragma unroll
        for (int r = 0; r < 4; ++r)
          if (jf * 16 + 4 * lhi + r > qq) sf[jf][r] = -1e30f;
    }
    float h0 = fmaxf(fmaxf(sf[0][0], sf[0][1]), fmaxf(sf[0][2], sf[0][3]));
    float h1 = fmaxf(fmaxf(sf[1][0], sf[1][1]), fmaxf(sf[1][2], sf[1][3]));
    float h2 = fmaxf(fmaxf(sf[2][0], sf[2][1]), fmaxf(sf[2][2], sf[2][3]));
    float h3 = fmaxf(fmaxf(sf[3][0], sf[3][1]), fmaxf(sf[3][2], sf[3][3]));
    float pm = fmaxf(fmaxf(h0, h1), fmaxf(h2, h3));
    pm = fmaxf(pm, __shfl_xor(pm, 16, 64));
    pm = fmaxf(pm, __shfl_xor(pm, 32, 64));
    const float pmax_abs = pm + ktf + bmax;

    if (!__all(pmax_abs - mrun <= 8.f)) {
      const float mnew = fmaxf(mrun, pmax_abs);
      const float scl = exp2f(mrun - mnew);
      mrun = mnew;
#pragma unroll
      for (int r = 0; r < 4; ++r) {
        const float sr = __shfl(scl, 4 * lhi + r, 64);
        lrun[r] *= sr;
#pragma unroll
        for (int hf = 0; hf < 4; ++hf) o[hf][r] *= sr;
      }
    }
    const float meff = mrun - ktf;

#pragma unroll
    for (int jf = 0; jf < 4; ++jf) {
      f32x4 pp;
#pragma unroll
      for (int r = 0; r < 4; ++r)
        pp[r] = exp2f(sf[jf][r] + (be[jf][r] - meff));
      u32x2 pw2;
      pw2[0] = cvtpk(pp[0], pp[1]);
      pw2[1] = cvtpk(pp[2], pp[3]);
      const int u = (2 * jf + (lhi >> 1)) ^ c7;
      *(u32x2*)&Pw[l15 * 64 + u * 8 + (lhi & 1) * 4] = pw2;
    }

    bf16x8 pa0 = *(const bf16x8*)&Pw[l15 * 64 + ((lhi ^ c7) * 8)];
    bf16x8 pa1 = *(const bf16x8*)&Pw[l15 * 64 + (((4 + lhi) ^ c7) * 8)];
    f32x4 psum = {};
    __builtin_amdgcn_s_setprio(1);
    psum = MFMA16(pa0, vones, psum, 0, 0, 0);
    psum = MFMA16(pa1, vones, psum, 0, 0, 0);
#pragma unroll
    for (int hf = 0; hf < 4; ++hf) {
      o[hf] = MFMA16(pa0, vf[2 * hf], o[hf], 0, 0, 0);
      o[hf] = MFMA16(pa1, vf[2 * hf + 1], o[hf], 0, 0, 0);
    }
    __builtin_amdgcn_s_setprio(0);
    lrun += psum;
  };

  for (int t = 0; t < ntB; ++t) {
    const int cur = t & 1, nxt = cur ^ 1;
    const bool lastStage = (t + 1 == ntB);
    if (!lastStage) {
      gl_lds16(kst, &Ks[nxt][tid * 8]);
      gl_lds16(kst + 32 * HD, &Ks[nxt][2048 + tid * 8]);
      gl_lds16(vst, &Vs[nxt][tid * 8]);
      gl_lds16(vst + (long)32 * T_LEN, &Vs[nxt][2048 + tid * 8]);
      kst += 64 * HD;
      vst += 64;
    }
    const bool actA = (t < ntA);

    // K fragments once, shared by both q-sets
    bf16x8 kf[8];
#pragma unroll
    for (int jf = 0; jf < 4; ++jf) {
      const int krow = jf * 16 + l15;
      kf[2 * jf] = *(const bf16x8*)&Ks[cur][krow * 64 + ((lhi ^ c7) * 8)];
      kf[2 * jf + 1] = *(const bf16x8*)&Ks[cur][krow * 64 + (((4 + lhi) ^ c7) * 8)];
    }
    // V fragments once, shared by both q-sets
    bf16x8 vf[8];
#pragma unroll
    for (int hf = 0; hf < 4; ++hf) {
      const int vrow = hf * 16 + l15;
      vf[2 * hf] = *(const bf16x8*)&Vs[cur][vrow * 64 + ((lhi ^ c7) * 8)];
      vf[2 * hf + 1] = *(const bf16x8*)&Vs[cur][vrow * 64 + (((4 + lhi) ^ c7) * 8)];
    }

    // QK^T for both q-sets
    f32x4 sB[4], sA[4];
    __builtin_amdgcn_s_setprio(1);
#pragma unroll
    for (int jf = 0; jf < 4; ++jf) {
      f32x4 s = {};
      s = MFMA16(kf[2 * jf], aqB0, s, 0, 0, 0);
      s = MFMA16(kf[2 * jf + 1], aqB1, s, 0, 0, 0);
      sB[jf] = s;
    }
    __builtin_amdgcn_s_setprio(0);
    if (actA) {
      __builtin_amdgcn_s_setprio(1);
#pragma unroll
      for (int jf = 0; jf < 4; ++jf) {
        f32x4 s = {};
        s = MFMA16(kf[2 * jf], aqA0, s, 0, 0, 0);
        s = MFMA16(kf[2 * jf + 1], aqA1, s, 0, 0, 0);
        sA[jf] = s;
      }
      __builtin_amdgcn_s_setprio(0);
    }

    process(sB, t == ntB - 1, oB, lrunB, mrunB, vf);
    if (actA) process(sA, t == ntA - 1, oA, lrunA, mrunA, vf);

    ktf += kstep;
    if (!lastStage) __syncthreads();
  }

  // epilogue: rows q_local = 4*lhi + r; cols hd = hf*16 + l15
#pragma unroll
  for (int r = 0; r < 4; ++r) {
    const float invA = 1.f / lrunA[r];
    const float invB = 1.f / lrunB[r];
    const long rowA = (long)b * S_LEN + qA0 + wv * 16 + 4 * lhi + r;
    const long rowB = (long)b * S_LEN + qB0 + wv * 16 + 4 * lhi + r;
#pragma unroll
    for (int hf = 0; hf < 4; ++hf) {
      ctx[rowA * DIM + h * HD + hf * 16 + l15] = f2bf(oA[hf][r] * invA);
      ctx[rowB * DIM + h * HD + hf * 16 + l15] = f2bf(oB[hf][r] * invB);
    }
  }
}

// ---------------------------------------------------------------------------
extern "C" void kernel_launch(void* const* d_in, const int* in_sizes, int n_in,
                              void* d_out, int out_size, void* d_ws, size_t ws_size,
                              hipStream_t stream) {
  (void)in_sizes; (void)n_in; (void)out_size; (void)ws_size;
  const float* x       = (const float*)d_in[0];
  const float* cache_k = (const float*)d_in[1];
  const float* cache_v = (const float*)d_in[2];
  const float* cosT    = (const float*)d_in[3];
  const float* sinT    = (const float*)d_in[4];
  const float* attn_w  = (const float*)d_in[5];
  const float* ffn_w   = (const float*)d_in[6];
  const float* wq      = (const float*)d_in[7];
  const float* bq      = (const float*)d_in[8];
  const float* wk      = (const float*)d_in[9];
  const float* bk      = (const float*)d_in[10];
  const float* wv_     = (const float*)d_in[11];
  const float* bv      = (const float*)d_in[12];
  const float* wo      = (const float*)d_in[13];
  const float* bo      = (const float*)d_in[14];
  const float* wg      = (const float*)d_in[15];
  const float* bg      = (const float*)d_in[16];
  const float* wval    = (const float*)d_in[17];
  const float* bval    = (const float*)d_in[18];
  const float* wp      = (const float*)d_in[19];
  const float* bp      = (const float*)d_in[20];
  float* out = (float*)d_out;

  char* w = (char*)d_ws;
  size_t off = 0;
  auto alloc = [&](size_t bytes) -> char* {
    char* p = w + off;
    off += (bytes + 255) & ~(size_t)255;
    return p;
  };
  // permanent
  u16*   wqkv_bf  = (u16*)alloc((size_t)3 * DIM * DIM * 2);  // preswizzled
  u16*   wo_bf    = (u16*)alloc((size_t)DIM * DIM * 2);      // linear
  u16*   wgv_bf   = (u16*)alloc((size_t)2 * FF * DIM * 2);   // interleaved+preswizzled
  u16*   wproj_bf = (u16*)alloc((size_t)DIM * FF * 2);       // linear
  float* bqkv     = (float*)alloc((size_t)3 * DIM * 4);
  float* bgv      = (float*)alloc((size_t)2 * FF * 4);       // interleaved
  float* x2       = (float*)alloc((size_t)MROWS * DIM * 4);
  // arena with lifetime-based aliasing
  char* AR = alloc((size_t)117440512);
  u16* qkv   = (u16*)(AR + 0);          // [4096][3072]   live: qkv gemm -> rope/build
  u16* Qb    = (u16*)(AR + 25165824);   // [32][2048][64] live: rope -> attn
  u16* Kb    = (u16*)(AR + 33554432);   // [32][3072][64]
  u16* Vtg   = (u16*)(AR + 46137344);   // [32][64][3072] transposed V
  u16* h1    = (u16*)(AR + 58720256);   // [4096][1024]   preswizzled (qkv gemm A)
  u16* ctx   = (u16*)(AR + 0);          // [4096][1024]   linear (aliases dead qkv)
  u16* h2    = (u16*)(AR + 8388608);    // [4096][1024]   preswizzled (gv gemm A)
  u16* gated = (u16*)(AR + 16777216);   // [4096][4096]   linear

  // 1) weights -> bf16 (preswizzled for 256-GEMMs; linear for skinny GEMMs)
  cvt_sw_kernel<<<512, 256, 0, stream>>>(wq, wqkv_bf, DIM * DIM / 8);
  cvt_sw_kernel<<<512, 256, 0, stream>>>(wk, wqkv_bf + DIM * DIM, DIM * DIM / 8);
  cvt_sw_kernel<<<512, 256, 0, stream>>>(wv_, wqkv_bf + 2 * DIM * DIM, DIM * DIM / 8);
  cvt_kernel<<<512, 256, 0, stream>>>(wo, wo_bf, DIM * DIM / 4);
  cvt_ilv_sw_kernel<<<1024, 256, 0, stream>>>(wg, wval, wgv_bf);
  cvt_kernel<<<1024, 256, 0, stream>>>(wp, wproj_bf, DIM * FF / 4);
  bias_ilv_kernel<<<16, 256, 0, stream>>>(bg, bval, bgv);
  hipMemcpyAsync(bqkv, bq, DIM * 4, hipMemcpyDeviceToDevice, stream);
  hipMemcpyAsync(bqkv + DIM, bk, DIM * 4, hipMemcpyDeviceToDevice, stream);
  hipMemcpyAsync(bqkv + 2 * DIM, bv, DIM * 4, hipMemcpyDeviceToDevice, stream);

  // 2) attn rmsnorm (swizzled out), fused QKV 256-gemm
  rmsnorm_kernel<<<MROWS, 256, 0, stream>>>(x, attn_w, h1);
  gemm256<0><<<dim3(12, 16), 512, 0, stream>>>(h1, wqkv_bf, bqkv, qkv, 3 * DIM, DIM);
  // 3) rope + cache concat
  rope_q_kernel<<<2048, 256, 0, stream>>>(qkv, cosT, sinT, Qb);
  rope_k_kernel<<<3072, 256, 0, stream>>>(qkv, cache_k, cosT, sinT, Kb);
  build_vt_kernel<<<3072, 256, 0, stream>>>(qkv, cache_v, Vtg);
  // 4) attention: paired dual-Q blocks (constant work per block, 2 blocks/CU)
  attn_kernel<<<dim3(B_SZ * NH, 16), 256, 0, stream>>>(
      Qb, Kb, Vtg, ctx, (2.0f / (float)(T_LEN - 1)) * LOG2E);
  // 5) o-proj + residual (fp32), skinny tile
  gemm_bt<1, 64><<<dim3(16, 32), 256, 0, stream>>>(ctx, wo_bf, bo, x, nullptr, x2,
                                                   DIM, DIM);
  // 6) ffn rmsnorm (swizzled out), gate+value 256-gemm w/ silu epilogue, proj + residual
  rmsnorm_kernel<<<MROWS, 256, 0, stream>>>(x2, ffn_w, h2);
  gemm256<2><<<dim3(32, 16), 512, 0, stream>>>(h2, wgv_bf, bgv, gated, 2 * FF, DIM);
  gemm_bt<1, 64><<<dim3(16, 32), 256, 0, stream>>>(gated, wproj_bf, bp, x2, nullptr, out,
                                                   DIM, FF);
}

// Round 8
// 361.093 us; speedup vs baseline: 1.5632x; 1.0319x over previous
//
#include <hip/hip_runtime.h>
#include <stdint.h>

typedef unsigned short u16;
typedef unsigned int   u32;
typedef __bf16 bf16x8 __attribute__((ext_vector_type(8)));
typedef float  f32x4  __attribute__((ext_vector_type(4)));
typedef u32    u32x4  __attribute__((ext_vector_type(4)));
typedef u32    u32x2  __attribute__((ext_vector_type(2)));

#define B_SZ  2
#define S_LEN 2048
#define NH    16
#define HD    64
#define DIM   1024
#define FF    4096
#define T_LEN 3072
#define PREV  1024
#define MROWS (B_SZ * S_LEN) /* 4096 */
#define LOG2E 1.44269504f

#define MFMA16 __builtin_amdgcn_mfma_f32_16x16x32_bf16

__device__ __forceinline__ u16 f2bf(float f) {
  u32 u = __builtin_bit_cast(u32, f);
  u32 r = u + 0x7FFFu + ((u >> 16) & 1u);
  return (u16)(r >> 16);
}
__device__ __forceinline__ float bf2f(u16 h) {
  u32 u = ((u32)h) << 16;
  return __builtin_bit_cast(float, u);
}
__device__ __forceinline__ u32 cvtpk(float lo, float hi) {
  u32 r;
  asm("v_cvt_pk_bf16_f32 %0, %1, %2" : "=v"(r) : "v"(lo), "v"(hi));
  return r;
}

// async global->LDS, 16B per lane. LDS dest must be wave-uniform base + lane*16.
__device__ __forceinline__ void gl_lds16(const void* g, void* l) {
  __builtin_amdgcn_global_load_lds(
      (const __attribute__((address_space(1))) u32*)g,
      (__attribute__((address_space(3))) u32*)l, 16, 0, 0);
}

#define GFENCE() asm volatile("" ::: "memory")
#define BARF()                         \
  do {                                 \
    GFENCE();                          \
    __builtin_amdgcn_s_barrier();      \
    GFENCE();                          \
  } while (0)

// ---------------- fp32 -> bf16 convert (linear, for 3-buf GEMM weights) ----------------
__global__ __launch_bounds__(256) void cvt_kernel(const float* __restrict__ src,
                                                  u16* __restrict__ dst, int n4) {
  int i = blockIdx.x * 256 + threadIdx.x;
  const int stride = gridDim.x * 256;
  for (; i < n4; i += stride) {
    f32x4 v = *(const f32x4*)&src[(long)i * 4];
    u32x2 o;
    o[0] = (u32)f2bf(v[0]) | ((u32)f2bf(v[1]) << 16);
    o[1] = (u32)f2bf(v[2]) | ((u32)f2bf(v[3]) << 16);
    *(u32x2*)&dst[(long)i * 4] = o;
  }
}

// ---------------- wq,wk,wv -> wqkv_bf, K-unit XOR-preswizzled (K=1024) ----------------
__global__ __launch_bounds__(256) void cvt_qkv_sw_kernel(const float* __restrict__ wq,
                                                         const float* __restrict__ wk,
                                                         const float* __restrict__ wv,
                                                         u16* __restrict__ dst) {
  int i = blockIdx.x * 256 + threadIdx.x;  // 3 * 131072 units
  const int stride = gridDim.x * 256;
  for (; i < 3 * 131072; i += stride) {
    const int seg = i >> 17;
    const int loc = i & 131071;
    const float* src = (seg == 0) ? wq : (seg == 1) ? wk : wv;
    int row = loc >> 7;
    int g = loc & 127;
    const float* s = &src[((long)row << 10) + g * 8];
    f32x4 a = *(const f32x4*)s;
    f32x4 b = *(const f32x4*)(s + 4);
    u32x4 o;
    o[0] = (u32)f2bf(a[0]) | ((u32)f2bf(a[1]) << 16);
    o[1] = (u32)f2bf(a[2]) | ((u32)f2bf(a[3]) << 16);
    o[2] = (u32)f2bf(b[0]) | ((u32)f2bf(b[1]) << 16);
    o[3] = (u32)f2bf(b[2]) | ((u32)f2bf(b[3]) << 16);
    const int gp = (g & ~7) | ((g & 7) ^ (row & 7));
    *(u32x4*)&dst[((long)seg << 20) + ((long)row << 10) + gp * 8] = o;
  }
}

// interleave wg/wval rows (dst row 2j = wg[j], 2j+1 = wval[j]), preswizzled, K=1024
__global__ __launch_bounds__(256) void cvt_ilv_sw_kernel(const float* __restrict__ wg,
                                                         const float* __restrict__ wval,
                                                         u16* __restrict__ dst) {
  int i = blockIdx.x * 256 + threadIdx.x;  // FF * 128 units
  const int stride = gridDim.x * 256;
  for (; i < FF * 128; i += stride) {
    int j = i >> 7;
    int g = i & 127;
    const float* sg = &wg[((long)j << 10) + g * 8];
    const float* sv = &wval[((long)j << 10) + g * 8];
    f32x4 a = *(const f32x4*)sg;
    f32x4 b = *(const f32x4*)(sg + 4);
    u32x4 og;
    og[0] = (u32)f2bf(a[0]) | ((u32)f2bf(a[1]) << 16);
    og[1] = (u32)f2bf(a[2]) | ((u32)f2bf(a[3]) << 16);
    og[2] = (u32)f2bf(b[0]) | ((u32)f2bf(b[1]) << 16);
    og[3] = (u32)f2bf(b[2]) | ((u32)f2bf(b[3]) << 16);
    f32x4 c = *(const f32x4*)sv;
    f32x4 d = *(const f32x4*)(sv + 4);
    u32x4 ov;
    ov[0] = (u32)f2bf(c[0]) | ((u32)f2bf(c[1]) << 16);
    ov[1] = (u32)f2bf(c[2]) | ((u32)f2bf(c[3]) << 16);
    ov[2] = (u32)f2bf(d[0]) | ((u32)f2bf(d[1]) << 16);
    ov[3] = (u32)f2bf(d[2]) | ((u32)f2bf(d[3]) << 16);
    const int rg = 2 * j, rv = 2 * j + 1;
    const int gpg = (g & ~7) | ((g & 7) ^ (rg & 7));
    const int gpv = (g & ~7) | ((g & 7) ^ (rv & 7));
    *(u32x4*)&dst[((long)rg << 10) + gpg * 8] = og;
    *(u32x4*)&dst[((long)rv << 10) + gpv * 8] = ov;
  }
}

// all bias packing in one kernel: bqkv = [bq|bk|bv]; bgv = interleave(bg,bval)
__global__ __launch_bounds__(256) void bias_pack_kernel(const float* __restrict__ bq,
                                                        const float* __restrict__ bk,
                                                        const float* __restrict__ bv,
                                                        const float* __restrict__ bg,
                                                        const float* __restrict__ bval,
                                                        float* __restrict__ bqkv,
                                                        float* __restrict__ bgv) {
  int i = blockIdx.x * 256 + threadIdx.x;  // 3072 + 4096 items
  if (i < 3 * DIM) {
    float v = (i < DIM) ? bq[i] : (i < 2 * DIM) ? bk[i - DIM] : bv[i - 2 * DIM];
    bqkv[i] = v;
  } else if (i < 3 * DIM + FF) {
    int j = i - 3 * DIM;
    bgv[2 * j] = bg[j];
    bgv[2 * j + 1] = bval[j];
  }
}

// ---------------- RMSNorm: fp32 row -> bf16 row, K-unit XOR-preswizzled out ----------------
__global__ __launch_bounds__(256) void rmsnorm_kernel(const float* __restrict__ x,
                                                      const float* __restrict__ w,
                                                      u16* __restrict__ out) {
  const int row = blockIdx.x;
  const int tid = threadIdx.x;
  const long base = (long)row * DIM + tid * 4;
  f32x4 v = *(const f32x4*)&x[base];
  float ss = v[0] * v[0] + v[1] * v[1] + v[2] * v[2] + v[3] * v[3];
#pragma unroll
  for (int d = 1; d <= 32; d <<= 1) ss += __shfl_xor(ss, d, 64);
  __shared__ float red[4];
  if ((tid & 63) == 0) red[tid >> 6] = ss;
  __syncthreads();
  float tot = red[0] + red[1] + red[2] + red[3];
  const float sc = rsqrtf(tot * (1.f / (float)DIM) + 1e-6f);
  f32x4 wv4 = *(const f32x4*)&w[tid * 4];
  u32x2 o;
  o[0] = (u32)f2bf(v[0] * sc * wv4[0]) | ((u32)f2bf(v[1] * sc * wv4[1]) << 16);
  o[1] = (u32)f2bf(v[2] * sc * wv4[2]) | ((u32)f2bf(v[3] * sc * wv4[3]) << 16);
  const int u = tid >> 1, hf = tid & 1;
  const int up = (u & 0x78) | ((u & 7) ^ (row & 7));
  *(u32x2*)&out[(long)row * DIM + up * 8 + hf * 4] = o;
}

// ---------------- 256x256 8-phase GEMM (T1+T2+T3+T4+T5), K multiple of 64 ----------------
template <int EPI>
__global__ __launch_bounds__(512, 2) void gemm256(const u16* __restrict__ A,
                                                  const u16* __restrict__ Bw,
                                                  const float* __restrict__ bias,
                                                  u16* __restrict__ out_bf,
                                                  int N, int K) {
  __shared__ __align__(16) u16 Ab[2][256 * 64];
  __shared__ __align__(16) u16 Bb[2][256 * 64];
  const int tid = threadIdx.x;
  const int lane = tid & 63;
  const int wid = tid >> 6;
  const int wm = wid >> 2, wn = wid & 3;
  const int l15 = lane & 15, lhi = lane >> 4;
  const int c7 = l15 & 7;
  // T1: XCD-aware bijective swizzle (grid count % 8 == 0 guaranteed by launch)
  const int nwg = gridDim.x * gridDim.y;
  const int id = blockIdx.y * gridDim.x + blockIdx.x;
  const int cpx = nwg >> 3;
  const int swz = (id & 7) * cpx + (id >> 3);
  const long m0 = (long)(swz / gridDim.x) * 256;
  const long n0 = (long)(swz % gridDim.x) * 256;
  const int NT = K >> 6;

  const int srow = tid >> 3;
  const int sunit = (tid & 7) * 8;
  const u16* agp = A + (m0 + srow) * K + sunit;
  const u16* bgp = Bw + (n0 + srow) * K + sunit;
  const int ldst = tid * 8;

  auto stageA = [&](int kt, int b) {
    const int k0 = kt << 6;
    u16* d = &Ab[b][0];
#pragma unroll
    for (int c = 0; c < 4; ++c)
      gl_lds16(agp + (long)(c * 64) * K + k0, d + c * 4096 + ldst);
  };
  auto stageB = [&](int kt, int b) {
    const int k0 = kt << 6;
    u16* d = &Bb[b][0];
#pragma unroll
    for (int c = 0; c < 4; ++c)
      gl_lds16(bgp + (long)(c * 64) * K + k0, d + c * 4096 + ldst);
  };

#define READ_A(MH)                                                               \
  _Pragma("unroll") for (int m_ = 0; m_ < 4; ++m_) {                             \
    _Pragma("unroll") for (int ks_ = 0; ks_ < 2; ++ks_) {                        \
      Afr[MH][m_ * 2 + ks_] =                                                    \
          *(const bf16x8*)&Ac[(wm * 128 + (MH)*64 + m_ * 16 + l15) * 64 +        \
                              (((ks_ * 4 + lhi) ^ c7) * 8)];                     \
    }                                                                            \
  }
#define READ_B(NH)                                                               \
  _Pragma("unroll") for (int n_ = 0; n_ < 2; ++n_) {                             \
    _Pragma("unroll") for (int ks_ = 0; ks_ < 2; ++ks_) {                        \
      Bfr[NH][n_ * 2 + ks_] =                                                    \
          *(const bf16x8*)&Bc[(wn * 64 + (NH)*32 + n_ * 16 + l15) * 64 +         \
                              (((ks_ * 4 + lhi) ^ c7) * 8)];                     \
    }                                                                            \
  }
#define QUAD(MH, NH)                                                             \
  do {                                                                           \
    __builtin_amdgcn_s_setprio(1);                                               \
    _Pragma("unroll") for (int m_ = 0; m_ < 4; ++m_) {                           \
      _Pragma("unroll") for (int n_ = 0; n_ < 2; ++n_) {                         \
        acc[(MH)*4 + m_][(NH)*2 + n_] =                                          \
            MFMA16(Afr[MH][m_ * 2], Bfr[NH][n_ * 2],                             \
                   acc[(MH)*4 + m_][(NH)*2 + n_], 0, 0, 0);                      \
        acc[(MH)*4 + m_][(NH)*2 + n_] =                                          \
            MFMA16(Afr[MH][m_ * 2 + 1], Bfr[NH][n_ * 2 + 1],                     \
                   acc[(MH)*4 + m_][(NH)*2 + n_], 0, 0, 0);                      \
      }                                                                          \
    }                                                                            \
    __builtin_amdgcn_s_setprio(0);                                               \
  } while (0)

  f32x4 acc[8][4] = {};

  // prologue: tiles 0,1 staged; wait tile 0 (tile 1 stays in flight)
  stageA(0, 0);
  stageB(0, 0);
  stageA(1, 1);
  stageB(1, 1);
  asm volatile("s_waitcnt vmcnt(8)" ::: "memory");
  __builtin_amdgcn_s_barrier();
  GFENCE();

  for (int kt = 0; kt < NT; ++kt) {
    const int b = kt & 1;
    const u16* Ac = &Ab[b][0];
    const u16* Bc = &Bb[b][0];
    bf16x8 Afr[2][8], Bfr[2][4];
    // P0: read A-half0 + B-half0
    READ_A(0);
    READ_B(0);
    BARF();
    QUAD(0, 0);
    BARF();
    // P1: read A-half1 + B-half1
    READ_A(1);
    READ_B(1);
    BARF();
    QUAD(0, 1);
    BARF();
    // P2: stage A(kt+2) (A regions free after P1)
    if (kt + 2 < NT) stageA(kt + 2, b);
    BARF();
    QUAD(1, 0);
    BARF();
    // P3: stage B(kt+2)
    if (kt + 2 < NT) stageB(kt + 2, b);
    BARF();
    QUAD(1, 1);
    // K-tile boundary: next tile must be resident; keep prefetch in flight
    if (kt + 1 < NT) {
      if (kt + 2 < NT)
        asm volatile("s_waitcnt vmcnt(8)" ::: "memory");
      else
        asm volatile("s_waitcnt vmcnt(0)" ::: "memory");
      __builtin_amdgcn_s_barrier();
      GFENCE();
    }
  }
#undef READ_A
#undef READ_B
#undef QUAD

#pragma unroll
  for (int mi = 0; mi < 8; ++mi) {
    const long row0 = m0 + wm * 128 + mi * 16 + lhi * 4;
#pragma unroll
    for (int ni = 0; ni < 4; ++ni) {
      const long col = n0 + wn * 64 + ni * 16 + l15;
      const float bb = bias[col];
#pragma unroll
      for (int r = 0; r < 4; ++r) {
        float v = acc[mi][ni][r] + bb;
        if (EPI == 2) {
          float other = __shfl_xor(v, 1, 64);
          if (!(l15 & 1)) {
            float s = v / (1.f + __expf(-v)) * other;  // silu(g)*v
            out_bf[(row0 + r) * (N >> 1) + (col >> 1)] = f2bf(s);
          }
        } else {
          out_bf[(row0 + r) * N + col] = f2bf(v);
        }
      }
    }
  }
}

// ---------------- 3-buffer GEMM (linear layouts) for skinny N ----------------
template <int EPI, int NB>
__global__ __launch_bounds__(256) void gemm_bt(const u16* __restrict__ A,
                                               const u16* __restrict__ Bw,
                                               const float* __restrict__ bias,
                                               const float* __restrict__ resid,
                                               u16* __restrict__ out_bf,
                                               float* __restrict__ out_f,
                                               int N, int K) {
  constexpr int BHALF = NB / 64;
  constexpr int NFR = NB / 32;
  constexpr int LPT = 2 + BHALF;
  __shared__ __align__(16) u16 As[3][128 * 32];
  __shared__ __align__(16) u16 Bs[3][NB * 32];
  const int tid = threadIdx.x;
  const int lane = tid & 63;
  const int wv = tid >> 6;
  const int wr = wv >> 1, wc = wv & 1;
  const long m0 = (long)blockIdx.y * 128;
  const long n0 = (long)blockIdx.x * NB;

  const int arow = tid >> 2;
  const int acol = (tid & 3) << 3;
  const u16* ag = A + (m0 + arow) * K + acol;
  const u16* bg = Bw + (n0 + arow) * K + acol;
  const long hK = (long)64 * K;

  f32x4 acc[4][NFR] = {};
  const int l15 = lane & 15;
  const int lhi = lane >> 4;
  const int aoff0 = (wr * 64 + l15) * 32 + lhi * 8;
  const int boff0 = (wc * (NB / 2) + l15) * 32 + lhi * 8;
  const int nk = K >> 5;

  auto stage = [&](int t, int buf) {
    const int k0 = t << 5;
    gl_lds16(ag + k0, &As[buf][tid * 8]);
    gl_lds16(ag + k0 + hK, &As[buf][2048 + tid * 8]);
    gl_lds16(bg + k0, &Bs[buf][tid * 8]);
    if (BHALF == 2) gl_lds16(bg + k0 + hK, &Bs[buf][2048 + tid * 8]);
  };

  stage(0, 0);
  stage(1, 1);
  asm volatile("s_waitcnt vmcnt(%0)" ::"n"(LPT) : "memory");
  __builtin_amdgcn_s_barrier();
  GFENCE();

  for (int t = 0; t < nk; ++t) {
    const int cb = t % 3;
    if (t + 2 < nk) stage(t + 2, (t + 2) % 3);
    bf16x8 af[4], bfr[NFR];
#pragma unroll
    for (int i = 0; i < 4; ++i) af[i] = *(const bf16x8*)&As[cb][aoff0 + i * 16 * 32];
#pragma unroll
    for (int j = 0; j < NFR; ++j) bfr[j] = *(const bf16x8*)&Bs[cb][boff0 + j * 16 * 32];
    __builtin_amdgcn_s_setprio(1);
#pragma unroll
    for (int i = 0; i < 4; ++i)
#pragma unroll
      for (int j = 0; j < NFR; ++j)
        acc[i][j] = MFMA16(af[i], bfr[j], acc[i][j], 0, 0, 0);
    __builtin_amdgcn_s_setprio(0);
    if (t + 2 < nk) {
      asm volatile("s_waitcnt vmcnt(%0)" ::"n"(LPT) : "memory");
      __builtin_amdgcn_s_barrier();
      GFENCE();
    } else if (t + 1 < nk) {
      asm volatile("s_waitcnt vmcnt(0)" ::: "memory");
      __builtin_amdgcn_s_barrier();
      GFENCE();
    }
  }

#pragma unroll
  for (int i = 0; i < 4; ++i) {
    const long row0 = m0 + wr * 64 + i * 16 + lhi * 4;
#pragma unroll
    for (int j = 0; j < NFR; ++j) {
      const long col = n0 + wc * (NB / 2) + j * 16 + l15;
      const float bb = bias[col];
#pragma unroll
      for (int r = 0; r < 4; ++r) {
        const long idx = (row0 + r) * N + col;
        float v = acc[i][j][r] + bb;
        if (EPI == 0) out_bf[idx] = f2bf(v);
        else          out_f[idx] = resid[idx] + v;
      }
    }
  }
}

// ---------------- fused RoPE(Q), RoPE(K)+concat, V-transpose+concat ----------------
// blocks [0,2048): Q; [2048,5120): K; [5120,8192): Vt
__global__ __launch_bounds__(256) void rope_all_kernel(const u16* __restrict__ qkv,
                                                       const float* __restrict__ cache_k,
                                                       const float* __restrict__ cache_v,
                                                       const float* __restrict__ cosT,
                                                       const float* __restrict__ sinT,
                                                       u16* __restrict__ Q,
                                                       u16* __restrict__ Kall,
                                                       u16* __restrict__ Vtg) {
  const int blk = blockIdx.x;
  if (blk < 2048) {
    int idx = blk * 256 + threadIdx.x;  // B*H*S*8 = 524288 units of 8 elems
    int u = idx & 7;
    int s = (idx >> 3) & (S_LEN - 1);
    int bh = idx >> 14;
    int b = bh >> 4, h = bh & 15;
    int pos = PREV + s;
    const float SC = 0.125f * LOG2E;
    const u16* src = qkv + ((long)(b * S_LEN + s)) * (3 * DIM) + h * HD + u * 8;
    u32x4 d = *(const u32x4*)src;
    f32x4 cv = *(const f32x4*)&cosT[(long)pos * 32 + u * 4];
    f32x4 sv = *(const f32x4*)&sinT[(long)pos * 32 + u * 4];
    u32x4 o;
#pragma unroll
    for (int p = 0; p < 4; ++p) {
      float x0 = bf2f((u16)(d[p] & 0xffff));
      float x1 = bf2f((u16)(d[p] >> 16));
      float y0 = (x0 * cv[p] - x1 * sv[p]) * SC;
      float y1 = (x0 * sv[p] + x1 * cv[p]) * SC;
      o[p] = (u32)f2bf(y0) | ((u32)f2bf(y1) << 16);
    }
    *(u32x4*)&Q[((long)bh * S_LEN + s) * HD + u * 8] = o;
  } else if (blk < 5120) {
    int idx = (blk - 2048) * 256 + threadIdx.x;  // B*H*T*8 = 786432
    int u = idx & 7;
    int t2 = idx >> 3;
    int j = t2 % T_LEN;
    int bh = t2 / T_LEN;
    int b = bh >> 4, h = bh & 15;
    float e[8];
    if (j < PREV) {
      const float* src = cache_k + ((long)bh * PREV + j) * HD + u * 8;
      f32x4 a = *(const f32x4*)src;
      f32x4 c = *(const f32x4*)(src + 4);
      e[0] = a[0]; e[1] = a[1]; e[2] = a[2]; e[3] = a[3];
      e[4] = c[0]; e[5] = c[1]; e[6] = c[2]; e[7] = c[3];
    } else {
      const u16* src = qkv + ((long)(b * S_LEN + (j - PREV))) * (3 * DIM) + DIM + h * HD + u * 8;
      u32x4 d = *(const u32x4*)src;
#pragma unroll
      for (int p = 0; p < 4; ++p) {
        e[2 * p] = bf2f((u16)(d[p] & 0xffff));
        e[2 * p + 1] = bf2f((u16)(d[p] >> 16));
      }
    }
    f32x4 cv = *(const f32x4*)&cosT[(long)j * 32 + u * 4];
    f32x4 sv = *(const f32x4*)&sinT[(long)j * 32 + u * 4];
    u32x4 o;
#pragma unroll
    for (int p = 0; p < 4; ++p) {
      float y0 = e[2 * p] * cv[p] - e[2 * p + 1] * sv[p];
      float y1 = e[2 * p] * sv[p] + e[2 * p + 1] * cv[p];
      o[p] = (u32)f2bf(y0) | ((u32)f2bf(y1) << 16);
    }
    *(u32x4*)&Kall[((long)bh * T_LEN + j) * HD + (u ^ (j & 7)) * 8] = o;
  } else {
    int idx = (blk - 5120) * 256 + threadIdx.x;  // 32 * 384 * 64 = 786432
    int hd = idx & 63;
    int t2 = idx >> 6;
    int kb = t2 % 384;  // 8-key block
    int bh = t2 / 384;
    int b = bh >> 4, h = bh & 15;
    int key0 = kb * 8;
    u16 vals[8];
    if (key0 < PREV) {
#pragma unroll
      for (int i = 0; i < 8; ++i)
        vals[i] = f2bf(cache_v[((long)bh * PREV + key0 + i) * HD + hd]);
    } else {
#pragma unroll
      for (int i = 0; i < 8; ++i)
        vals[i] = qkv[((long)(b * S_LEN + key0 + i - PREV)) * (3 * DIM) + 2 * DIM + h * HD + hd];
    }
    u32x4 o;
#pragma unroll
    for (int p = 0; p < 4; ++p)
      o[p] = (u32)vals[2 * p] | ((u32)vals[2 * p + 1] << 16);
    const int span = kb >> 3;
    const int u = (kb & 7) ^ (hd & 7);
    *(u32x4*)&Vtg[((long)bh * HD + hd) * T_LEN + span * 64 + u * 8] = o;
  }
}

// ---------------- flash attention: paired dual-Q blocks, shared KV sweep ----------------
__global__ __launch_bounds__(256, 2) void attn_kernel(const u16* __restrict__ Q,
                                                      const u16* __restrict__ Kg,
                                                      const u16* __restrict__ Vtg,
                                                      u16* __restrict__ ctx, float slope2) {
  __shared__ __align__(16) u16 Ks[2][64 * 64];     // [key][d], swizzled
  __shared__ __align__(16) u16 Vs[2][64 * 64];     // [hd][key], swizzled
  __shared__ __align__(16) u16 Ps[2][4][16 * 64];  // per-qset per-wave P, swizzled

  const int tid = threadIdx.x;
  const int lane = tid & 63;
  const int wv = tid >> 6;
  const int l15 = lane & 15;
  const int lhi = lane >> 4;
  const int c7 = l15 & 7;
  const int bh = blockIdx.x;
  const int p = blockIdx.y;            // pair index 0..15
  const int b = bh >> 4, h = bh & 15;
  const int qA0 = p * 64;
  const int qB0 = (31 - p) * 64;
  const int ntA = 17 + p;              // (PREV + qA0 + 64) >> 6
  const int ntB = 48 - p;              // ntA + ntB = 65

  const long qrowA = (long)bh * S_LEN + qA0 + wv * 16 + l15;
  const long qrowB = (long)bh * S_LEN + qB0 + wv * 16 + l15;
  bf16x8 aqA0 = *(const bf16x8*)&Q[qrowA * HD + lhi * 8];
  bf16x8 aqA1 = *(const bf16x8*)&Q[qrowA * HD + 32 + lhi * 8];
  bf16x8 aqB0 = *(const bf16x8*)&Q[qrowB * HD + lhi * 8];
  bf16x8 aqB1 = *(const bf16x8*)&Q[qrowB * HD + 32 + lhi * 8];

  const long kgb = (long)bh * T_LEN * HD;  // K: [key][64]
  const long vgb = (long)bh * HD * T_LEN;  // Vt: [hd][T]
  const int srow = tid >> 3;               // staging row 0..31
  const int sunit = (tid & 7) * 8;

  const u16* kst = Kg + kgb + (long)srow * HD + sunit;     // +64*HD per tile
  const u16* vst = Vtg + vgb + (long)srow * T_LEN + sunit; // +64 per tile

  // prologue: stage tile 0
  gl_lds16(kst, &Ks[0][tid * 8]);
  gl_lds16(kst + 32 * HD, &Ks[0][2048 + tid * 8]);
  gl_lds16(vst, &Vs[0][tid * 8]);
  gl_lds16(vst + (long)32 * T_LEN, &Vs[0][2048 + tid * 8]);
  kst += 64 * HD;
  vst += 64;
  __syncthreads();

  f32x4 oA[4] = {}, oB[4] = {};
  f32x4 lrunA = {0.f, 0.f, 0.f, 0.f}, lrunB = {0.f, 0.f, 0.f, 0.f};
  float mrunA = -1e30f, mrunB = -1e30f;
  const int qq = wv * 16 + l15;  // local q (mask threshold, same layout both q-sets)

  f32x4 be[4];  // per-thread bias constants slope*(jf*16+4*lhi+r)
#pragma unroll
  for (int jf = 0; jf < 4; ++jf)
#pragma unroll
    for (int r = 0; r < 4; ++r)
      be[jf][r] = slope2 * (float)(jf * 16 + 4 * lhi + r);
  const float bmax = slope2 * 63.f;

  bf16x8 vones;
#pragma unroll
  for (int e = 0; e < 8; ++e) vones[e] = (__bf16)1.0f;

  float ktf = 0.f;
  const float kstep = slope2 * 64.f;

  // softmax + PV for one q-set (separate P buffer per q-set)
  auto process = [&](f32x4 (&sf)[4], bool maskNow, f32x4 (&o)[4], f32x4& lrun,
                     float& mrun, bf16x8 (&vf)[8], u16* Pw) {
    if (maskNow) {
#pragma unroll
      for (int jf = 0; jf < 4; ++jf)
#pragma unroll
        for (int r = 0; r < 4; ++r)
          if (jf * 16 + 4 * lhi + r > qq) sf[jf][r] = -1e30f;
    }
    float h0 = fmaxf(fmaxf(sf[0][0], sf[0][1]), fmaxf(sf[0][2], sf[0][3]));
    float h1 = fmaxf(fmaxf(sf[1][0], sf[1][1]), fmaxf(sf[1][2], sf[1][3]));
    float h2 = fmaxf(fmaxf(sf[2][0], sf[2][1]), fmaxf(sf[2][2], sf[2][3]));
    float h3 = fmaxf(fmaxf(sf[3][0], sf[3][1]), fmaxf(sf[3][2], sf[3][3]));
    float pm = fmaxf(fmaxf(h0, h1), fmaxf(h2, h3));
    pm = fmaxf(pm, __shfl_xor(pm, 16, 64));
    pm = fmaxf(pm, __shfl_xor(pm, 32, 64));
    const float pmax_abs = pm + ktf + bmax;

    if (!__all(pmax_abs - mrun <= 8.f)) {
      const float mnew = fmaxf(mrun, pmax_abs);
      const float scl = exp2f(mrun - mnew);
      mrun = mnew;
#pragma unroll
      for (int r = 0; r < 4; ++r) {
        const float sr = __shfl(scl, 4 * lhi + r, 64);
        lrun[r] *= sr;
#pragma unroll
        for (int hf = 0; hf < 4; ++hf) o[hf][r] *= sr;
      }
    }
    const float meff = mrun - ktf;

#pragma unroll
    for (int jf = 0; jf < 4; ++jf) {
      f32x4 pp;
#pragma unroll
      for (int r = 0; r < 4; ++r)
        pp[r] = exp2f(sf[jf][r] + (be[jf][r] - meff));
      u32x2 pw2;
      pw2[0] = cvtpk(pp[0], pp[1]);
      pw2[1] = cvtpk(pp[2], pp[3]);
      const int u = (2 * jf + (lhi >> 1)) ^ c7;
      *(u32x2*)&Pw[l15 * 64 + u * 8 + (lhi & 1) * 4] = pw2;
    }

    bf16x8 pa0 = *(const bf16x8*)&Pw[l15 * 64 + ((lhi ^ c7) * 8)];
    bf16x8 pa1 = *(const bf16x8*)&Pw[l15 * 64 + (((4 + lhi) ^ c7) * 8)];
    f32x4 psum = {};
    __builtin_amdgcn_s_setprio(1);
    psum = MFMA16(pa0, vones, psum, 0, 0, 0);
    psum = MFMA16(pa1, vones, psum, 0, 0, 0);
#pragma unroll
    for (int hf = 0; hf < 4; ++hf) {
      o[hf] = MFMA16(pa0, vf[2 * hf], o[hf], 0, 0, 0);
      o[hf] = MFMA16(pa1, vf[2 * hf + 1], o[hf], 0, 0, 0);
    }
    __builtin_amdgcn_s_setprio(0);
    lrun += psum;
  };

  for (int t = 0; t < ntB; ++t) {
    const int cur = t & 1, nxt = cur ^ 1;
    const bool lastStage = (t + 1 == ntB);
    if (!lastStage) {
      gl_lds16(kst, &Ks[nxt][tid * 8]);
      gl_lds16(kst + 32 * HD, &Ks[nxt][2048 + tid * 8]);
      gl_lds16(vst, &Vs[nxt][tid * 8]);
      gl_lds16(vst + (long)32 * T_LEN, &Vs[nxt][2048 + tid * 8]);
      kst += 64 * HD;
      vst += 64;
    }
    const bool actA = (t < ntA);

    // K fragments once, shared by both q-sets
    bf16x8 kf[8];
#pragma unroll
    for (int jf = 0; jf < 4; ++jf) {
      const int krow = jf * 16 + l15;
      kf[2 * jf] = *(const bf16x8*)&Ks[cur][krow * 64 + ((lhi ^ c7) * 8)];
      kf[2 * jf + 1] = *(const bf16x8*)&Ks[cur][krow * 64 + (((4 + lhi) ^ c7) * 8)];
    }
    // V fragments once, shared by both q-sets
    bf16x8 vf[8];
#pragma unroll
    for (int hf = 0; hf < 4; ++hf) {
      const int vrow = hf * 16 + l15;
      vf[2 * hf] = *(const bf16x8*)&Vs[cur][vrow * 64 + ((lhi ^ c7) * 8)];
      vf[2 * hf + 1] = *(const bf16x8*)&Vs[cur][vrow * 64 + (((4 + lhi) ^ c7) * 8)];
    }

    // QK^T for both q-sets
    f32x4 sB[4], sA[4];
    __builtin_amdgcn_s_setprio(1);
#pragma unroll
    for (int jf = 0; jf < 4; ++jf) {
      f32x4 s = {};
      s = MFMA16(kf[2 * jf], aqB0, s, 0, 0, 0);
      s = MFMA16(kf[2 * jf + 1], aqB1, s, 0, 0, 0);
      sB[jf] = s;
    }
    __builtin_amdgcn_s_setprio(0);
    if (actA) {
      __builtin_amdgcn_s_setprio(1);
#pragma unroll
      for (int jf = 0; jf < 4; ++jf) {
        f32x4 s = {};
        s = MFMA16(kf[2 * jf], aqA0, s, 0, 0, 0);
        s = MFMA16(kf[2 * jf + 1], aqA1, s, 0, 0, 0);
        sA[jf] = s;
      }
      __builtin_amdgcn_s_setprio(0);
    }

    process(sB, t == ntB - 1, oB, lrunB, mrunB, vf, &Ps[0][wv][0]);
    if (actA) process(sA, t == ntA - 1, oA, lrunA, mrunA, vf, &Ps[1][wv][0]);

    ktf += kstep;
    if (!lastStage) __syncthreads();
  }

  // epilogue: rows q_local = 4*lhi + r; cols hd = hf*16 + l15
#pragma unroll
  for (int r = 0; r < 4; ++r) {
    const float invA = 1.f / lrunA[r];
    const float invB = 1.f / lrunB[r];
    const long rowA = (long)b * S_LEN + qA0 + wv * 16 + 4 * lhi + r;
    const long rowB = (long)b * S_LEN + qB0 + wv * 16 + 4 * lhi + r;
#pragma unroll
    for (int hf = 0; hf < 4; ++hf) {
      ctx[rowA * DIM + h * HD + hf * 16 + l15] = f2bf(oA[hf][r] * invA);
      ctx[rowB * DIM + h * HD + hf * 16 + l15] = f2bf(oB[hf][r] * invB);
    }
  }
}

// ---------------------------------------------------------------------------
extern "C" void kernel_launch(void* const* d_in, const int* in_sizes, int n_in,
                              void* d_out, int out_size, void* d_ws, size_t ws_size,
                              hipStream_t stream) {
  (void)in_sizes; (void)n_in; (void)out_size; (void)ws_size;
  const float* x       = (const float*)d_in[0];
  const float* cache_k = (const float*)d_in[1];
  const float* cache_v = (const float*)d_in[2];
  const float* cosT    = (const float*)d_in[3];
  const float* sinT    = (const float*)d_in[4];
  const float* attn_w  = (const float*)d_in[5];
  const float* ffn_w   = (const float*)d_in[6];
  const float* wq      = (const float*)d_in[7];
  const float* bq      = (const float*)d_in[8];
  const float* wk      = (const float*)d_in[9];
  const float* bk      = (const float*)d_in[10];
  const float* wv_     = (const float*)d_in[11];
  const float* bv      = (const float*)d_in[12];
  const float* wo      = (const float*)d_in[13];
  const float* bo      = (const float*)d_in[14];
  const float* wg      = (const float*)d_in[15];
  const float* bg      = (const float*)d_in[16];
  const float* wval    = (const float*)d_in[17];
  const float* bval    = (const float*)d_in[18];
  const float* wp      = (const float*)d_in[19];
  const float* bp      = (const float*)d_in[20];
  float* out = (float*)d_out;

  char* w = (char*)d_ws;
  size_t off = 0;
  auto alloc = [&](size_t bytes) -> char* {
    char* p = w + off;
    off += (bytes + 255) & ~(size_t)255;
    return p;
  };
  // permanent
  u16*   wqkv_bf  = (u16*)alloc((size_t)3 * DIM * DIM * 2);  // preswizzled
  u16*   wo_bf    = (u16*)alloc((size_t)DIM * DIM * 2);      // linear
  u16*   wgv_bf   = (u16*)alloc((size_t)2 * FF * DIM * 2);   // interleaved+preswizzled
  u16*   wproj_bf = (u16*)alloc((size_t)DIM * FF * 2);       // linear
  float* bqkv     = (float*)alloc((size_t)3 * DIM * 4);
  float* bgv      = (float*)alloc((size_t)2 * FF * 4);       // interleaved
  float* x2       = (float*)alloc((size_t)MROWS * DIM * 4);
  // arena with lifetime-based aliasing
  char* AR = alloc((size_t)117440512);
  u16* qkv   = (u16*)(AR + 0);          // [4096][3072]   live: qkv gemm -> rope/build
  u16* Qb    = (u16*)(AR + 25165824);   // [32][2048][64] live: rope -> attn
  u16* Kb    = (u16*)(AR + 33554432);   // [32][3072][64]
  u16* Vtg   = (u16*)(AR + 46137344);   // [32][64][3072] transposed V
  u16* h1    = (u16*)(AR + 58720256);   // [4096][1024]   preswizzled (qkv gemm A)
  u16* ctx   = (u16*)(AR + 0);          // [4096][1024]   linear (aliases dead qkv)
  u16* h2    = (u16*)(AR + 8388608);    // [4096][1024]   preswizzled (gv gemm A)
  u16* gated = (u16*)(AR + 16777216);   // [4096][4096]   linear

  // 1) weight/bias prep (5 launches)
  cvt_qkv_sw_kernel<<<1024, 256, 0, stream>>>(wq, wk, wv_, wqkv_bf);
  cvt_kernel<<<512, 256, 0, stream>>>(wo, wo_bf, DIM * DIM / 4);
  cvt_ilv_sw_kernel<<<1024, 256, 0, stream>>>(wg, wval, wgv_bf);
  cvt_kernel<<<1024, 256, 0, stream>>>(wp, wproj_bf, DIM * FF / 4);
  bias_pack_kernel<<<28, 256, 0, stream>>>(bq, bk, bv, bg, bval, bqkv, bgv);

  // 2) attn rmsnorm (swizzled out), fused QKV 256-gemm
  rmsnorm_kernel<<<MROWS, 256, 0, stream>>>(x, attn_w, h1);
  gemm256<0><<<dim3(12, 16), 512, 0, stream>>>(h1, wqkv_bf, bqkv, qkv, 3 * DIM, DIM);
  // 3) fused rope + cache concat (1 launch)
  rope_all_kernel<<<8192, 256, 0, stream>>>(qkv, cache_k, cache_v, cosT, sinT,
                                            Qb, Kb, Vtg);
  // 4) attention: paired dual-Q blocks
  attn_kernel<<<dim3(B_SZ * NH, 16), 256, 0, stream>>>(
      Qb, Kb, Vtg, ctx, (2.0f / (float)(T_LEN - 1)) * LOG2E);
  // 5) o-proj + residual (fp32), skinny tile
  gemm_bt<1, 64><<<dim3(16, 32), 256, 0, stream>>>(ctx, wo_bf, bo, x, nullptr, x2,
                                                   DIM, DIM);
  // 6) ffn rmsnorm (swizzled out), gate+value 256-gemm w/ silu epilogue, proj + residual
  rmsnorm_kernel<<<MROWS, 256, 0, stream>>>(x2, ffn_w, h2);
  gemm256<2><<<dim3(32, 16), 512, 0, stream>>>(h2, wgv_bf, bgv, gated, 2 * FF, DIM);
  gemm_bt<1, 64><<<dim3(16, 32), 256, 0, stream>>>(gated, wproj_bf, bp, x2, nullptr, out,
                                                   DIM, FF);
}

// Round 9
// 348.617 us; speedup vs baseline: 1.6191x; 1.0358x over previous
//
#include <hip/hip_runtime.h>
#include <stdint.h>

typedef unsigned short u16;
typedef unsigned int   u32;
typedef __bf16 bf16x8 __attribute__((ext_vector_type(8)));
typedef float  f32x4  __attribute__((ext_vector_type(4)));
typedef u32    u32x4  __attribute__((ext_vector_type(4)));
typedef u32    u32x2  __attribute__((ext_vector_type(2)));

#define B_SZ  2
#define S_LEN 2048
#define NH    16
#define HD    64
#define DIM   1024
#define FF    4096
#define T_LEN 3072
#define PREV  1024
#define MROWS (B_SZ * S_LEN) /* 4096 */
#define LOG2E 1.44269504f

#define MFMA16 __builtin_amdgcn_mfma_f32_16x16x32_bf16

__device__ __forceinline__ u16 f2bf(float f) {
  u32 u = __builtin_bit_cast(u32, f);
  u32 r = u + 0x7FFFu + ((u >> 16) & 1u);
  return (u16)(r >> 16);
}
__device__ __forceinline__ float bf2f(u16 h) {
  u32 u = ((u32)h) << 16;
  return __builtin_bit_cast(float, u);
}
__device__ __forceinline__ u32 cvtpk(float lo, float hi) {
  u32 r;
  asm("v_cvt_pk_bf16_f32 %0, %1, %2" : "=v"(r) : "v"(lo), "v"(hi));
  return r;
}

// async global->LDS, 16B per lane. LDS dest must be wave-uniform base + lane*16.
__device__ __forceinline__ void gl_lds16(const void* g, void* l) {
  __builtin_amdgcn_global_load_lds(
      (const __attribute__((address_space(1))) u32*)g,
      (__attribute__((address_space(3))) u32*)l, 16, 0, 0);
}

#define GFENCE() asm volatile("" ::: "memory")
#define BARF()                         \
  do {                                 \
    GFENCE();                          \
    __builtin_amdgcn_s_barrier();      \
    GFENCE();                          \
  } while (0)

// ---------------- ALL weight/bias conversion in ONE launch ----------------
// Block-uniform segment ranges (all multiples of 256):
//   [0, 393216): wqkv preswizzled   (8-elem units)
//   [+524288):   wgv interleave+sw  (8-elem g AND 8-elem v per unit)
//   [+131072):   wo linear          (8-elem)
//   [+524288):   wp linear          (8-elem)
//   [+7168):     bias packs
__global__ __launch_bounds__(256) void cvt_all_kernel(
    const float* __restrict__ wq, const float* __restrict__ wk,
    const float* __restrict__ wv, const float* __restrict__ wg,
    const float* __restrict__ wval, const float* __restrict__ wo,
    const float* __restrict__ wp, const float* __restrict__ bq,
    const float* __restrict__ bk, const float* __restrict__ bv,
    const float* __restrict__ bg, const float* __restrict__ bval,
    u16* __restrict__ wqkv_bf, u16* __restrict__ wgv_bf,
    u16* __restrict__ wo_bf, u16* __restrict__ wp_bf,
    float* __restrict__ bqkv, float* __restrict__ bgv) {
  long gid = (long)blockIdx.x * 256 + threadIdx.x;
  if (gid < 393216) {  // wqkv, K-unit XOR-preswizzled
    int i = (int)gid;
    const int seg = i >> 17;
    const int loc = i & 131071;
    const float* src = (seg == 0) ? wq : (seg == 1) ? wk : wv;
    int row = loc >> 7;
    int g = loc & 127;
    const float* s = &src[((long)row << 10) + g * 8];
    f32x4 a = *(const f32x4*)s;
    f32x4 b = *(const f32x4*)(s + 4);
    u32x4 o;
    o[0] = (u32)f2bf(a[0]) | ((u32)f2bf(a[1]) << 16);
    o[1] = (u32)f2bf(a[2]) | ((u32)f2bf(a[3]) << 16);
    o[2] = (u32)f2bf(b[0]) | ((u32)f2bf(b[1]) << 16);
    o[3] = (u32)f2bf(b[2]) | ((u32)f2bf(b[3]) << 16);
    const int gp = (g & ~7) | ((g & 7) ^ (row & 7));
    *(u32x4*)&wqkv_bf[((long)seg << 20) + ((long)row << 10) + gp * 8] = o;
    return;
  }
  gid -= 393216;
  if (gid < 524288) {  // wgv interleave + preswizzle
    int i = (int)gid;
    int j = i >> 7;
    int g = i & 127;
    const float* sg = &wg[((long)j << 10) + g * 8];
    const float* sv = &wval[((long)j << 10) + g * 8];
    f32x4 a = *(const f32x4*)sg;
    f32x4 b = *(const f32x4*)(sg + 4);
    u32x4 og;
    og[0] = (u32)f2bf(a[0]) | ((u32)f2bf(a[1]) << 16);
    og[1] = (u32)f2bf(a[2]) | ((u32)f2bf(a[3]) << 16);
    og[2] = (u32)f2bf(b[0]) | ((u32)f2bf(b[1]) << 16);
    og[3] = (u32)f2bf(b[2]) | ((u32)f2bf(b[3]) << 16);
    f32x4 c = *(const f32x4*)sv;
    f32x4 d = *(const f32x4*)(sv + 4);
    u32x4 ov;
    ov[0] = (u32)f2bf(c[0]) | ((u32)f2bf(c[1]) << 16);
    ov[1] = (u32)f2bf(c[2]) | ((u32)f2bf(c[3]) << 16);
    ov[2] = (u32)f2bf(d[0]) | ((u32)f2bf(d[1]) << 16);
    ov[3] = (u32)f2bf(d[2]) | ((u32)f2bf(d[3]) << 16);
    const int rg = 2 * j, rv = 2 * j + 1;
    const int gpg = (g & ~7) | ((g & 7) ^ (rg & 7));
    const int gpv = (g & ~7) | ((g & 7) ^ (rv & 7));
    *(u32x4*)&wgv_bf[((long)rg << 10) + gpg * 8] = og;
    *(u32x4*)&wgv_bf[((long)rv << 10) + gpv * 8] = ov;
    return;
  }
  gid -= 524288;
  if (gid < 131072) {  // wo linear
    int i = (int)gid;
    f32x4 a = *(const f32x4*)&wo[(long)i * 8];
    f32x4 b = *(const f32x4*)&wo[(long)i * 8 + 4];
    u32x4 o;
    o[0] = (u32)f2bf(a[0]) | ((u32)f2bf(a[1]) << 16);
    o[1] = (u32)f2bf(a[2]) | ((u32)f2bf(a[3]) << 16);
    o[2] = (u32)f2bf(b[0]) | ((u32)f2bf(b[1]) << 16);
    o[3] = (u32)f2bf(b[2]) | ((u32)f2bf(b[3]) << 16);
    *(u32x4*)&wo_bf[(long)i * 8] = o;
    return;
  }
  gid -= 131072;
  if (gid < 524288) {  // wp linear
    int i = (int)gid;
    f32x4 a = *(const f32x4*)&wp[(long)i * 8];
    f32x4 b = *(const f32x4*)&wp[(long)i * 8 + 4];
    u32x4 o;
    o[0] = (u32)f2bf(a[0]) | ((u32)f2bf(a[1]) << 16);
    o[1] = (u32)f2bf(a[2]) | ((u32)f2bf(a[3]) << 16);
    o[2] = (u32)f2bf(b[0]) | ((u32)f2bf(b[1]) << 16);
    o[3] = (u32)f2bf(b[2]) | ((u32)f2bf(b[3]) << 16);
    *(u32x4*)&wp_bf[(long)i * 8] = o;
    return;
  }
  gid -= 524288;
  {  // bias packs
    int i = (int)gid;
    if (i < 3 * DIM) {
      float v = (i < DIM) ? bq[i] : (i < 2 * DIM) ? bk[i - DIM] : bv[i - 2 * DIM];
      bqkv[i] = v;
    } else if (i < 3 * DIM + FF) {
      int j = i - 3 * DIM;
      bgv[2 * j] = bg[j];
      bgv[2 * j + 1] = bval[j];
    }
  }
}

// ---------------- RMSNorm: fp32 row -> bf16 row, K-unit XOR-preswizzled out ----------------
__global__ __launch_bounds__(256) void rmsnorm_kernel(const float* __restrict__ x,
                                                      const float* __restrict__ w,
                                                      u16* __restrict__ out) {
  const int row = blockIdx.x;
  const int tid = threadIdx.x;
  const long base = (long)row * DIM + tid * 4;
  f32x4 v = *(const f32x4*)&x[base];
  float ss = v[0] * v[0] + v[1] * v[1] + v[2] * v[2] + v[3] * v[3];
#pragma unroll
  for (int d = 1; d <= 32; d <<= 1) ss += __shfl_xor(ss, d, 64);
  __shared__ float red[4];
  if ((tid & 63) == 0) red[tid >> 6] = ss;
  __syncthreads();
  float tot = red[0] + red[1] + red[2] + red[3];
  const float sc = rsqrtf(tot * (1.f / (float)DIM) + 1e-6f);
  f32x4 wv4 = *(const f32x4*)&w[tid * 4];
  u32x2 o;
  o[0] = (u32)f2bf(v[0] * sc * wv4[0]) | ((u32)f2bf(v[1] * sc * wv4[1]) << 16);
  o[1] = (u32)f2bf(v[2] * sc * wv4[2]) | ((u32)f2bf(v[3] * sc * wv4[3]) << 16);
  const int u = tid >> 1, hf = tid & 1;
  const int up = (u & 0x78) | ((u & 7) ^ (row & 7));
  *(u32x2*)&out[(long)row * DIM + up * 8 + hf * 4] = o;
}

// ---------------- 256x256 GEMM, 2-barrier K-tile (T2+T4+T5), K multiple of 64 ----------
// Per tile: read all 24 frags; Q00+Q10 (B0 dies) overlap reads; lgkm-drain+barrier
// (all waves' reads sampled -> buf overwrite-safe); stage kt+2; Q01+Q11; vmcnt(8)+barrier.
template <int EPI>
__global__ __launch_bounds__(512, 2) void gemm256(const u16* __restrict__ A,
                                                  const u16* __restrict__ Bw,
                                                  const float* __restrict__ bias,
                                                  u16* __restrict__ out_bf,
                                                  int N, int K) {
  __shared__ __align__(16) u16 Ab[2][256 * 64];
  __shared__ __align__(16) u16 Bb[2][256 * 64];
  const int tid = threadIdx.x;
  const int lane = tid & 63;
  const int wid = tid >> 6;
  const int wm = wid >> 2, wn = wid & 3;
  const int l15 = lane & 15, lhi = lane >> 4;
  const int c7 = l15 & 7;
  const long m0 = (long)blockIdx.y * 256;
  const long n0 = (long)blockIdx.x * 256;
  const int NT = K >> 6;

  const int srow = tid >> 3;
  const int sunit = (tid & 7) * 8;
  const u16* agp = A + (m0 + srow) * K + sunit;
  const u16* bgp = Bw + (n0 + srow) * K + sunit;
  const int ldst = tid * 8;

  auto stageA = [&](int kt, int b) {
    const int k0 = kt << 6;
    u16* d = &Ab[b][0];
#pragma unroll
    for (int c = 0; c < 4; ++c)
      gl_lds16(agp + (long)(c * 64) * K + k0, d + c * 4096 + ldst);
  };
  auto stageB = [&](int kt, int b) {
    const int k0 = kt << 6;
    u16* d = &Bb[b][0];
#pragma unroll
    for (int c = 0; c < 4; ++c)
      gl_lds16(bgp + (long)(c * 64) * K + k0, d + c * 4096 + ldst);
  };

#define READ_A(MH)                                                               \
  _Pragma("unroll") for (int m_ = 0; m_ < 4; ++m_) {                             \
    _Pragma("unroll") for (int ks_ = 0; ks_ < 2; ++ks_) {                        \
      Afr[MH][m_ * 2 + ks_] =                                                    \
          *(const bf16x8*)&Ac[(wm * 128 + (MH)*64 + m_ * 16 + l15) * 64 +        \
                              (((ks_ * 4 + lhi) ^ c7) * 8)];                     \
    }                                                                            \
  }
#define READ_B(NH)                                                               \
  _Pragma("unroll") for (int n_ = 0; n_ < 2; ++n_) {                             \
    _Pragma("unroll") for (int ks_ = 0; ks_ < 2; ++ks_) {                        \
      Bfr[NH][n_ * 2 + ks_] =                                                    \
          *(const bf16x8*)&Bc[(wn * 64 + (NH)*32 + n_ * 16 + l15) * 64 +         \
                              (((ks_ * 4 + lhi) ^ c7) * 8)];                     \
    }                                                                            \
  }
#define QUAD(MH, NH)                                                             \
  do {                                                                           \
    __builtin_amdgcn_s_setprio(1);                                               \
    _Pragma("unroll") for (int m_ = 0; m_ < 4; ++m_) {                           \
      _Pragma("unroll") for (int n_ = 0; n_ < 2; ++n_) {                         \
        acc[(MH)*4 + m_][(NH)*2 + n_] =                                          \
            MFMA16(Afr[MH][m_ * 2], Bfr[NH][n_ * 2],                             \
                   acc[(MH)*4 + m_][(NH)*2 + n_], 0, 0, 0);                      \
        acc[(MH)*4 + m_][(NH)*2 + n_] =                                          \
            MFMA16(Afr[MH][m_ * 2 + 1], Bfr[NH][n_ * 2 + 1],                     \
                   acc[(MH)*4 + m_][(NH)*2 + n_], 0, 0, 0);                      \
      }                                                                          \
    }                                                                            \
    __builtin_amdgcn_s_setprio(0);                                               \
  } while (0)

  f32x4 acc[8][4] = {};

  // prologue: tiles 0,1 staged; wait tile 0 (tile 1 stays in flight)
  stageA(0, 0);
  stageB(0, 0);
  stageA(1, 1);
  stageB(1, 1);
  asm volatile("s_waitcnt vmcnt(8)" ::: "memory");
  __builtin_amdgcn_s_barrier();
  GFENCE();

  for (int kt = 0; kt < NT; ++kt) {
    const int b = kt & 1;
    const u16* Ac = &Ab[b][0];
    const u16* Bc = &Bb[b][0];
    bf16x8 Afr[2][8], Bfr[2][4];
    // read everything for this tile (24 ds_read_b128), overlap with first 32 MFMA
    READ_A(0);
    READ_B(0);
    READ_A(1);
    READ_B(1);
    QUAD(0, 0);
    QUAD(1, 0);  // B-half0 dead after this
    // all this tile's LDS reads sampled before anyone overwrites buf b
    asm volatile("s_waitcnt lgkmcnt(0)" ::: "memory");
    __builtin_amdgcn_sched_barrier(0);
    __builtin_amdgcn_s_barrier();
    GFENCE();
    if (kt + 2 < NT) {
      stageA(kt + 2, b);
      stageB(kt + 2, b);
    }
    QUAD(0, 1);
    QUAD(1, 1);
    // boundary: tile kt+1 must be resident; keep kt+2 prefetch in flight
    if (kt + 1 < NT) {
      if (kt + 2 < NT)
        asm volatile("s_waitcnt vmcnt(8)" ::: "memory");
      else
        asm volatile("s_waitcnt vmcnt(0)" ::: "memory");
      __builtin_amdgcn_s_barrier();
      GFENCE();
    }
  }
#undef READ_A
#undef READ_B
#undef QUAD

#pragma unroll
  for (int mi = 0; mi < 8; ++mi) {
    const long row0 = m0 + wm * 128 + mi * 16 + lhi * 4;
#pragma unroll
    for (int ni = 0; ni < 4; ++ni) {
      const long col = n0 + wn * 64 + ni * 16 + l15;
      const float bb = bias[col];
#pragma unroll
      for (int r = 0; r < 4; ++r) {
        float v = acc[mi][ni][r] + bb;
        if (EPI == 2) {
          float other = __shfl_xor(v, 1, 64);
          if (!(l15 & 1)) {
            float s = v / (1.f + __expf(-v)) * other;  // silu(g)*v
            out_bf[(row0 + r) * (N >> 1) + (col >> 1)] = f2bf(s);
          }
        } else {
          out_bf[(row0 + r) * N + col] = f2bf(v);
        }
      }
    }
  }
}

// ---------------- 3-buffer GEMM (linear layouts) for skinny N ----------------
template <int EPI, int NB>
__global__ __launch_bounds__(256) void gemm_bt(const u16* __restrict__ A,
                                               const u16* __restrict__ Bw,
                                               const float* __restrict__ bias,
                                               const float* __restrict__ resid,
                                               u16* __restrict__ out_bf,
                                               float* __restrict__ out_f,
                                               int N, int K) {
  constexpr int BHALF = NB / 64;
  constexpr int NFR = NB / 32;
  constexpr int LPT = 2 + BHALF;
  __shared__ __align__(16) u16 As[3][128 * 32];
  __shared__ __align__(16) u16 Bs[3][NB * 32];
  const int tid = threadIdx.x;
  const int lane = tid & 63;
  const int wv = tid >> 6;
  const int wr = wv >> 1, wc = wv & 1;
  const long m0 = (long)blockIdx.y * 128;
  const long n0 = (long)blockIdx.x * NB;

  const int arow = tid >> 2;
  const int acol = (tid & 3) << 3;
  const u16* ag = A + (m0 + arow) * K + acol;
  const u16* bg = Bw + (n0 + arow) * K + acol;
  const long hK = (long)64 * K;

  f32x4 acc[4][NFR] = {};
  const int l15 = lane & 15;
  const int lhi = lane >> 4;
  const int aoff0 = (wr * 64 + l15) * 32 + lhi * 8;
  const int boff0 = (wc * (NB / 2) + l15) * 32 + lhi * 8;
  const int nk = K >> 5;

  auto stage = [&](int t, int buf) {
    const int k0 = t << 5;
    gl_lds16(ag + k0, &As[buf][tid * 8]);
    gl_lds16(ag + k0 + hK, &As[buf][2048 + tid * 8]);
    gl_lds16(bg + k0, &Bs[buf][tid * 8]);
    if (BHALF == 2) gl_lds16(bg + k0 + hK, &Bs[buf][2048 + tid * 8]);
  };

  stage(0, 0);
  stage(1, 1);
  asm volatile("s_waitcnt vmcnt(%0)" ::"n"(LPT) : "memory");
  __builtin_amdgcn_s_barrier();
  GFENCE();

  for (int t = 0; t < nk; ++t) {
    const int cb = t % 3;
    if (t + 2 < nk) stage(t + 2, (t + 2) % 3);
    bf16x8 af[4], bfr[NFR];
#pragma unroll
    for (int i = 0; i < 4; ++i) af[i] = *(const bf16x8*)&As[cb][aoff0 + i * 16 * 32];
#pragma unroll
    for (int j = 0; j < NFR; ++j) bfr[j] = *(const bf16x8*)&Bs[cb][boff0 + j * 16 * 32];
    __builtin_amdgcn_s_setprio(1);
#pragma unroll
    for (int i = 0; i < 4; ++i)
#pragma unroll
      for (int j = 0; j < NFR; ++j)
        acc[i][j] = MFMA16(af[i], bfr[j], acc[i][j], 0, 0, 0);
    __builtin_amdgcn_s_setprio(0);
    if (t + 2 < nk) {
      asm volatile("s_waitcnt vmcnt(%0)" ::"n"(LPT) : "memory");
      __builtin_amdgcn_s_barrier();
      GFENCE();
    } else if (t + 1 < nk) {
      asm volatile("s_waitcnt vmcnt(0)" ::: "memory");
      __builtin_amdgcn_s_barrier();
      GFENCE();
    }
  }

#pragma unroll
  for (int i = 0; i < 4; ++i) {
    const long row0 = m0 + wr * 64 + i * 16 + lhi * 4;
#pragma unroll
    for (int j = 0; j < NFR; ++j) {
      const long col = n0 + wc * (NB / 2) + j * 16 + l15;
      const float bb = bias[col];
#pragma unroll
      for (int r = 0; r < 4; ++r) {
        const long idx = (row0 + r) * N + col;
        float v = acc[i][j][r] + bb;
        if (EPI == 0) out_bf[idx] = f2bf(v);
        else          out_f[idx] = resid[idx] + v;
      }
    }
  }
}

// ---------------- fused RoPE(Q), RoPE(K)+concat, V-transpose+concat ----------------
// blocks [0,2048): Q; [2048,5120): K; [5120,8192): Vt
__global__ __launch_bounds__(256) void rope_all_kernel(const u16* __restrict__ qkv,
                                                       const float* __restrict__ cache_k,
                                                       const float* __restrict__ cache_v,
                                                       const float* __restrict__ cosT,
                                                       const float* __restrict__ sinT,
                                                       u16* __restrict__ Q,
                                                       u16* __restrict__ Kall,
                                                       u16* __restrict__ Vtg) {
  const int blk = blockIdx.x;
  if (blk < 2048) {
    int idx = blk * 256 + threadIdx.x;  // B*H*S*8 = 524288 units of 8 elems
    int u = idx & 7;
    int s = (idx >> 3) & (S_LEN - 1);
    int bh = idx >> 14;
    int b = bh >> 4, h = bh & 15;
    int pos = PREV + s;
    const float SC = 0.125f * LOG2E;
    const u16* src = qkv + ((long)(b * S_LEN + s)) * (3 * DIM) + h * HD + u * 8;
    u32x4 d = *(const u32x4*)src;
    f32x4 cv = *(const f32x4*)&cosT[(long)pos * 32 + u * 4];
    f32x4 sv = *(const f32x4*)&sinT[(long)pos * 32 + u * 4];
    u32x4 o;
#pragma unroll
    for (int p = 0; p < 4; ++p) {
      float x0 = bf2f((u16)(d[p] & 0xffff));
      float x1 = bf2f((u16)(d[p] >> 16));
      float y0 = (x0 * cv[p] - x1 * sv[p]) * SC;
      float y1 = (x0 * sv[p] + x1 * cv[p]) * SC;
      o[p] = (u32)f2bf(y0) | ((u32)f2bf(y1) << 16);
    }
    *(u32x4*)&Q[((long)bh * S_LEN + s) * HD + u * 8] = o;
  } else if (blk < 5120) {
    int idx = (blk - 2048) * 256 + threadIdx.x;  // B*H*T*8 = 786432
    int u = idx & 7;
    int t2 = idx >> 3;
    int j = t2 % T_LEN;
    int bh = t2 / T_LEN;
    int b = bh >> 4, h = bh & 15;
    float e[8];
    if (j < PREV) {
      const float* src = cache_k + ((long)bh * PREV + j) * HD + u * 8;
      f32x4 a = *(const f32x4*)src;
      f32x4 c = *(const f32x4*)(src + 4);
      e[0] = a[0]; e[1] = a[1]; e[2] = a[2]; e[3] = a[3];
      e[4] = c[0]; e[5] = c[1]; e[6] = c[2]; e[7] = c[3];
    } else {
      const u16* src = qkv + ((long)(b * S_LEN + (j - PREV))) * (3 * DIM) + DIM + h * HD + u * 8;
      u32x4 d = *(const u32x4*)src;
#pragma unroll
      for (int p = 0; p < 4; ++p) {
        e[2 * p] = bf2f((u16)(d[p] & 0xffff));
        e[2 * p + 1] = bf2f((u16)(d[p] >> 16));
      }
    }
    f32x4 cv = *(const f32x4*)&cosT[(long)j * 32 + u * 4];
    f32x4 sv = *(const f32x4*)&sinT[(long)j * 32 + u * 4];
    u32x4 o;
#pragma unroll
    for (int p = 0; p < 4; ++p) {
      float y0 = e[2 * p] * cv[p] - e[2 * p + 1] * sv[p];
      float y1 = e[2 * p] * sv[p] + e[2 * p + 1] * cv[p];
      o[p] = (u32)f2bf(y0) | ((u32)f2bf(y1) << 16);
    }
    *(u32x4*)&Kall[((long)bh * T_LEN + j) * HD + (u ^ (j & 7)) * 8] = o;
  } else {
    int idx = (blk - 5120) * 256 + threadIdx.x;  // 32 * 384 * 64 = 786432
    int hd = idx & 63;
    int t2 = idx >> 6;
    int kb = t2 % 384;  // 8-key block
    int bh = t2 / 384;
    int b = bh >> 4, h = bh & 15;
    int key0 = kb * 8;
    u16 vals[8];
    if (key0 < PREV) {
#pragma unroll
      for (int i = 0; i < 8; ++i)
        vals[i] = f2bf(cache_v[((long)bh * PREV + key0 + i) * HD + hd]);
    } else {
#pragma unroll
      for (int i = 0; i < 8; ++i)
        vals[i] = qkv[((long)(b * S_LEN + key0 + i - PREV)) * (3 * DIM) + 2 * DIM + h * HD + hd];
    }
    u32x4 o;
#pragma unroll
    for (int p = 0; p < 4; ++p)
      o[p] = (u32)vals[2 * p] | ((u32)vals[2 * p + 1] << 16);
    const int span = kb >> 3;
    const int u = (kb & 7) ^ (hd & 7);
    *(u32x4*)&Vtg[((long)bh * HD + hd) * T_LEN + span * 64 + u * 8] = o;
  }
}

// ---------------- flash attention: paired dual-Q blocks, shared KV sweep ----------------
__global__ __launch_bounds__(256, 2) void attn_kernel(const u16* __restrict__ Q,
                                                      const u16* __restrict__ Kg,
                                                      const u16* __restrict__ Vtg,
                                                      u16* __restrict__ ctx, float slope2) {
  __shared__ __align__(16) u16 Ks[2][64 * 64];     // [key][d], swizzled
  __shared__ __align__(16) u16 Vs[2][64 * 64];     // [hd][key], swizzled
  __shared__ __align__(16) u16 Ps[2][4][16 * 64];  // per-qset per-wave P, swizzled

  const int tid = threadIdx.x;
  const int lane = tid & 63;
  const int wv = tid >> 6;
  const int l15 = lane & 15;
  const int lhi = lane >> 4;
  const int c7 = l15 & 7;
  const int bh = blockIdx.x;
  const int p = blockIdx.y;            // pair index 0..15
  const int b = bh >> 4, h = bh & 15;
  const int qA0 = p * 64;
  const int qB0 = (31 - p) * 64;
  const int ntA = 17 + p;              // (PREV + qA0 + 64) >> 6
  const int ntB = 48 - p;              // ntA + ntB = 65

  const long qrowA = (long)bh * S_LEN + qA0 + wv * 16 + l15;
  const long qrowB = (long)bh * S_LEN + qB0 + wv * 16 + l15;
  bf16x8 aqA0 = *(const bf16x8*)&Q[qrowA * HD + lhi * 8];
  bf16x8 aqA1 = *(const bf16x8*)&Q[qrowA * HD + 32 + lhi * 8];
  bf16x8 aqB0 = *(const bf16x8*)&Q[qrowB * HD + lhi * 8];
  bf16x8 aqB1 = *(const bf16x8*)&Q[qrowB * HD + 32 + lhi * 8];

  const long kgb = (long)bh * T_LEN * HD;  // K: [key][64]
  const long vgb = (long)bh * HD * T_LEN;  // Vt: [hd][T]
  const int srow = tid >> 3;               // staging row 0..31
  const int sunit = (tid & 7) * 8;

  const u16* kst = Kg + kgb + (long)srow * HD + sunit;     // +64*HD per tile
  const u16* vst = Vtg + vgb + (long)srow * T_LEN + sunit; // +64 per tile

  // prologue: stage tile 0
  gl_lds16(kst, &Ks[0][tid * 8]);
  gl_lds16(kst + 32 * HD, &Ks[0][2048 + tid * 8]);
  gl_lds16(vst, &Vs[0][tid * 8]);
  gl_lds16(vst + (long)32 * T_LEN, &Vs[0][2048 + tid * 8]);
  kst += 64 * HD;
  vst += 64;
  __syncthreads();

  f32x4 oA[4] = {}, oB[4] = {};
  f32x4 lrunA = {0.f, 0.f, 0.f, 0.f}, lrunB = {0.f, 0.f, 0.f, 0.f};
  float mrunA = -1e30f, mrunB = -1e30f;
  const int qq = wv * 16 + l15;  // local q (mask threshold, same layout both q-sets)

  f32x4 be[4];  // per-thread bias constants slope*(jf*16+4*lhi+r)
#pragma unroll
  for (int jf = 0; jf < 4; ++jf)
#pragma unroll
    for (int r = 0; r < 4; ++r)
      be[jf][r] = slope2 * (float)(jf * 16 + 4 * lhi + r);
  const float bmax = slope2 * 63.f;

  bf16x8 vones;
#pragma unroll
  for (int e = 0; e < 8; ++e) vones[e] = (__bf16)1.0f;

  float ktf = 0.f;
  const float kstep = slope2 * 64.f;

  // softmax + PV for one q-set (separate P buffer per q-set)
  auto process = [&](f32x4 (&sf)[4], bool maskNow, f32x4 (&o)[4], f32x4& lrun,
                     float& mrun, bf16x8 (&vf)[8], u16* Pw) {
    if (maskNow) {
#pragma unroll
      for (int jf = 0; jf < 4; ++jf)
#pragma unroll
        for (int r = 0; r < 4; ++r)
          if (jf * 16 + 4 * lhi + r > qq) sf[jf][r] = -1e30f;
    }
    float h0 = fmaxf(fmaxf(sf[0][0], sf[0][1]), fmaxf(sf[0][2], sf[0][3]));
    float h1 = fmaxf(fmaxf(sf[1][0], sf[1][1]), fmaxf(sf[1][2], sf[1][3]));
    float h2 = fmaxf(fmaxf(sf[2][0], sf[2][1]), fmaxf(sf[2][2], sf[2][3]));
    float h3 = fmaxf(fmaxf(sf[3][0], sf[3][1]), fmaxf(sf[3][2], sf[3][3]));
    float pm = fmaxf(fmaxf(h0, h1), fmaxf(h2, h3));
    pm = fmaxf(pm, __shfl_xor(pm, 16, 64));
    pm = fmaxf(pm, __shfl_xor(pm, 32, 64));
    const float pmax_abs = pm + ktf + bmax;

    if (!__all(pmax_abs - mrun <= 8.f)) {
      const float mnew = fmaxf(mrun, pmax_abs);
      const float scl = exp2f(mrun - mnew);
      mrun = mnew;
#pragma unroll
      for (int r = 0; r < 4; ++r) {
        const float sr = __shfl(scl, 4 * lhi + r, 64);
        lrun[r] *= sr;
#pragma unroll
        for (int hf = 0; hf < 4; ++hf) o[hf][r] *= sr;
      }
    }
    const float meff = mrun - ktf;

#pragma unroll
    for (int jf = 0; jf < 4; ++jf) {
      f32x4 pp;
#pragma unroll
      for (int r = 0; r < 4; ++r)
        pp[r] = exp2f(sf[jf][r] + (be[jf][r] - meff));
      u32x2 pw2;
      pw2[0] = cvtpk(pp[0], pp[1]);
      pw2[1] = cvtpk(pp[2], pp[3]);
      const int u = (2 * jf + (lhi >> 1)) ^ c7;
      *(u32x2*)&Pw[l15 * 64 + u * 8 + (lhi & 1) * 4] = pw2;
    }

    bf16x8 pa0 = *(const bf16x8*)&Pw[l15 * 64 + ((lhi ^ c7) * 8)];
    bf16x8 pa1 = *(const bf16x8*)&Pw[l15 * 64 + (((4 + lhi) ^ c7) * 8)];
    f32x4 psum = {};
    __builtin_amdgcn_s_setprio(1);
    psum = MFMA16(pa0, vones, psum, 0, 0, 0);
    psum = MFMA16(pa1, vones, psum, 0, 0, 0);
#pragma unroll
    for (int hf = 0; hf < 4; ++hf) {
      o[hf] = MFMA16(pa0, vf[2 * hf], o[hf], 0, 0, 0);
      o[hf] = MFMA16(pa1, vf[2 * hf + 1], o[hf], 0, 0, 0);
    }
    __builtin_amdgcn_s_setprio(0);
    lrun += psum;
  };

  for (int t = 0; t < ntB; ++t) {
    const int cur = t & 1, nxt = cur ^ 1;
    const bool lastStage = (t + 1 == ntB);
    if (!lastStage) {
      gl_lds16(kst, &Ks[nxt][tid * 8]);
      gl_lds16(kst + 32 * HD, &Ks[nxt][2048 + tid * 8]);
      gl_lds16(vst, &Vs[nxt][tid * 8]);
      gl_lds16(vst + (long)32 * T_LEN, &Vs[nxt][2048 + tid * 8]);
      kst += 64 * HD;
      vst += 64;
    }
    const bool actA = (t < ntA);

    // K fragments once, shared by both q-sets
    bf16x8 kf[8];
#pragma unroll
    for (int jf = 0; jf < 4; ++jf) {
      const int krow = jf * 16 + l15;
      kf[2 * jf] = *(const bf16x8*)&Ks[cur][krow * 64 + ((lhi ^ c7) * 8)];
      kf[2 * jf + 1] = *(const bf16x8*)&Ks[cur][krow * 64 + (((4 + lhi) ^ c7) * 8)];
    }
    // V fragments once, shared by both q-sets
    bf16x8 vf[8];
#pragma unroll
    for (int hf = 0; hf < 4; ++hf) {
      const int vrow = hf * 16 + l15;
      vf[2 * hf] = *(const bf16x8*)&Vs[cur][vrow * 64 + ((lhi ^ c7) * 8)];
      vf[2 * hf + 1] = *(const bf16x8*)&Vs[cur][vrow * 64 + (((4 + lhi) ^ c7) * 8)];
    }

    // QK^T for both q-sets
    f32x4 sB[4], sA[4];
    __builtin_amdgcn_s_setprio(1);
#pragma unroll
    for (int jf = 0; jf < 4; ++jf) {
      f32x4 s = {};
      s = MFMA16(kf[2 * jf], aqB0, s, 0, 0, 0);
      s = MFMA16(kf[2 * jf + 1], aqB1, s, 0, 0, 0);
      sB[jf] = s;
    }
    __builtin_amdgcn_s_setprio(0);
    if (actA) {
      __builtin_amdgcn_s_setprio(1);
#pragma unroll
      for (int jf = 0; jf < 4; ++jf) {
        f32x4 s = {};
        s = MFMA16(kf[2 * jf], aqA0, s, 0, 0, 0);
        s = MFMA16(kf[2 * jf + 1], aqA1, s, 0, 0, 0);
        sA[jf] = s;
      }
      __builtin_amdgcn_s_setprio(0);
    }

    process(sB, t == ntB - 1, oB, lrunB, mrunB, vf, &Ps[0][wv][0]);
    if (actA) process(sA, t == ntA - 1, oA, lrunA, mrunA, vf, &Ps[1][wv][0]);

    ktf += kstep;
    if (!lastStage) __syncthreads();
  }

  // epilogue: rows q_local = 4*lhi + r; cols hd = hf*16 + l15
#pragma unroll
  for (int r = 0; r < 4; ++r) {
    const float invA = 1.f / lrunA[r];
    const float invB = 1.f / lrunB[r];
    const long rowA = (long)b * S_LEN + qA0 + wv * 16 + 4 * lhi + r;
    const long rowB = (long)b * S_LEN + qB0 + wv * 16 + 4 * lhi + r;
#pragma unroll
    for (int hf = 0; hf < 4; ++hf) {
      ctx[rowA * DIM + h * HD + hf * 16 + l15] = f2bf(oA[hf][r] * invA);
      ctx[rowB * DIM + h * HD + hf * 16 + l15] = f2bf(oB[hf][r] * invB);
    }
  }
}

// ---------------------------------------------------------------------------
extern "C" void kernel_launch(void* const* d_in, const int* in_sizes, int n_in,
                              void* d_out, int out_size, void* d_ws, size_t ws_size,
                              hipStream_t stream) {
  (void)in_sizes; (void)n_in; (void)out_size; (void)ws_size;
  const float* x       = (const float*)d_in[0];
  const float* cache_k = (const float*)d_in[1];
  const float* cache_v = (const float*)d_in[2];
  const float* cosT    = (const float*)d_in[3];
  const float* sinT    = (const float*)d_in[4];
  const float* attn_w  = (const float*)d_in[5];
  const float* ffn_w   = (const float*)d_in[6];
  const float* wq      = (const float*)d_in[7];
  const float* bq      = (const float*)d_in[8];
  const float* wk      = (const float*)d_in[9];
  const float* bk      = (const float*)d_in[10];
  const float* wv_     = (const float*)d_in[11];
  const float* bv      = (const float*)d_in[12];
  const float* wo      = (const float*)d_in[13];
  const float* bo      = (const float*)d_in[14];
  const float* wg      = (const float*)d_in[15];
  const float* bg      = (const float*)d_in[16];
  const float* wval    = (const float*)d_in[17];
  const float* bval    = (const float*)d_in[18];
  const float* wp      = (const float*)d_in[19];
  const float* bp      = (const float*)d_in[20];
  float* out = (float*)d_out;

  char* w = (char*)d_ws;
  size_t off = 0;
  auto alloc = [&](size_t bytes) -> char* {
    char* p = w + off;
    off += (bytes + 255) & ~(size_t)255;
    return p;
  };
  // permanent
  u16*   wqkv_bf  = (u16*)alloc((size_t)3 * DIM * DIM * 2);  // preswizzled
  u16*   wo_bf    = (u16*)alloc((size_t)DIM * DIM * 2);      // linear
  u16*   wgv_bf   = (u16*)alloc((size_t)2 * FF * DIM * 2);   // interleaved+preswizzled
  u16*   wproj_bf = (u16*)alloc((size_t)DIM * FF * 2);       // linear
  float* bqkv     = (float*)alloc((size_t)3 * DIM * 4);
  float* bgv      = (float*)alloc((size_t)2 * FF * 4);       // interleaved
  float* x2       = (float*)alloc((size_t)MROWS * DIM * 4);
  // arena with lifetime-based aliasing
  char* AR = alloc((size_t)117440512);
  u16* qkv   = (u16*)(AR + 0);          // [4096][3072]   live: qkv gemm -> rope/build
  u16* Qb    = (u16*)(AR + 25165824);   // [32][2048][64] live: rope -> attn
  u16* Kb    = (u16*)(AR + 33554432);   // [32][3072][64]
  u16* Vtg   = (u16*)(AR + 46137344);   // [32][64][3072] transposed V
  u16* h1    = (u16*)(AR + 58720256);   // [4096][1024]   preswizzled (qkv gemm A)
  u16* ctx   = (u16*)(AR + 0);          // [4096][1024]   linear (aliases dead qkv)
  u16* h2    = (u16*)(AR + 8388608);    // [4096][1024]   preswizzled (gv gemm A)
  u16* gated = (u16*)(AR + 16777216);   // [4096][4096]   linear

  // 1) ALL weight + bias conversion in one launch
  cvt_all_kernel<<<6172, 256, 0, stream>>>(wq, wk, wv_, wg, wval, wo, wp,
                                           bq, bk, bv, bg, bval,
                                           wqkv_bf, wgv_bf, wo_bf, wproj_bf,
                                           bqkv, bgv);

  // 2) attn rmsnorm (swizzled out), fused QKV 256-gemm
  rmsnorm_kernel<<<MROWS, 256, 0, stream>>>(x, attn_w, h1);
  gemm256<0><<<dim3(12, 16), 512, 0, stream>>>(h1, wqkv_bf, bqkv, qkv, 3 * DIM, DIM);
  // 3) fused rope + cache concat (1 launch)
  rope_all_kernel<<<8192, 256, 0, stream>>>(qkv, cache_k, cache_v, cosT, sinT,
                                            Qb, Kb, Vtg);
  // 4) attention: paired dual-Q blocks
  attn_kernel<<<dim3(B_SZ * NH, 16), 256, 0, stream>>>(
      Qb, Kb, Vtg, ctx, (2.0f / (float)(T_LEN - 1)) * LOG2E);
  // 5) o-proj + residual (fp32), skinny tile
  gemm_bt<1, 64><<<dim3(16, 32), 256, 0, stream>>>(ctx, wo_bf, bo, x, nullptr, x2,
                                                   DIM, DIM);
  // 6) ffn rmsnorm (swizzled out), gate+value 256-gemm w/ silu epilogue, proj + residual
  rmsnorm_kernel<<<MROWS, 256, 0, stream>>>(x2, ffn_w, h2);
  gemm256<2><<<dim3(32, 16), 512, 0, stream>>>(h2, wgv_bf, bgv, gated, 2 * FF, DIM);
  gemm_bt<1, 64><<<dim3(16, 32), 256, 0, stream>>>(gated, wproj_bf, bp, x2, nullptr, out,
                                                   DIM, FF);
}